// Round 1
// baseline (16360.863 us; speedup 1.0000x reference)
//
#include <hip/hip_runtime.h>

// ---------- types ----------
typedef float  f32x4  __attribute__((ext_vector_type(4)));
typedef unsigned short u16x4 __attribute__((ext_vector_type(4)));
typedef unsigned short u16x8 __attribute__((ext_vector_type(8)));
typedef __bf16 bf16x8 __attribute__((ext_vector_type(8)));

// round-to-nearest-even f32 -> bf16 (bit trick)
static __device__ __forceinline__ unsigned short bf16_rn(float x) {
  unsigned u = __builtin_bit_cast(unsigned, x);
  unsigned r = (u + 0x7FFFu + ((u >> 16) & 1u)) >> 16;
  return (unsigned short)r;
}
// split x ~= hi + lo (each bf16); residual ~2^-17 relative
static __device__ __forceinline__ void split1(float x, unsigned short& h, unsigned short& l) {
  unsigned short hh = bf16_rn(x);
  float hf = __builtin_bit_cast(float, ((unsigned)hh) << 16);
  h = hh;
  l = bf16_rn(x - hf);
}

// ---------- GEMM: C = A(f32,MxK) * B(f32,KxN) + bias, via split-bf16 3-term MFMA ----------
#define BM 128
#define BN 128
#define BK 32
#define LDK 40  // padded LDS row (bf16 elems) -> 80B rows, 2-way bank conflicts only

__global__ __launch_bounds__(256) void gemm_split3(
    const float* __restrict__ A, const float* __restrict__ B,
    const float* __restrict__ bias, float* __restrict__ C,
    int M, int N, int K) {
  __shared__ unsigned short Ah[BM * LDK];
  __shared__ unsigned short Al[BM * LDK];
  __shared__ unsigned short Bh[BN * LDK];
  __shared__ unsigned short Bl[BN * LDK];

  const int tid  = threadIdx.x;
  const int lane = tid & 63;
  const int wave = tid >> 6;
  const int bm = blockIdx.x * BM;  // m-fast so consecutive blocks share the B panel
  const int bn = blockIdx.y * BN;
  const int wm = (wave >> 1) * 64;
  const int wn = (wave & 1) * 64;
  const bool nvec = ((N & 3) == 0);

  f32x4 acc[4][4] = {};

  const int ar  = tid >> 3;          // 0..31
  const int ak  = (tid & 7) << 2;    // 0..28
  const int bk  = tid >> 5;          // 0..7
  const int bn4 = (tid & 31) << 2;   // 0..124

  for (int k0 = 0; k0 < K; k0 += BK) {
    // stage A (128x32 f32) -> split bf16 hi/lo
#pragma unroll
    for (int p = 0; p < 4; ++p) {
      int r = ar + (p << 5);
      f32x4 v = *(const f32x4*)(A + (size_t)(bm + r) * K + (k0 + ak));
      u16x4 h, l;
#pragma unroll
      for (int j = 0; j < 4; ++j) { unsigned short hh, ll; split1(v[j], hh, ll); h[j] = hh; l[j] = ll; }
      *(u16x4*)(&Ah[r * LDK + ak]) = h;
      *(u16x4*)(&Al[r * LDK + ak]) = l;
    }
    // stage B (32x128 f32) transposed -> LDS [col][k]
#pragma unroll
    for (int p = 0; p < 4; ++p) {
      int kr = bk + (p << 3);
      const float* src = B + (size_t)(k0 + kr) * N + (bn + bn4);
      float v[4];
      if (nvec) {
        f32x4 t4 = *(const f32x4*)src;
        v[0] = t4.x; v[1] = t4.y; v[2] = t4.z; v[3] = t4.w;
      } else {
#pragma unroll
        for (int j = 0; j < 4; ++j) {
          int col = bn + bn4 + j;
          v[j] = (col < N) ? src[j] : 0.f;
        }
      }
#pragma unroll
      for (int j = 0; j < 4; ++j) {
        unsigned short hh, ll; split1(v[j], hh, ll);
        Bh[(bn4 + j) * LDK + kr] = hh;
        Bl[(bn4 + j) * LDK + kr] = ll;
      }
    }
    __syncthreads();

    const int fr = lane & 15;
    const int kg = (lane >> 4) << 3;
    u16x8 a_h[4], a_l[4], b_h[4], b_l[4];
#pragma unroll
    for (int i = 0; i < 4; ++i) {
      a_h[i] = *(const u16x8*)(&Ah[(wm + i * 16 + fr) * LDK + kg]);
      a_l[i] = *(const u16x8*)(&Al[(wm + i * 16 + fr) * LDK + kg]);
      b_h[i] = *(const u16x8*)(&Bh[(wn + i * 16 + fr) * LDK + kg]);
      b_l[i] = *(const u16x8*)(&Bl[(wn + i * 16 + fr) * LDK + kg]);
    }
#pragma unroll
    for (int i = 0; i < 4; ++i)
#pragma unroll
      for (int j = 0; j < 4; ++j) {
        acc[i][j] = __builtin_amdgcn_mfma_f32_16x16x32_bf16(
            __builtin_bit_cast(bf16x8, a_h[i]), __builtin_bit_cast(bf16x8, b_h[j]), acc[i][j], 0, 0, 0);
        acc[i][j] = __builtin_amdgcn_mfma_f32_16x16x32_bf16(
            __builtin_bit_cast(bf16x8, a_h[i]), __builtin_bit_cast(bf16x8, b_l[j]), acc[i][j], 0, 0, 0);
        acc[i][j] = __builtin_amdgcn_mfma_f32_16x16x32_bf16(
            __builtin_bit_cast(bf16x8, a_l[i]), __builtin_bit_cast(bf16x8, b_h[j]), acc[i][j], 0, 0, 0);
      }
    __syncthreads();
  }
  // epilogue: D col = lane&15, row = (lane>>4)*4 + reg  [HW-verified mapping]
  const int cc = lane & 15;
  const int rg = (lane >> 4) << 2;
#pragma unroll
  for (int i = 0; i < 4; ++i)
#pragma unroll
    for (int j = 0; j < 4; ++j)
#pragma unroll
      for (int r = 0; r < 4; ++r) {
        int row = bm + wm + i * 16 + rg + r;
        int col = bn + wn + j * 16 + cc;
        if (col < N) {
          float v = acc[i][j][r];
          if (bias) v += bias[col];
          C[(size_t)row * N + col] = v;
        }
      }
}

// ---------- LSTM recurrence step (fp32) ----------
// 128 WGs x 256 thr. WG w owns units [8w, 8w+8). Thread (b=t&15, j=(t>>4)&7, kh=t>>7)
// computes all 4 gate dots (k-half) for unit 8w+j, batch b. whT is [4096 cols][1024 k].
__global__ __launch_bounds__(256) void lstm_step(
    const float* __restrict__ whT, const float* __restrict__ xw_t,
    const float* __restrict__ bh, const float* __restrict__ h_in,
    float* __restrict__ h_out, float* __restrict__ c_buf, float* __restrict__ ys_t) {
  __shared__ float hs[16 * 1024];  // XOR-swizzled copy of h (64 KB)
  const int tid = threadIdx.x;
#pragma unroll
  for (int p = 0; p < 16; ++p) {
    int idx = (p * 256 + tid) << 2;
    int b = idx >> 10;
    int k = idx & 1023;
    f32x4 v = *(const f32x4*)(h_in + idx);
    *(f32x4*)(&hs[(b << 10) | (k ^ (b << 3))]) = v;
  }
  __syncthreads();

  const int b = tid & 15;
  const int j = (tid >> 4) & 7;
  const int kh = tid >> 7;
  const int u = (blockIdx.x << 3) + j;

  const float* w0 = whT + ((size_t)u << 10);
  const float* w1 = whT + ((size_t)(1024 + u) << 10);
  const float* w2 = whT + ((size_t)(2048 + u) << 10);
  const float* w3 = whT + ((size_t)(3072 + u) << 10);

  float a0 = 0.f, a1 = 0.f, a2 = 0.f, a3 = 0.f;
  const int kbeg = kh << 9;
#pragma unroll 4
  for (int k = kbeg; k < kbeg + 512; k += 4) {
    f32x4 hv = *(const f32x4*)(&hs[(b << 10) | (k ^ (b << 3))]);
    f32x4 v0 = *(const f32x4*)(w0 + k);
    f32x4 v1 = *(const f32x4*)(w1 + k);
    f32x4 v2 = *(const f32x4*)(w2 + k);
    f32x4 v3 = *(const f32x4*)(w3 + k);
#pragma unroll
    for (int q = 0; q < 4; ++q) {
      a0 += hv[q] * v0[q];
      a1 += hv[q] * v1[q];
      a2 += hv[q] * v2[q];
      a3 += hv[q] * v3[q];
    }
  }
  __syncthreads();              // hs no longer needed; reuse as reduction buffer
  float* red = hs;              // [j][b][gate]
  const int ri = ((j * 16 + b) << 2);
  if (kh == 1) {
    red[ri + 0] = a0; red[ri + 1] = a1; red[ri + 2] = a2; red[ri + 3] = a3;
  }
  __syncthreads();
  if (kh == 0) {
    a0 += red[ri + 0]; a1 += red[ri + 1]; a2 += red[ri + 2]; a3 += red[ri + 3];
    float p0 = a0 + xw_t[b * 4096 + u]         + bh[u];
    float p1 = a1 + xw_t[b * 4096 + 1024 + u]  + bh[1024 + u];
    float p2 = a2 + xw_t[b * 4096 + 2048 + u]  + bh[2048 + u];
    float p3 = a3 + xw_t[b * 4096 + 3072 + u]  + bh[3072 + u];
    float f  = 1.f / (1.f + expf(-p0));
    float i_ = 1.f / (1.f + expf(-p1));
    float o  = 1.f / (1.f + expf(-p2));
    float g  = tanhf(p3);
    float c = c_buf[(b << 10) + u];
    c = f * c + i_ * g;
    float h = o * tanhf(c);
    c_buf[(b << 10) + u] = c;
    h_out[(b << 10) + u] = h;
    ys_t[(b << 10) + u] = h;
  }
}

// ---------- small utility kernels ----------
__global__ __launch_bounds__(256) void embed_gather(
    const int* __restrict__ tokens, const float* __restrict__ emb, float* __restrict__ x) {
  int sb = blockIdx.x;
  int tok = tokens[sb];
  const f32x4* src = (const f32x4*)(emb + (size_t)tok * 1024);
  f32x4* dst = (f32x4*)(x + (size_t)sb * 1024);
  dst[threadIdx.x] = src[threadIdx.x];
}

__global__ void transpose_wh(const float* __restrict__ wh, float* __restrict__ whT) {
  __shared__ float tile[32][33];
  int l = blockIdx.z;
  int c0 = blockIdx.x << 5;
  int k0 = blockIdx.y << 5;
  int tx = threadIdx.x, ty = threadIdx.y;  // 32 x 8
  const float* src = wh + ((size_t)l << 22);
  float* dst = whT + ((size_t)l << 22);
#pragma unroll
  for (int i = 0; i < 32; i += 8)
    tile[ty + i][tx] = src[(size_t)(k0 + ty + i) * 4096 + c0 + tx];
  __syncthreads();
#pragma unroll
  for (int i = 0; i < 32; i += 8)
    dst[(size_t)(c0 + ty + i) * 1024 + k0 + tx] = tile[tx][ty + i];
}

__global__ __launch_bounds__(256) void init_hc(
    const float* __restrict__ hidden, float* __restrict__ hbuf, float* __restrict__ cbuf) {
  int i = blockIdx.x * 256 + threadIdx.x;  // 0..32767
  int l = i >> 14;
  int idx = i & 16383;
  hbuf[(l << 15) + idx] = hidden[(l << 15) + idx];           // h0 -> parity-0 buffer
  cbuf[(l << 14) + idx] = hidden[(l << 15) + 16384 + idx];   // c0
}

__global__ __launch_bounds__(256) void finalize_hc(
    const float* __restrict__ hbuf, const float* __restrict__ cbuf, float* __restrict__ out_nh) {
  int i = blockIdx.x * 256 + threadIdx.x;  // 0..32767
  int l = i >> 14;
  int idx = i & 16383;
  out_nh[(l << 15) + idx] = hbuf[(l << 15) + idx];           // final h (parity 0 after 256 steps)
  out_nh[(l << 15) + 16384 + idx] = cbuf[(l << 14) + idx];   // final c
}

// ---------- host ----------
extern "C" void kernel_launch(void* const* d_in, const int* in_sizes, int n_in,
                              void* d_out, int out_size, void* d_ws, size_t ws_size,
                              hipStream_t stream) {
  (void)in_sizes; (void)n_in; (void)out_size; (void)ws_size;
  const int*   tokens    = (const int*)  d_in[0];
  const float* hidden    = (const float*)d_in[1];
  const float* embedding = (const float*)d_in[2];
  const float* wi        = (const float*)d_in[3];
  const float* bi        = (const float*)d_in[4];
  const float* wh        = (const float*)d_in[5];
  const float* bh        = (const float*)d_in[6];
  const float* wdec      = (const float*)d_in[7];
  const float* bdec      = (const float*)d_in[8];

  float* out     = (float*)d_out;
  float* out_res = out;                                   // 256*16*50257
  float* out_nh  = out + (size_t)205852672;               // 2*2*16*1024
  float* out_x   = out + (size_t)205852672 + 65536;       // 256*16*1024

  // workspace layout (floats); total ~134.6 MB
  float* ws    = (float*)d_ws;
  float* whT   = ws;                        // 2*4096*1024 = 8388608
  float* x_emb = whT   + 8388608;           // 4096*1024   = 4194304
  float* xwb   = x_emb + 4194304;           // 4096*4096   = 16777216 (reused per layer)
  float* ys0   = xwb   + 16777216;          // 4096*1024   = 4194304
  float* hbuf  = ys0   + 4194304;           // [2][2][16][1024] = 65536
  float* cbuf  = hbuf  + 65536;             // [2][16][1024]    = 32768

  transpose_wh<<<dim3(128, 32, 2), dim3(32, 8), 0, stream>>>(wh, whT);
  embed_gather<<<4096, 256, 0, stream>>>(tokens, embedding, x_emb);
  init_hc<<<128, 256, 0, stream>>>(hidden, hbuf, cbuf);

  for (int l = 0; l < 2; ++l) {
    const float* a = (l == 0) ? x_emb : ys0;
    gemm_split3<<<dim3(32, 32), 256, 0, stream>>>(
        a, wi + (size_t)l * 4194304, bi + l * 4096, xwb, 4096, 4096, 1024);
    float* ys = (l == 0) ? ys0 : out_x;
    float* hb = hbuf + (size_t)l * 32768;
    float* cb = cbuf + (size_t)l * 16384;
    const float* wT = whT + (size_t)l * 4194304;
    const float* bhl = bh + l * 4096;
    for (int t = 0; t < 256; ++t) {
      lstm_step<<<128, 256, 0, stream>>>(
          wT, xwb + (size_t)t * 65536, bhl,
          hb + ((t & 1) << 14), hb + (((t + 1) & 1) << 14),
          cb, ys + (size_t)t * 16384);
    }
  }
  gemm_split3<<<dim3(32, 393), 256, 0, stream>>>(
      out_x, wdec, bdec, out_res, 4096, 50257, 1024);
  finalize_hc<<<128, 256, 0, stream>>>(hbuf, cbuf, out_nh);
}

// Round 2
// 12365.725 us; speedup vs baseline: 1.3231x; 1.3231x over previous
//
#include <hip/hip_runtime.h>

// ---------- types ----------
typedef float  f32x4  __attribute__((ext_vector_type(4)));
typedef unsigned short u16x4 __attribute__((ext_vector_type(4)));
typedef unsigned short u16x8 __attribute__((ext_vector_type(8)));
typedef __bf16 bf16x8 __attribute__((ext_vector_type(8)));

// round-to-nearest-even f32 -> bf16 (bit trick)
static __device__ __forceinline__ unsigned short bf16_rn(float x) {
  unsigned u = __builtin_bit_cast(unsigned, x);
  unsigned r = (u + 0x7FFFu + ((u >> 16) & 1u)) >> 16;
  return (unsigned short)r;
}
// split x ~= hi + lo (each bf16); residual ~2^-17 relative
static __device__ __forceinline__ void split1(float x, unsigned short& h, unsigned short& l) {
  unsigned short hh = bf16_rn(x);
  float hf = __builtin_bit_cast(float, ((unsigned)hh) << 16);
  h = hh;
  l = bf16_rn(x - hf);
}

// ---------- GEMM: C = A(f32,MxK) * B(f32,KxN) + bias, via split-bf16 3-term MFMA ----------
#define BM 128
#define BN 128
#define BK 32
#define LDK 40  // padded LDS row (bf16 elems)

__global__ __launch_bounds__(256) void gemm_split3(
    const float* __restrict__ A, const float* __restrict__ B,
    const float* __restrict__ bias, float* __restrict__ C,
    int M, int N, int K) {
  __shared__ unsigned short Ah[BM * LDK];
  __shared__ unsigned short Al[BM * LDK];
  __shared__ unsigned short Bh[BN * LDK];
  __shared__ unsigned short Bl[BN * LDK];

  const int tid  = threadIdx.x;
  const int lane = tid & 63;
  const int wave = tid >> 6;
  const int bm = blockIdx.x * BM;
  const int bn = blockIdx.y * BN;
  const int wm = (wave >> 1) * 64;
  const int wn = (wave & 1) * 64;
  const bool nvec = ((N & 3) == 0);

  f32x4 acc[4][4] = {};

  const int ar  = tid >> 3;
  const int ak  = (tid & 7) << 2;
  const int bk  = tid >> 5;
  const int bn4 = (tid & 31) << 2;

  for (int k0 = 0; k0 < K; k0 += BK) {
#pragma unroll
    for (int p = 0; p < 4; ++p) {
      int r = ar + (p << 5);
      f32x4 v = *(const f32x4*)(A + (size_t)(bm + r) * K + (k0 + ak));
      u16x4 h, l;
#pragma unroll
      for (int j = 0; j < 4; ++j) { unsigned short hh, ll; split1(v[j], hh, ll); h[j] = hh; l[j] = ll; }
      *(u16x4*)(&Ah[r * LDK + ak]) = h;
      *(u16x4*)(&Al[r * LDK + ak]) = l;
    }
#pragma unroll
    for (int p = 0; p < 4; ++p) {
      int kr = bk + (p << 3);
      const float* src = B + (size_t)(k0 + kr) * N + (bn + bn4);
      float v[4];
      if (nvec) {
        f32x4 t4 = *(const f32x4*)src;
        v[0] = t4.x; v[1] = t4.y; v[2] = t4.z; v[3] = t4.w;
      } else {
#pragma unroll
        for (int j = 0; j < 4; ++j) {
          int col = bn + bn4 + j;
          v[j] = (col < N) ? src[j] : 0.f;
        }
      }
#pragma unroll
      for (int j = 0; j < 4; ++j) {
        unsigned short hh, ll; split1(v[j], hh, ll);
        Bh[(bn4 + j) * LDK + kr] = hh;
        Bl[(bn4 + j) * LDK + kr] = ll;
      }
    }
    __syncthreads();

    const int fr = lane & 15;
    const int kg = (lane >> 4) << 3;
    u16x8 a_h[4], a_l[4], b_h[4], b_l[4];
#pragma unroll
    for (int i = 0; i < 4; ++i) {
      a_h[i] = *(const u16x8*)(&Ah[(wm + i * 16 + fr) * LDK + kg]);
      a_l[i] = *(const u16x8*)(&Al[(wm + i * 16 + fr) * LDK + kg]);
      b_h[i] = *(const u16x8*)(&Bh[(wn + i * 16 + fr) * LDK + kg]);
      b_l[i] = *(const u16x8*)(&Bl[(wn + i * 16 + fr) * LDK + kg]);
    }
#pragma unroll
    for (int i = 0; i < 4; ++i)
#pragma unroll
      for (int j = 0; j < 4; ++j) {
        acc[i][j] = __builtin_amdgcn_mfma_f32_16x16x32_bf16(
            __builtin_bit_cast(bf16x8, a_h[i]), __builtin_bit_cast(bf16x8, b_h[j]), acc[i][j], 0, 0, 0);
        acc[i][j] = __builtin_amdgcn_mfma_f32_16x16x32_bf16(
            __builtin_bit_cast(bf16x8, a_h[i]), __builtin_bit_cast(bf16x8, b_l[j]), acc[i][j], 0, 0, 0);
        acc[i][j] = __builtin_amdgcn_mfma_f32_16x16x32_bf16(
            __builtin_bit_cast(bf16x8, a_l[i]), __builtin_bit_cast(bf16x8, b_h[j]), acc[i][j], 0, 0, 0);
      }
    __syncthreads();
  }
  const int cc = lane & 15;
  const int rg = (lane >> 4) << 2;
#pragma unroll
  for (int i = 0; i < 4; ++i)
#pragma unroll
    for (int j = 0; j < 4; ++j)
#pragma unroll
      for (int r = 0; r < 4; ++r) {
        int row = bm + wm + i * 16 + rg + r;
        int col = bn + wn + j * 16 + cc;
        if (col < N) {
          float v = acc[i][j][r];
          if (bias) v += bias[col];
          C[(size_t)row * N + col] = v;
        }
      }
}

// ---------- persistent LSTM recurrence (cooperative, weights in VGPRs) ----------
// Grid 256 WGs x 256 thr. WG w owns units [4w,4w+4) -> 16 weight cols (unit-major,
// gate-minor: local col c = i*4+g -> global col g*1024 + 4w+i). Wave v owns k-range
// [256v,256v+256): 8 MFMA k-steps. Two-level cumulative barrier per step.
static __device__ __forceinline__ void gbar(unsigned* bar, unsigned target, int gi, int tid) {
  __syncthreads();
  if (tid == 0) {
    unsigned r = __hip_atomic_fetch_add(&bar[16 + gi * 16], 1u, __ATOMIC_ACQ_REL, __HIP_MEMORY_SCOPE_AGENT);
    if ((r & 15u) == 15u)
      __hip_atomic_fetch_add(&bar[0], 1u, __ATOMIC_RELEASE, __HIP_MEMORY_SCOPE_AGENT);
    while (__hip_atomic_load(&bar[0], __ATOMIC_RELAXED, __HIP_MEMORY_SCOPE_AGENT) < target)
      __builtin_amdgcn_s_sleep(2);
    __builtin_amdgcn_fence(__ATOMIC_ACQUIRE, "agent");
  }
  __syncthreads();
}

__global__ __launch_bounds__(256) void lstm_persistent(
    const float* __restrict__ whT,   // [4096 cols][1024 k] this layer
    const float* __restrict__ xw,    // [256][16][4096]
    const float* __restrict__ bh,    // [4096]
    const float* __restrict__ h0,    // [16][1024]  (hidden[l][0])
    const float* __restrict__ c0,    // [16][1024]  (hidden[l][1])
    float* __restrict__ hpp,         // [2][16][1024] ping-pong
    float* __restrict__ ys,          // [256][16][1024]
    float* __restrict__ hfin, float* __restrict__ cfin,
    unsigned* __restrict__ bar, unsigned base) {
  __shared__ float red[4][16][16];
  const int tid  = threadIdx.x;
  const int lane = tid & 63;
  const int wave = tid >> 6;
  const int bid  = blockIdx.x;
  const int gi   = bid >> 4;
  const int lc   = lane & 15;          // A-row (batch) and B-col (local col)
  const int kg8  = (lane >> 4) << 3;   // k sub-offset within a 32-k step
  const int wk   = wave << 8;          // wave k-base

  // B-frags: weights, split bf16, loaded once into VGPRs
  const int gcol = (lc & 3) * 1024 + (bid << 2) + (lc >> 2);
  bf16x8 w_h[8], w_l[8];
#pragma unroll
  for (int kk = 0; kk < 8; ++kk) {
    const float* src = whT + ((size_t)gcol << 10) + (wk + (kk << 5) + kg8);
    f32x4 v0 = *(const f32x4*)src;
    f32x4 v1 = *(const f32x4*)(src + 4);
    u16x8 h8, l8;
#pragma unroll
    for (int j = 0; j < 4; ++j) {
      unsigned short hh, ll;
      split1(v0[j], hh, ll); h8[j] = hh;     l8[j] = ll;
      split1(v1[j], hh, ll); h8[4 + j] = hh; l8[4 + j] = ll;
    }
    w_h[kk] = __builtin_bit_cast(bf16x8, h8);
    w_l[kk] = __builtin_bit_cast(bf16x8, l8);
  }

  // activation-thread state (tid<64): (batch ab, unit-local ai)
  const int ab = tid & 15;
  const int ai = tid >> 4;             // valid when tid<64
  const int au = (bid << 2) + (ai & 3);
  float c_reg = 0.f, h_keep = 0.f;
  if (tid < 64) c_reg = c0[(ab << 10) + au];

  for (int s = 0; s < 256; ++s) {
    const float* hsrc = (s == 0) ? h0 : (hpp + ((s & 1) << 14));
    f32x4 acc0 = {}, acc1 = {}, acc2 = {};   // 3 independent split-term chains
#pragma unroll
    for (int kk = 0; kk < 8; ++kk) {
      const float* hp = hsrc + (lc << 10) + (wk + (kk << 5) + kg8);
      f32x4 v0 = *(const f32x4*)hp;
      f32x4 v1 = *(const f32x4*)(hp + 4);
      u16x8 h8, l8;
#pragma unroll
      for (int j = 0; j < 4; ++j) {
        unsigned short hh, ll;
        split1(v0[j], hh, ll); h8[j] = hh;     l8[j] = ll;
        split1(v1[j], hh, ll); h8[4 + j] = hh; l8[4 + j] = ll;
      }
      bf16x8 ah = __builtin_bit_cast(bf16x8, h8);
      bf16x8 al = __builtin_bit_cast(bf16x8, l8);
      acc0 = __builtin_amdgcn_mfma_f32_16x16x32_bf16(ah, w_h[kk], acc0, 0, 0, 0);
      acc1 = __builtin_amdgcn_mfma_f32_16x16x32_bf16(ah, w_l[kk], acc1, 0, 0, 0);
      acc2 = __builtin_amdgcn_mfma_f32_16x16x32_bf16(al, w_h[kk], acc2, 0, 0, 0);
    }
    f32x4 a = acc0 + acc1 + acc2;
#pragma unroll
    for (int r = 0; r < 4; ++r) red[wave][(lane >> 4) * 4 + r][lc] = a[r];
    __syncthreads();
    if (tid < 64) {
      float pre[4];
#pragma unroll
      for (int g = 0; g < 4; ++g) {
        int c = (ai << 2) + g;
        float p = red[0][ab][c] + red[1][ab][c] + red[2][ab][c] + red[3][ab][c];
        p += xw[((size_t)s << 16) + (ab << 12) + (g << 10) + au] + bh[(g << 10) + au];
        pre[g] = p;
      }
      float f  = 1.f / (1.f + expf(-pre[0]));
      float i_ = 1.f / (1.f + expf(-pre[1]));
      float o  = 1.f / (1.f + expf(-pre[2]));
      float g_ = tanhf(pre[3]);
      c_reg = f * c_reg + i_ * g_;
      float h = o * tanhf(c_reg);
      h_keep = h;
      hpp[(((s + 1) & 1) << 14) + (ab << 10) + au] = h;
      ys[((size_t)s << 14) + (ab << 10) + au] = h;
    }
    gbar(bar, (base + (unsigned)s + 1u) << 4, gi, tid);
  }
  if (tid < 64) {
    hfin[(ab << 10) + au] = h_keep;
    cfin[(ab << 10) + au] = c_reg;
  }
}

// ---------- small utility kernels ----------
__global__ __launch_bounds__(256) void embed_gather(
    const int* __restrict__ tokens, const float* __restrict__ emb, float* __restrict__ x) {
  int sb = blockIdx.x;
  int tok = tokens[sb];
  const f32x4* src = (const f32x4*)(emb + (size_t)tok * 1024);
  f32x4* dst = (f32x4*)(x + (size_t)sb * 1024);
  dst[threadIdx.x] = src[threadIdx.x];
}

__global__ void transpose_wh(const float* __restrict__ wh, float* __restrict__ whT) {
  __shared__ float tile[32][33];
  int l = blockIdx.z;
  int c0 = blockIdx.x << 5;
  int k0 = blockIdx.y << 5;
  int tx = threadIdx.x, ty = threadIdx.y;  // 32 x 8
  const float* src = wh + ((size_t)l << 22);
  float* dst = whT + ((size_t)l << 22);
#pragma unroll
  for (int i = 0; i < 32; i += 8)
    tile[ty + i][tx] = src[(size_t)(k0 + ty + i) * 4096 + c0 + tx];
  __syncthreads();
#pragma unroll
  for (int i = 0; i < 32; i += 8)
    dst[(size_t)(c0 + ty + i) * 1024 + k0 + tx] = tile[tx][ty + i];
}

// ---------- host ----------
extern "C" void kernel_launch(void* const* d_in, const int* in_sizes, int n_in,
                              void* d_out, int out_size, void* d_ws, size_t ws_size,
                              hipStream_t stream) {
  (void)in_sizes; (void)n_in; (void)out_size; (void)ws_size;
  const int*   tokens    = (const int*)  d_in[0];
  const float* hidden    = (const float*)d_in[1];
  const float* embedding = (const float*)d_in[2];
  const float* wi        = (const float*)d_in[3];
  const float* bi        = (const float*)d_in[4];
  const float* wh        = (const float*)d_in[5];
  const float* bh        = (const float*)d_in[6];
  const float* wdec      = (const float*)d_in[7];
  const float* bdec      = (const float*)d_in[8];

  float* out     = (float*)d_out;
  float* out_res = out;                                   // 256*16*50257
  float* out_nh  = out + (size_t)205852672;               // 2*2*16*1024
  float* out_x   = out + (size_t)205852672 + 65536;       // 256*16*1024

  // workspace layout (floats)
  float* ws    = (float*)d_ws;
  float* whT   = ws;                        // 2*4096*1024 = 8388608
  float* x_emb = whT   + 8388608;           // 4096*1024   = 4194304
  float* xwb   = x_emb + 4194304;           // 4096*4096   = 16777216
  float* ys0   = xwb   + 16777216;          // 4096*1024   = 4194304
  float* hpp   = ys0   + 4194304;           // 2*16*1024   = 32768
  unsigned* bar = (unsigned*)(hpp + 32768); // 16 + 16*16 u32 (pad 1024)

  hipMemsetAsync(bar, 0, 1024 * sizeof(unsigned), stream);
  transpose_wh<<<dim3(128, 32, 2), dim3(32, 8), 0, stream>>>(wh, whT);
  embed_gather<<<4096, 256, 0, stream>>>(tokens, embedding, x_emb);

  for (int l = 0; l < 2; ++l) {
    const float* a = (l == 0) ? x_emb : ys0;
    gemm_split3<<<dim3(32, 32), 256, 0, stream>>>(
        a, wi + (size_t)l * 4194304, bi + l * 4096, xwb, 4096, 4096, 1024);

    const float* wT   = whT + (size_t)l * 4194304;
    const float* xwp  = xwb;
    const float* bhl  = bh + l * 4096;
    const float* h0p  = hidden + (size_t)l * 32768;
    const float* c0p  = h0p + 16384;
    float* hppp = hpp;
    float* ysp  = (l == 0) ? ys0 : out_x;
    float* hfin = out_nh + (size_t)l * 32768;
    float* cfin = hfin + 16384;
    unsigned basev = (unsigned)(l * 256);
    unsigned* barp = bar;
    void* args[] = { &wT, &xwp, &bhl, &h0p, &c0p, &hppp, &ysp, &hfin, &cfin, &barp, &basev };
    hipLaunchCooperativeKernel((const void*)lstm_persistent,
                               dim3(256), dim3(256), args, 0, stream);
  }
  gemm_split3<<<dim3(32, 393), 256, 0, stream>>>(
      out_x, wdec, bdec, out_res, 4096, 50257, 1024);
}

// Round 3
// 11501.044 us; speedup vs baseline: 1.4226x; 1.0752x over previous
//
#include <hip/hip_runtime.h>

// ---------- types ----------
typedef float  f32x4  __attribute__((ext_vector_type(4)));
typedef unsigned short u16x4 __attribute__((ext_vector_type(4)));
typedef unsigned short u16x8 __attribute__((ext_vector_type(8)));
typedef __bf16 bf16x8 __attribute__((ext_vector_type(8)));

// round-to-nearest-even f32 -> bf16 (bit trick)
static __device__ __forceinline__ unsigned short bf16_rn(float x) {
  unsigned u = __builtin_bit_cast(unsigned, x);
  unsigned r = (u + 0x7FFFu + ((u >> 16) & 1u)) >> 16;
  return (unsigned short)r;
}
// split x ~= hi + lo (each bf16); residual ~2^-17 relative
static __device__ __forceinline__ void split1(float x, unsigned short& h, unsigned short& l) {
  unsigned short hh = bf16_rn(x);
  float hf = __builtin_bit_cast(float, ((unsigned)hh) << 16);
  h = hh;
  l = bf16_rn(x - hf);
}

// ---------- GEMM: C = A(f32,MxK) * B(f32,KxN) + bias, via split-bf16 3-term MFMA ----------
#define BM 128
#define BN 128
#define BK 32
#define LDK 40  // padded LDS row (bf16 elems)

__global__ __launch_bounds__(256) void gemm_split3(
    const float* __restrict__ A, const float* __restrict__ B,
    const float* __restrict__ bias, float* __restrict__ C,
    int M, int N, int K) {
  __shared__ unsigned short Ah[BM * LDK];
  __shared__ unsigned short Al[BM * LDK];
  __shared__ unsigned short Bh[BN * LDK];
  __shared__ unsigned short Bl[BN * LDK];

  const int tid  = threadIdx.x;
  const int lane = tid & 63;
  const int wave = tid >> 6;
  const int bm = blockIdx.x * BM;
  const int bn = blockIdx.y * BN;
  const int wm = (wave >> 1) * 64;
  const int wn = (wave & 1) * 64;
  const bool nvec = ((N & 3) == 0);

  f32x4 acc[4][4] = {};

  const int ar  = tid >> 3;
  const int ak  = (tid & 7) << 2;
  const int bk  = tid >> 5;
  const int bn4 = (tid & 31) << 2;

  for (int k0 = 0; k0 < K; k0 += BK) {
#pragma unroll
    for (int p = 0; p < 4; ++p) {
      int r = ar + (p << 5);
      f32x4 v = *(const f32x4*)(A + (size_t)(bm + r) * K + (k0 + ak));
      u16x4 h, l;
#pragma unroll
      for (int j = 0; j < 4; ++j) { unsigned short hh, ll; split1(v[j], hh, ll); h[j] = hh; l[j] = ll; }
      *(u16x4*)(&Ah[r * LDK + ak]) = h;
      *(u16x4*)(&Al[r * LDK + ak]) = l;
    }
#pragma unroll
    for (int p = 0; p < 4; ++p) {
      int kr = bk + (p << 3);
      const float* src = B + (size_t)(k0 + kr) * N + (bn + bn4);
      float v[4];
      if (nvec) {
        f32x4 t4 = *(const f32x4*)src;
        v[0] = t4.x; v[1] = t4.y; v[2] = t4.z; v[3] = t4.w;
      } else {
#pragma unroll
        for (int j = 0; j < 4; ++j) {
          int col = bn + bn4 + j;
          v[j] = (col < N) ? src[j] : 0.f;
        }
      }
#pragma unroll
      for (int j = 0; j < 4; ++j) {
        unsigned short hh, ll; split1(v[j], hh, ll);
        Bh[(bn4 + j) * LDK + kr] = hh;
        Bl[(bn4 + j) * LDK + kr] = ll;
      }
    }
    __syncthreads();

    const int fr = lane & 15;
    const int kg = (lane >> 4) << 3;
    u16x8 a_h[4], a_l[4], b_h[4], b_l[4];
#pragma unroll
    for (int i = 0; i < 4; ++i) {
      a_h[i] = *(const u16x8*)(&Ah[(wm + i * 16 + fr) * LDK + kg]);
      a_l[i] = *(const u16x8*)(&Al[(wm + i * 16 + fr) * LDK + kg]);
      b_h[i] = *(const u16x8*)(&Bh[(wn + i * 16 + fr) * LDK + kg]);
      b_l[i] = *(const u16x8*)(&Bl[(wn + i * 16 + fr) * LDK + kg]);
    }
#pragma unroll
    for (int i = 0; i < 4; ++i)
#pragma unroll
      for (int j = 0; j < 4; ++j) {
        acc[i][j] = __builtin_amdgcn_mfma_f32_16x16x32_bf16(
            __builtin_bit_cast(bf16x8, a_h[i]), __builtin_bit_cast(bf16x8, b_h[j]), acc[i][j], 0, 0, 0);
        acc[i][j] = __builtin_amdgcn_mfma_f32_16x16x32_bf16(
            __builtin_bit_cast(bf16x8, a_h[i]), __builtin_bit_cast(bf16x8, b_l[j]), acc[i][j], 0, 0, 0);
        acc[i][j] = __builtin_amdgcn_mfma_f32_16x16x32_bf16(
            __builtin_bit_cast(bf16x8, a_l[i]), __builtin_bit_cast(bf16x8, b_h[j]), acc[i][j], 0, 0, 0);
      }
    __syncthreads();
  }
  const int cc = lane & 15;
  const int rg = (lane >> 4) << 2;
#pragma unroll
  for (int i = 0; i < 4; ++i)
#pragma unroll
    for (int j = 0; j < 4; ++j)
#pragma unroll
      for (int r = 0; r < 4; ++r) {
        int row = bm + wm + i * 16 + rg + r;
        int col = bn + wn + j * 16 + cc;
        if (col < N) {
          float v = acc[i][j][r];
          if (bias) v += bias[col];
          C[(size_t)row * N + col] = v;
        }
      }
}

// ---------- hierarchical grid barrier ----------
// bar layout (u32): [0]=root, [64+gi*64]=leaf counter gi, [2048+gi*64]=group flag gi.
// 256 WGs = 16 groups x 16 members. Arrival: leaf (16 RMWs/line) -> root (16 RMWs/line).
// Broadcast: rep (m==0) polls root (16 pollers), release-stores gflag[gi]; members poll
// their gflag line (15 pollers). Transitive release/acquire gives h visibility.
static __device__ __forceinline__ void gbar(unsigned* bar, unsigned e, int gi, int m, int tid) {
  __syncthreads();
  if (tid == 0) {
    unsigned r = __hip_atomic_fetch_add(&bar[64 + gi * 64], 1u, __ATOMIC_RELEASE, __HIP_MEMORY_SCOPE_AGENT);
    if ((r & 15u) == 15u)
      __hip_atomic_fetch_add(&bar[0], 1u, __ATOMIC_ACQ_REL, __HIP_MEMORY_SCOPE_AGENT);
    if (m == 0) {
      while (__hip_atomic_load(&bar[0], __ATOMIC_RELAXED, __HIP_MEMORY_SCOPE_AGENT) < (e << 4))
        __builtin_amdgcn_s_sleep(2);
      __builtin_amdgcn_fence(__ATOMIC_ACQUIRE, "agent");
      __hip_atomic_store(&bar[2048 + gi * 64], e, __ATOMIC_RELEASE, __HIP_MEMORY_SCOPE_AGENT);
    } else {
      while (__hip_atomic_load(&bar[2048 + gi * 64], __ATOMIC_RELAXED, __HIP_MEMORY_SCOPE_AGENT) < e)
        __builtin_amdgcn_s_sleep(2);
      __builtin_amdgcn_fence(__ATOMIC_ACQUIRE, "agent");
    }
  }
  __syncthreads();
}

// ---------- persistent LSTM recurrence (cooperative, weights in VGPRs) ----------
__global__ __launch_bounds__(256) void lstm_persistent(
    const float* __restrict__ whT,   // [4096 cols][1024 k] this layer
    const float* __restrict__ xw,    // [256][16][4096]
    const float* __restrict__ bh,    // [4096]
    const float* __restrict__ h0,
    const float* __restrict__ c0,
    float* __restrict__ hpp,         // [2][16][1024] ping-pong
    float* __restrict__ ys,          // [256][16][1024]
    float* __restrict__ hfin, float* __restrict__ cfin,
    unsigned* __restrict__ bar, unsigned base) {
  __shared__ float red[4][16][16];
  const int tid  = threadIdx.x;
  const int lane = tid & 63;
  const int wave = tid >> 6;
  const int bid  = blockIdx.x;
  const int gi   = bid >> 4;
  const int gm   = bid & 15;
  const int lc   = lane & 15;
  const int kg8  = (lane >> 4) << 3;
  const int wk   = wave << 8;

  // B-frags: weights, split bf16, loaded once into VGPRs
  const int gcol = (lc & 3) * 1024 + (bid << 2) + (lc >> 2);
  bf16x8 w_h[8], w_l[8];
#pragma unroll
  for (int kk = 0; kk < 8; ++kk) {
    const float* src = whT + ((size_t)gcol << 10) + (wk + (kk << 5) + kg8);
    f32x4 v0 = *(const f32x4*)src;
    f32x4 v1 = *(const f32x4*)(src + 4);
    u16x8 h8, l8;
#pragma unroll
    for (int j = 0; j < 4; ++j) {
      unsigned short hh, ll;
      split1(v0[j], hh, ll); h8[j] = hh;     l8[j] = ll;
      split1(v1[j], hh, ll); h8[4 + j] = hh; l8[4 + j] = ll;
    }
    w_h[kk] = __builtin_bit_cast(bf16x8, h8);
    w_l[kk] = __builtin_bit_cast(bf16x8, l8);
  }

  // activation-thread state (tid<64): (batch ab, unit-local ai)
  const int ab = tid & 15;
  const int ai = tid >> 4;
  const int au = (bid << 2) + (ai & 3);
  float c_reg = 0.f, h_keep = 0.f;
  float bhv[4], xwv[4];
  if (tid < 64) {
    c_reg = c0[(ab << 10) + au];
#pragma unroll
    for (int g = 0; g < 4; ++g) bhv[g] = bh[(g << 10) + au];        // loop-invariant
#pragma unroll
    for (int g = 0; g < 4; ++g) xwv[g] = xw[(ab << 12) + (g << 10) + au];  // s=0 prefetch
  }

  for (int s = 0; s < 256; ++s) {
    const float* hsrc = (s == 0) ? h0 : (hpp + ((s & 1) << 14));
    f32x4 acc0 = {}, acc1 = {}, acc2 = {};
#pragma unroll
    for (int kk = 0; kk < 8; ++kk) {
      const float* hp = hsrc + (lc << 10) + (wk + (kk << 5) + kg8);
      f32x4 v0 = *(const f32x4*)hp;
      f32x4 v1 = *(const f32x4*)(hp + 4);
      u16x8 h8, l8;
#pragma unroll
      for (int j = 0; j < 4; ++j) {
        unsigned short hh, ll;
        split1(v0[j], hh, ll); h8[j] = hh;     l8[j] = ll;
        split1(v1[j], hh, ll); h8[4 + j] = hh; l8[4 + j] = ll;
      }
      bf16x8 ah = __builtin_bit_cast(bf16x8, h8);
      bf16x8 al = __builtin_bit_cast(bf16x8, l8);
      acc0 = __builtin_amdgcn_mfma_f32_16x16x32_bf16(ah, w_h[kk], acc0, 0, 0, 0);
      acc1 = __builtin_amdgcn_mfma_f32_16x16x32_bf16(ah, w_l[kk], acc1, 0, 0, 0);
      acc2 = __builtin_amdgcn_mfma_f32_16x16x32_bf16(al, w_h[kk], acc2, 0, 0, 0);
    }
    f32x4 a = acc0 + acc1 + acc2;
#pragma unroll
    for (int r = 0; r < 4; ++r) red[wave][(lane >> 4) * 4 + r][lc] = a[r];
    __syncthreads();
    if (tid < 64) {
      float pre[4];
#pragma unroll
      for (int g = 0; g < 4; ++g) {
        int c = (ai << 2) + g;
        pre[g] = red[0][ab][c] + red[1][ab][c] + red[2][ab][c] + red[3][ab][c]
               + xwv[g] + bhv[g];
      }
      float f  = 1.f / (1.f + expf(-pre[0]));
      float i_ = 1.f / (1.f + expf(-pre[1]));
      float o  = 1.f / (1.f + expf(-pre[2]));
      float g_ = tanhf(pre[3]);
      c_reg = f * c_reg + i_ * g_;
      float h = o * tanhf(c_reg);
      h_keep = h;
      hpp[(((s + 1) & 1) << 14) + (ab << 10) + au] = h;
      ys[((size_t)s << 14) + (ab << 10) + au] = h;
      if (s < 255) {   // prefetch next xw; in flight across the barrier wait
        const float* xn = xw + ((size_t)(s + 1) << 16);
#pragma unroll
        for (int g = 0; g < 4; ++g) xwv[g] = xn[(ab << 12) + (g << 10) + au];
      }
    }
    gbar(bar, base + (unsigned)s + 1u, gi, gm, tid);
  }
  if (tid < 64) {
    hfin[(ab << 10) + au] = h_keep;
    cfin[(ab << 10) + au] = c_reg;
  }
}

// ---------- small utility kernels ----------
__global__ __launch_bounds__(256) void embed_gather(
    const int* __restrict__ tokens, const float* __restrict__ emb, float* __restrict__ x) {
  int sb = blockIdx.x;
  int tok = tokens[sb];
  const f32x4* src = (const f32x4*)(emb + (size_t)tok * 1024);
  f32x4* dst = (f32x4*)(x + (size_t)sb * 1024);
  dst[threadIdx.x] = src[threadIdx.x];
}

__global__ void transpose_wh(const float* __restrict__ wh, float* __restrict__ whT) {
  __shared__ float tile[32][33];
  int l = blockIdx.z;
  int c0 = blockIdx.x << 5;
  int k0 = blockIdx.y << 5;
  int tx = threadIdx.x, ty = threadIdx.y;  // 32 x 8
  const float* src = wh + ((size_t)l << 22);
  float* dst = whT + ((size_t)l << 22);
#pragma unroll
  for (int i = 0; i < 32; i += 8)
    tile[ty + i][tx] = src[(size_t)(k0 + ty + i) * 4096 + c0 + tx];
  __syncthreads();
#pragma unroll
  for (int i = 0; i < 32; i += 8)
    dst[(size_t)(c0 + ty + i) * 1024 + k0 + tx] = tile[tx][ty + i];
}

// ---------- host ----------
extern "C" void kernel_launch(void* const* d_in, const int* in_sizes, int n_in,
                              void* d_out, int out_size, void* d_ws, size_t ws_size,
                              hipStream_t stream) {
  (void)in_sizes; (void)n_in; (void)out_size; (void)ws_size;
  const int*   tokens    = (const int*)  d_in[0];
  const float* hidden    = (const float*)d_in[1];
  const float* embedding = (const float*)d_in[2];
  const float* wi        = (const float*)d_in[3];
  const float* bi        = (const float*)d_in[4];
  const float* wh        = (const float*)d_in[5];
  const float* bh        = (const float*)d_in[6];
  const float* wdec      = (const float*)d_in[7];
  const float* bdec      = (const float*)d_in[8];

  float* out     = (float*)d_out;
  float* out_res = out;                                   // 256*16*50257
  float* out_nh  = out + (size_t)205852672;               // 2*2*16*1024
  float* out_x   = out + (size_t)205852672 + 65536;       // 256*16*1024

  // workspace layout (floats)
  float* ws    = (float*)d_ws;
  float* whT   = ws;                        // 2*4096*1024 = 8388608
  float* x_emb = whT   + 8388608;           // 4096*1024   = 4194304
  float* xwb   = x_emb + 4194304;           // 4096*4096   = 16777216
  float* ys0   = xwb   + 16777216;          // 4096*1024   = 4194304
  float* hpp   = ys0   + 4194304;           // 2*16*1024   = 32768
  unsigned* bar = (unsigned*)(hpp + 32768); // 4096 u32 region

  hipMemsetAsync(bar, 0, 4096 * sizeof(unsigned), stream);
  transpose_wh<<<dim3(128, 32, 2), dim3(32, 8), 0, stream>>>(wh, whT);
  embed_gather<<<4096, 256, 0, stream>>>(tokens, embedding, x_emb);

  for (int l = 0; l < 2; ++l) {
    const float* a = (l == 0) ? x_emb : ys0;
    gemm_split3<<<dim3(32, 32), 256, 0, stream>>>(
        a, wi + (size_t)l * 4194304, bi + l * 4096, xwb, 4096, 4096, 1024);

    const float* wT   = whT + (size_t)l * 4194304;
    const float* xwp  = xwb;
    const float* bhl  = bh + l * 4096;
    const float* h0p  = hidden + (size_t)l * 32768;
    const float* c0p  = h0p + 16384;
    float* hppp = hpp;
    float* ysp  = (l == 0) ? ys0 : out_x;
    float* hfin = out_nh + (size_t)l * 32768;
    float* cfin = hfin + 16384;
    unsigned basev = (unsigned)(l * 256);
    unsigned* barp = bar;
    void* args[] = { &wT, &xwp, &bhl, &h0p, &c0p, &hppp, &ysp, &hfin, &cfin, &barp, &basev };
    hipLaunchCooperativeKernel((const void*)lstm_persistent,
                               dim3(256), dim3(256), args, 0, stream);
  }
  gemm_split3<<<dim3(32, 393), 256, 0, stream>>>(
      out_x, wdec, bdec, out_res, 4096, 50257, 1024);
}

// Round 4
// 10602.621 us; speedup vs baseline: 1.5431x; 1.0847x over previous
//
#include <hip/hip_runtime.h>

// ---------- types ----------
typedef float  f32x4  __attribute__((ext_vector_type(4)));
typedef unsigned short u16x4 __attribute__((ext_vector_type(4)));
typedef unsigned short u16x8 __attribute__((ext_vector_type(8)));
typedef __bf16 bf16x8 __attribute__((ext_vector_type(8)));

// round-to-nearest-even f32 -> bf16 (bit trick)
static __device__ __forceinline__ unsigned short bf16_rn(float x) {
  unsigned u = __builtin_bit_cast(unsigned, x);
  unsigned r = (u + 0x7FFFu + ((u >> 16) & 1u)) >> 16;
  return (unsigned short)r;
}
// split x ~= hi + lo (each bf16); residual ~2^-17 relative
static __device__ __forceinline__ void split1(float x, unsigned short& h, unsigned short& l) {
  unsigned short hh = bf16_rn(x);
  float hf = __builtin_bit_cast(float, ((unsigned)hh) << 16);
  h = hh;
  l = bf16_rn(x - hf);
}

// ---------- GEMM: C = A(f32,MxK) * B(f32,KxN) + bias, split-bf16 3-term MFMA ----------
#define BM 128
#define BN 128
#define BK 32
#define LDK 40

// XOR-swizzled LDS index: 16B chunks permuted by row. Breaks the 16-way
// bank conflict of transposed B writes (row stride 4 = 16 banks) -> ~4-way,
// keeps 16B alignment for ds_read_b128 fragment reads.
static __device__ __forceinline__ int lds_idx(int row, int k) {
  return row * LDK + ((((k >> 3) ^ (row >> 2)) & 3) << 3) + (k & 7);
}

__global__ __launch_bounds__(256) void gemm_split3(
    const float* __restrict__ A, const float* __restrict__ B,
    const float* __restrict__ bias, float* __restrict__ C,
    int M, int N, int K) {
  __shared__ unsigned short Ah[BM * LDK];
  __shared__ unsigned short Al[BM * LDK];
  __shared__ unsigned short Bh[BN * LDK];
  __shared__ unsigned short Bl[BN * LDK];

  const int tid  = threadIdx.x;
  const int lane = tid & 63;
  const int wave = tid >> 6;
  const int bm = blockIdx.x * BM;
  const int bn = blockIdx.y * BN;
  const int wm = (wave >> 1) * 64;
  const int wn = (wave & 1) * 64;
  const bool nvec = ((N & 3) == 0);

  f32x4 acc[4][4] = {};

  const int ar  = tid >> 3;
  const int ak  = (tid & 7) << 2;
  const int bk  = tid >> 5;
  const int bn4 = (tid & 31) << 2;

  for (int k0 = 0; k0 < K; k0 += BK) {
#pragma unroll
    for (int p = 0; p < 4; ++p) {
      int r = ar + (p << 5);
      f32x4 v = *(const f32x4*)(A + (size_t)(bm + r) * K + (k0 + ak));
      u16x4 h, l;
#pragma unroll
      for (int j = 0; j < 4; ++j) { unsigned short hh, ll; split1(v[j], hh, ll); h[j] = hh; l[j] = ll; }
      int ix = lds_idx(r, ak);
      *(u16x4*)(&Ah[ix]) = h;
      *(u16x4*)(&Al[ix]) = l;
    }
#pragma unroll
    for (int p = 0; p < 4; ++p) {
      int kr = bk + (p << 3);
      const float* src = B + (size_t)(k0 + kr) * N + (bn + bn4);
      float v[4];
      if (nvec) {
        f32x4 t4 = *(const f32x4*)src;
        v[0] = t4.x; v[1] = t4.y; v[2] = t4.z; v[3] = t4.w;
      } else {
#pragma unroll
        for (int j = 0; j < 4; ++j) {
          int col = bn + bn4 + j;
          v[j] = (col < N) ? src[j] : 0.f;
        }
      }
#pragma unroll
      for (int j = 0; j < 4; ++j) {
        unsigned short hh, ll; split1(v[j], hh, ll);
        int ix = lds_idx(bn4 + j, kr);
        Bh[ix] = hh;
        Bl[ix] = ll;
      }
    }
    __syncthreads();

    const int fr = lane & 15;
    const int kg = (lane >> 4) << 3;
    u16x8 a_h[4], a_l[4], b_h[4], b_l[4];
#pragma unroll
    for (int i = 0; i < 4; ++i) {
      int ia = lds_idx(wm + i * 16 + fr, kg);
      int ib = lds_idx(wn + i * 16 + fr, kg);
      a_h[i] = *(const u16x8*)(&Ah[ia]);
      a_l[i] = *(const u16x8*)(&Al[ia]);
      b_h[i] = *(const u16x8*)(&Bh[ib]);
      b_l[i] = *(const u16x8*)(&Bl[ib]);
    }
#pragma unroll
    for (int i = 0; i < 4; ++i)
#pragma unroll
      for (int j = 0; j < 4; ++j) {
        acc[i][j] = __builtin_amdgcn_mfma_f32_16x16x32_bf16(
            __builtin_bit_cast(bf16x8, a_h[i]), __builtin_bit_cast(bf16x8, b_h[j]), acc[i][j], 0, 0, 0);
        acc[i][j] = __builtin_amdgcn_mfma_f32_16x16x32_bf16(
            __builtin_bit_cast(bf16x8, a_h[i]), __builtin_bit_cast(bf16x8, b_l[j]), acc[i][j], 0, 0, 0);
        acc[i][j] = __builtin_amdgcn_mfma_f32_16x16x32_bf16(
            __builtin_bit_cast(bf16x8, a_l[i]), __builtin_bit_cast(bf16x8, b_h[j]), acc[i][j], 0, 0, 0);
      }
    __syncthreads();
  }
  const int cc = lane & 15;
  const int rg = (lane >> 4) << 2;
#pragma unroll
  for (int i = 0; i < 4; ++i)
#pragma unroll
    for (int j = 0; j < 4; ++j)
#pragma unroll
      for (int r = 0; r < 4; ++r) {
        int row = bm + wm + i * 16 + rg + r;
        int col = bn + wn + j * 16 + cc;
        if (col < N) {
          float v = acc[i][j][r];
          if (bias) v += bias[col];
          C[(size_t)row * N + col] = v;
        }
      }
}

// ---------- distributed-flag grid barrier (no atomic RMW) ----------
// flags[256]: one epoch per WG. Publish: release fence + relaxed store by wave0
// lane0 (h producers ARE wave0 -> wave-level vmcnt covers their stores).
// Detect: wave0 lanes load 4 flags each, __all-ballot, acquire fence.
static __device__ __forceinline__ void poll_flags(const unsigned* flags, unsigned tgt, int lane) {
  for (;;) {
    unsigned v0 = __hip_atomic_load(flags + lane,       __ATOMIC_RELAXED, __HIP_MEMORY_SCOPE_AGENT);
    unsigned v1 = __hip_atomic_load(flags + 64 + lane,  __ATOMIC_RELAXED, __HIP_MEMORY_SCOPE_AGENT);
    unsigned v2 = __hip_atomic_load(flags + 128 + lane, __ATOMIC_RELAXED, __HIP_MEMORY_SCOPE_AGENT);
    unsigned v3 = __hip_atomic_load(flags + 192 + lane, __ATOMIC_RELAXED, __HIP_MEMORY_SCOPE_AGENT);
    unsigned m01 = v0 < v1 ? v0 : v1;
    unsigned m23 = v2 < v3 ? v2 : v3;
    unsigned mn  = m01 < m23 ? m01 : m23;
    if (__all((int)(mn >= tgt))) break;
    __builtin_amdgcn_s_sleep(4);
  }
}

// ---------- persistent LSTM recurrence (cooperative, weights in VGPRs) ----------
// h ping-pong is stored PRE-SPLIT (bf16 hi/lo) by the producer; consumers load
// MFMA A-fragments directly (no per-consumer split VALU on the critical path).
__global__ __launch_bounds__(256) void lstm_persistent(
    const float* __restrict__ whT,   // [4096 cols][1024 k] this layer
    const float* __restrict__ xw,    // [256][16][4096]
    const float* __restrict__ bh,    // [4096]
    const float* __restrict__ h0,    // [16][1024]
    const float* __restrict__ c0,    // [16][1024]
    unsigned short* __restrict__ hppH,  // [2][16][1024] bf16-hi
    unsigned short* __restrict__ hppL,  // [2][16][1024] bf16-lo
    float* __restrict__ ys,          // [256][16][1024]
    float* __restrict__ hfin, float* __restrict__ cfin,
    unsigned* __restrict__ flags, unsigned base) {
  __shared__ float red[4][16][16];
  const int tid  = threadIdx.x;
  const int lane = tid & 63;
  const int wave = tid >> 6;
  const int bid  = blockIdx.x;
  const int lc   = lane & 15;
  const int kg8  = (lane >> 4) << 3;
  const int wk   = wave << 8;

  // B-frags: weights, split bf16, loaded once into VGPRs
  const int gcol = (lc & 3) * 1024 + (bid << 2) + (lc >> 2);
  bf16x8 w_h[8], w_l[8];
#pragma unroll
  for (int kk = 0; kk < 8; ++kk) {
    const float* src = whT + ((size_t)gcol << 10) + (wk + (kk << 5) + kg8);
    f32x4 v0 = *(const f32x4*)src;
    f32x4 v1 = *(const f32x4*)(src + 4);
    u16x8 h8, l8;
#pragma unroll
    for (int j = 0; j < 4; ++j) {
      unsigned short hh, ll;
      split1(v0[j], hh, ll); h8[j] = hh;     l8[j] = ll;
      split1(v1[j], hh, ll); h8[4 + j] = hh; l8[4 + j] = ll;
    }
    w_h[kk] = __builtin_bit_cast(bf16x8, h8);
    w_l[kk] = __builtin_bit_cast(bf16x8, l8);
  }

  // activation-thread state (tid<64 == wave 0): (batch ab, unit-local ai)
  const int ab = tid & 15;
  const int ai = tid >> 4;
  const int au = (bid << 2) + (ai & 3);
  float c_reg = 0.f, h_keep = 0.f;
  float bhv[4], xwv[4];

  // prologue: stage split h0 into slot 0; epoch base+1 = "slot0 ready"
  if (tid < 64) {
    float h0v = h0[(ab << 10) + au];
    unsigned short hh, ll; split1(h0v, hh, ll);
    hppH[(ab << 10) + au] = hh;
    hppL[(ab << 10) + au] = ll;
    c_reg = c0[(ab << 10) + au];
#pragma unroll
    for (int g = 0; g < 4; ++g) bhv[g] = bh[(g << 10) + au];
#pragma unroll
    for (int g = 0; g < 4; ++g) xwv[g] = xw[(ab << 12) + (g << 10) + au];
  }
  if (wave == 0) {
    __builtin_amdgcn_fence(__ATOMIC_RELEASE, "agent");
    if (lane == 0)
      __hip_atomic_store(&flags[bid], base + 1u, __ATOMIC_RELAXED, __HIP_MEMORY_SCOPE_AGENT);
    poll_flags(flags, base + 1u, lane);
    __builtin_amdgcn_fence(__ATOMIC_ACQUIRE, "agent");
  }
  __syncthreads();

  for (int s = 0; s < 256; ++s) {
    const unsigned short* hH = hppH + ((s & 1) << 14);
    const unsigned short* hL = hppL + ((s & 1) << 14);
    f32x4 acc0 = {}, acc1 = {}, acc2 = {};
#pragma unroll
    for (int kk = 0; kk < 8; ++kk) {
      int off = (lc << 10) + wk + (kk << 5) + kg8;
      u16x8 ah8 = *(const u16x8*)(hH + off);
      u16x8 al8 = *(const u16x8*)(hL + off);
      bf16x8 ah = __builtin_bit_cast(bf16x8, ah8);
      bf16x8 al = __builtin_bit_cast(bf16x8, al8);
      acc0 = __builtin_amdgcn_mfma_f32_16x16x32_bf16(ah, w_h[kk], acc0, 0, 0, 0);
      acc1 = __builtin_amdgcn_mfma_f32_16x16x32_bf16(ah, w_l[kk], acc1, 0, 0, 0);
      acc2 = __builtin_amdgcn_mfma_f32_16x16x32_bf16(al, w_h[kk], acc2, 0, 0, 0);
    }
    f32x4 a = acc0 + acc1 + acc2;
#pragma unroll
    for (int r = 0; r < 4; ++r) red[wave][(lane >> 4) * 4 + r][lc] = a[r];
    __syncthreads();
    if (tid < 64) {
      float pre[4];
#pragma unroll
      for (int g = 0; g < 4; ++g) {
        int c = (ai << 2) + g;
        pre[g] = red[0][ab][c] + red[1][ab][c] + red[2][ab][c] + red[3][ab][c]
               + xwv[g] + bhv[g];
      }
      float f  = 1.f / (1.f + expf(-pre[0]));
      float i_ = 1.f / (1.f + expf(-pre[1]));
      float o  = 1.f / (1.f + expf(-pre[2]));
      float g_ = tanhf(pre[3]);
      c_reg = f * c_reg + i_ * g_;
      float h = o * tanhf(c_reg);
      h_keep = h;
      ys[((size_t)s << 14) + (ab << 10) + au] = h;
      unsigned short hh, ll; split1(h, hh, ll);
      int wslot = (((s + 1) & 1) << 14) + (ab << 10) + au;
      hppH[wslot] = hh;
      hppL[wslot] = ll;
    }
    // publish this step's h (epoch base+2+s), then prefetch, then wait for all
    if (wave == 0) {
      __builtin_amdgcn_fence(__ATOMIC_RELEASE, "agent");
      if (lane == 0)
        __hip_atomic_store(&flags[bid], base + 2u + (unsigned)s, __ATOMIC_RELAXED, __HIP_MEMORY_SCOPE_AGENT);
    }
    if (tid < 64 && s < 255) {
      const float* xn = xw + ((size_t)(s + 1) << 16);
#pragma unroll
      for (int g = 0; g < 4; ++g) xwv[g] = xn[(ab << 12) + (g << 10) + au];
    }
    if (wave == 0 && s < 255) {
      poll_flags(flags, base + 2u + (unsigned)s, lane);
      __builtin_amdgcn_fence(__ATOMIC_ACQUIRE, "agent");
    }
    __syncthreads();
  }
  if (tid < 64) {
    hfin[(ab << 10) + au] = h_keep;
    cfin[(ab << 10) + au] = c_reg;
  }
}

// ---------- small utility kernels ----------
__global__ __launch_bounds__(256) void embed_gather(
    const int* __restrict__ tokens, const float* __restrict__ emb, float* __restrict__ x) {
  int sb = blockIdx.x;
  int tok = tokens[sb];
  const f32x4* src = (const f32x4*)(emb + (size_t)tok * 1024);
  f32x4* dst = (f32x4*)(x + (size_t)sb * 1024);
  dst[threadIdx.x] = src[threadIdx.x];
}

__global__ void transpose_wh(const float* __restrict__ wh, float* __restrict__ whT) {
  __shared__ float tile[32][33];
  int l = blockIdx.z;
  int c0 = blockIdx.x << 5;
  int k0 = blockIdx.y << 5;
  int tx = threadIdx.x, ty = threadIdx.y;  // 32 x 8
  const float* src = wh + ((size_t)l << 22);
  float* dst = whT + ((size_t)l << 22);
#pragma unroll
  for (int i = 0; i < 32; i += 8)
    tile[ty + i][tx] = src[(size_t)(k0 + ty + i) * 4096 + c0 + tx];
  __syncthreads();
#pragma unroll
  for (int i = 0; i < 32; i += 8)
    dst[(size_t)(c0 + ty + i) * 1024 + k0 + tx] = tile[tx][ty + i];
}

// ---------- host ----------
extern "C" void kernel_launch(void* const* d_in, const int* in_sizes, int n_in,
                              void* d_out, int out_size, void* d_ws, size_t ws_size,
                              hipStream_t stream) {
  (void)in_sizes; (void)n_in; (void)out_size; (void)ws_size;
  const int*   tokens    = (const int*)  d_in[0];
  const float* hidden    = (const float*)d_in[1];
  const float* embedding = (const float*)d_in[2];
  const float* wi        = (const float*)d_in[3];
  const float* bi        = (const float*)d_in[4];
  const float* wh        = (const float*)d_in[5];
  const float* bh        = (const float*)d_in[6];
  const float* wdec      = (const float*)d_in[7];
  const float* bdec      = (const float*)d_in[8];

  float* out     = (float*)d_out;
  float* out_res = out;                                   // 256*16*50257
  float* out_nh  = out + (size_t)205852672;               // 2*2*16*1024
  float* out_x   = out + (size_t)205852672 + 65536;       // 256*16*1024

  // workspace layout (floats)
  float* ws    = (float*)d_ws;
  float* whT   = ws;                        // 2*4096*1024 = 8388608
  float* x_emb = whT   + 8388608;           // 4096*1024   = 4194304
  float* xwb   = x_emb + 4194304;           // 4096*4096   = 16777216
  float* ys0   = xwb   + 16777216;          // 4096*1024   = 4194304
  unsigned short* hppH = (unsigned short*)(ys0 + 4194304);  // 2*16*1024 u16
  unsigned short* hppL = hppH + 32768;                      // 2*16*1024 u16
  unsigned* flags = (unsigned*)(hppH + 65536);              // 256 u32 (pad 4096)

  hipMemsetAsync(flags, 0, 4096 * sizeof(unsigned), stream);
  transpose_wh<<<dim3(128, 32, 2), dim3(32, 8), 0, stream>>>(wh, whT);
  embed_gather<<<4096, 256, 0, stream>>>(tokens, embedding, x_emb);

  for (int l = 0; l < 2; ++l) {
    const float* a = (l == 0) ? x_emb : ys0;
    gemm_split3<<<dim3(32, 32), 256, 0, stream>>>(
        a, wi + (size_t)l * 4194304, bi + l * 4096, xwb, 4096, 4096, 1024);

    const float* wT   = whT + (size_t)l * 4194304;
    const float* xwp  = xwb;
    const float* bhl  = bh + l * 4096;
    const float* h0p  = hidden + (size_t)l * 32768;
    const float* c0p  = h0p + 16384;
    unsigned short* hH = hppH;
    unsigned short* hL = hppL;
    float* ysp  = (l == 0) ? ys0 : out_x;
    float* hfin = out_nh + (size_t)l * 32768;
    float* cfin = hfin + 16384;
    unsigned basev = (unsigned)(l * 260);
    unsigned* flp = flags;
    void* args[] = { &wT, &xwp, &bhl, &h0p, &c0p, &hH, &hL, &ysp, &hfin, &cfin, &flp, &basev };
    hipLaunchCooperativeKernel((const void*)lstm_persistent,
                               dim3(256), dim3(256), args, 0, stream);
  }
  gemm_split3<<<dim3(32, 393), 256, 0, stream>>>(
      out_x, wdec, bdec, out_res, 4096, 50257, 1024);
}

// Round 5
// 9360.436 us; speedup vs baseline: 1.7479x; 1.1327x over previous
//
#include <hip/hip_runtime.h>

// ---------- types ----------
typedef float  f32x4  __attribute__((ext_vector_type(4)));
typedef unsigned short u16x4 __attribute__((ext_vector_type(4)));
typedef unsigned short u16x8 __attribute__((ext_vector_type(8)));
typedef __bf16 bf16x8 __attribute__((ext_vector_type(8)));

// round-to-nearest-even f32 -> bf16 (bit trick)
static __device__ __forceinline__ unsigned short bf16_rn(float x) {
  unsigned u = __builtin_bit_cast(unsigned, x);
  unsigned r = (u + 0x7FFFu + ((u >> 16) & 1u)) >> 16;
  return (unsigned short)r;
}
// split x ~= hi + lo (each bf16); residual ~2^-17 relative
static __device__ __forceinline__ void split1(float x, unsigned short& h, unsigned short& l) {
  unsigned short hh = bf16_rn(x);
  float hf = __builtin_bit_cast(float, ((unsigned)hh) << 16);
  h = hh;
  l = bf16_rn(x - hf);
}

// ---------- GEMM: C = A(f32,MxK) * B(f32,KxN) + bias, split-bf16 3-term MFMA ----------
#define BM 128
#define BN 128
#define BK 32
#define LDK 40

// XOR-swizzled LDS index: 16B chunks permuted by row (kills the 16-way
// transposed-write bank conflict, keeps 16B alignment for ds_read_b128).
static __device__ __forceinline__ int lds_idx(int row, int k) {
  return row * LDK + ((((k >> 3) ^ (row >> 2)) & 3) << 3) + (k & 7);
}

__global__ __launch_bounds__(256) void gemm_split3(
    const float* __restrict__ A, const float* __restrict__ B,
    const float* __restrict__ bias, float* __restrict__ C,
    int M, int N, int K) {
  __shared__ unsigned short Ah[BM * LDK];
  __shared__ unsigned short Al[BM * LDK];
  __shared__ unsigned short Bh[BN * LDK];
  __shared__ unsigned short Bl[BN * LDK];

  const int tid  = threadIdx.x;
  const int lane = tid & 63;
  const int wave = tid >> 6;
  const int bm = blockIdx.x * BM;
  const int bn = blockIdx.y * BN;
  const int wm = (wave >> 1) * 64;
  const int wn = (wave & 1) * 64;
  const bool nvec = ((N & 3) == 0);

  f32x4 acc[4][4] = {};

  const int ar  = tid >> 3;
  const int ak  = (tid & 7) << 2;
  const int bk  = tid >> 5;
  const int bn4 = (tid & 31) << 2;

  for (int k0 = 0; k0 < K; k0 += BK) {
#pragma unroll
    for (int p = 0; p < 4; ++p) {
      int r = ar + (p << 5);
      f32x4 v = *(const f32x4*)(A + (size_t)(bm + r) * K + (k0 + ak));
      u16x4 h, l;
#pragma unroll
      for (int j = 0; j < 4; ++j) { unsigned short hh, ll; split1(v[j], hh, ll); h[j] = hh; l[j] = ll; }
      int ix = lds_idx(r, ak);
      *(u16x4*)(&Ah[ix]) = h;
      *(u16x4*)(&Al[ix]) = l;
    }
#pragma unroll
    for (int p = 0; p < 4; ++p) {
      int kr = bk + (p << 3);
      const float* src = B + (size_t)(k0 + kr) * N + (bn + bn4);
      float v[4];
      if (nvec) {
        f32x4 t4 = *(const f32x4*)src;
        v[0] = t4.x; v[1] = t4.y; v[2] = t4.z; v[3] = t4.w;
      } else {
#pragma unroll
        for (int j = 0; j < 4; ++j) {
          int col = bn + bn4 + j;
          v[j] = (col < N) ? src[j] : 0.f;
        }
      }
#pragma unroll
      for (int j = 0; j < 4; ++j) {
        unsigned short hh, ll; split1(v[j], hh, ll);
        int ix = lds_idx(bn4 + j, kr);
        Bh[ix] = hh;
        Bl[ix] = ll;
      }
    }
    __syncthreads();

    const int fr = lane & 15;
    const int kg = (lane >> 4) << 3;
    u16x8 a_h[4], a_l[4], b_h[4], b_l[4];
#pragma unroll
    for (int i = 0; i < 4; ++i) {
      int ia = lds_idx(wm + i * 16 + fr, kg);
      int ib = lds_idx(wn + i * 16 + fr, kg);
      a_h[i] = *(const u16x8*)(&Ah[ia]);
      a_l[i] = *(const u16x8*)(&Al[ia]);
      b_h[i] = *(const u16x8*)(&Bh[ib]);
      b_l[i] = *(const u16x8*)(&Bl[ib]);
    }
#pragma unroll
    for (int i = 0; i < 4; ++i)
#pragma unroll
      for (int j = 0; j < 4; ++j) {
        acc[i][j] = __builtin_amdgcn_mfma_f32_16x16x32_bf16(
            __builtin_bit_cast(bf16x8, a_h[i]), __builtin_bit_cast(bf16x8, b_h[j]), acc[i][j], 0, 0, 0);
        acc[i][j] = __builtin_amdgcn_mfma_f32_16x16x32_bf16(
            __builtin_bit_cast(bf16x8, a_h[i]), __builtin_bit_cast(bf16x8, b_l[j]), acc[i][j], 0, 0, 0);
        acc[i][j] = __builtin_amdgcn_mfma_f32_16x16x32_bf16(
            __builtin_bit_cast(bf16x8, a_l[i]), __builtin_bit_cast(bf16x8, b_h[j]), acc[i][j], 0, 0, 0);
      }
    __syncthreads();
  }
  const int cc = lane & 15;
  const int rg = (lane >> 4) << 2;
#pragma unroll
  for (int i = 0; i < 4; ++i)
#pragma unroll
    for (int j = 0; j < 4; ++j)
#pragma unroll
      for (int r = 0; r < 4; ++r) {
        int row = bm + wm + i * 16 + rg + r;
        int col = bn + wn + j * 16 + cc;
        if (col < N) {
          float v = acc[i][j][r];
          if (bias) v += bias[col];
          C[(size_t)row * N + col] = v;
        }
      }
}

// ---------- fence-free grid barrier ----------
// All cross-WG data (packed h, flags) moves via relaxed AGENT-scope atomics:
// stores write through to the coherence point, loads bypass (possibly stale)
// per-XCD L2. Release = s_waitcnt vmcnt(0) (store-ack) before flag store.
// NO buffer_wbl2 / buffer_inv anywhere in the step loop.
static __device__ __forceinline__ void poll_flags(const unsigned* flags, unsigned tgt, int lane) {
  for (;;) {
    unsigned v0 = __hip_atomic_load(flags + lane,       __ATOMIC_RELAXED, __HIP_MEMORY_SCOPE_AGENT);
    unsigned v1 = __hip_atomic_load(flags + 64 + lane,  __ATOMIC_RELAXED, __HIP_MEMORY_SCOPE_AGENT);
    unsigned v2 = __hip_atomic_load(flags + 128 + lane, __ATOMIC_RELAXED, __HIP_MEMORY_SCOPE_AGENT);
    unsigned v3 = __hip_atomic_load(flags + 192 + lane, __ATOMIC_RELAXED, __HIP_MEMORY_SCOPE_AGENT);
    unsigned m01 = v0 < v1 ? v0 : v1;
    unsigned m23 = v2 < v3 ? v2 : v3;
    unsigned mn  = m01 < m23 ? m01 : m23;
    if (__all((int)(mn >= tgt))) break;
    __builtin_amdgcn_s_sleep(1);
  }
  asm volatile("" ::: "memory");  // keep subsequent data loads below the poll
}

// ---------- persistent LSTM recurrence (cooperative, weights in VGPRs) ----------
// h ping-pong stored PACKED (hi<<16 | lo) via agent-scope atomic u32 stores;
// consumers unpack in-register into MFMA A-fragments.
__global__ __launch_bounds__(256) void lstm_persistent(
    const float* __restrict__ whT,   // [4096 cols][1024 k] this layer
    const float* __restrict__ xw,    // [256][16][4096]
    const float* __restrict__ bh,    // [4096]
    const float* __restrict__ h0,    // [16][1024]
    const float* __restrict__ c0,    // [16][1024]
    unsigned* __restrict__ hP,       // [2][16][1024] packed hi|lo
    float* __restrict__ ys,          // [256][16][1024]
    float* __restrict__ hfin, float* __restrict__ cfin,
    unsigned* __restrict__ flags, unsigned base) {
  __shared__ float red[4][16][16];
  const int tid  = threadIdx.x;
  const int lane = tid & 63;
  const int wave = tid >> 6;
  const int bid  = blockIdx.x;
  const int lc   = lane & 15;
  const int kg8  = (lane >> 4) << 3;
  const int wk   = wave << 8;

  // B-frags: weights, split bf16, loaded once into VGPRs
  const int gcol = (lc & 3) * 1024 + (bid << 2) + (lc >> 2);
  bf16x8 w_h[8], w_l[8];
#pragma unroll
  for (int kk = 0; kk < 8; ++kk) {
    const float* src = whT + ((size_t)gcol << 10) + (wk + (kk << 5) + kg8);
    f32x4 v0 = *(const f32x4*)src;
    f32x4 v1 = *(const f32x4*)(src + 4);
    u16x8 h8, l8;
#pragma unroll
    for (int j = 0; j < 4; ++j) {
      unsigned short hh, ll;
      split1(v0[j], hh, ll); h8[j] = hh;     l8[j] = ll;
      split1(v1[j], hh, ll); h8[4 + j] = hh; l8[4 + j] = ll;
    }
    w_h[kk] = __builtin_bit_cast(bf16x8, h8);
    w_l[kk] = __builtin_bit_cast(bf16x8, l8);
  }

  // activation-thread state (tid<64 == wave 0): (batch ab, unit-local ai)
  const int ab = tid & 15;
  const int ai = tid >> 4;
  const int au = (bid << 2) + (ai & 3);
  float c_reg = 0.f, h_keep = 0.f;
  float bhv[4], xwv[4], xwn[4];

  // prologue: stage packed h0 into slot 0; epoch base+1 = "slot0 ready"
  if (tid < 64) {
    float h0v = h0[(ab << 10) + au];
    unsigned short hh, ll; split1(h0v, hh, ll);
    unsigned p = ((unsigned)hh << 16) | (unsigned)ll;
    __hip_atomic_store(&hP[(ab << 10) + au], p, __ATOMIC_RELAXED, __HIP_MEMORY_SCOPE_AGENT);
    c_reg = c0[(ab << 10) + au];
#pragma unroll
    for (int g = 0; g < 4; ++g) bhv[g] = bh[(g << 10) + au];
#pragma unroll
    for (int g = 0; g < 4; ++g) xwv[g] = xw[(ab << 12) + (g << 10) + au];
  }
  if (wave == 0) {
    asm volatile("s_waitcnt vmcnt(0)" ::: "memory");
    if (lane == 0)
      __hip_atomic_store(&flags[bid], base + 1u, __ATOMIC_RELAXED, __HIP_MEMORY_SCOPE_AGENT);
    poll_flags(flags, base + 1u, lane);
  }
  __syncthreads();

  for (int s = 0; s < 256; ++s) {
    // prefetch next step's xw early: in flight under the whole step
    if (tid < 64 && s < 255) {
      const float* xn = xw + ((size_t)(s + 1) << 16);
#pragma unroll
      for (int g = 0; g < 4; ++g) xwn[g] = xn[(ab << 12) + (g << 10) + au];
    }
    const unsigned* hp = hP + ((s & 1) << 14);
    f32x4 acc0 = {}, acc1 = {}, acc2 = {};
#pragma unroll
    for (int kk = 0; kk < 8; ++kk) {
      const unsigned* src = hp + (lc << 10) + wk + (kk << 5) + kg8;
      unsigned r[8];
#pragma unroll
      for (int q = 0; q < 8; ++q)
        r[q] = __hip_atomic_load(src + q, __ATOMIC_RELAXED, __HIP_MEMORY_SCOPE_AGENT);
      u16x8 h8, l8;
#pragma unroll
      for (int q = 0; q < 8; ++q) { h8[q] = (unsigned short)(r[q] >> 16); l8[q] = (unsigned short)r[q]; }
      bf16x8 ah = __builtin_bit_cast(bf16x8, h8);
      bf16x8 al = __builtin_bit_cast(bf16x8, l8);
      acc0 = __builtin_amdgcn_mfma_f32_16x16x32_bf16(ah, w_h[kk], acc0, 0, 0, 0);
      acc1 = __builtin_amdgcn_mfma_f32_16x16x32_bf16(ah, w_l[kk], acc1, 0, 0, 0);
      acc2 = __builtin_amdgcn_mfma_f32_16x16x32_bf16(al, w_h[kk], acc2, 0, 0, 0);
    }
    f32x4 a = acc0 + acc1 + acc2;
#pragma unroll
    for (int r = 0; r < 4; ++r) red[wave][(lane >> 4) * 4 + r][lc] = a[r];
    __syncthreads();
    if (tid < 64) {
      float pre[4];
#pragma unroll
      for (int g = 0; g < 4; ++g) {
        int c = (ai << 2) + g;
        pre[g] = red[0][ab][c] + red[1][ab][c] + red[2][ab][c] + red[3][ab][c]
               + xwv[g] + bhv[g];
      }
      float f  = 1.f / (1.f + expf(-pre[0]));
      float i_ = 1.f / (1.f + expf(-pre[1]));
      float o  = 1.f / (1.f + expf(-pre[2]));
      float g_ = tanhf(pre[3]);
      c_reg = f * c_reg + i_ * g_;
      float h = o * tanhf(c_reg);
      h_keep = h;
      ys[((size_t)s << 14) + (ab << 10) + au] = h;
      unsigned short hh, ll; split1(h, hh, ll);
      unsigned p = ((unsigned)hh << 16) | (unsigned)ll;
      __hip_atomic_store(&hP[(((s + 1) & 1) << 14) + (ab << 10) + au], p,
                         __ATOMIC_RELAXED, __HIP_MEMORY_SCOPE_AGENT);
    }
    if (wave == 0) {
      asm volatile("s_waitcnt vmcnt(0)" ::: "memory");  // h stores ack'd at coherence point
      if (lane == 0)
        __hip_atomic_store(&flags[bid], base + 2u + (unsigned)s, __ATOMIC_RELAXED, __HIP_MEMORY_SCOPE_AGENT);
    }
    if (tid < 64) {
#pragma unroll
      for (int g = 0; g < 4; ++g) xwv[g] = xwn[g];
    }
    if (wave == 0 && s < 255)
      poll_flags(flags, base + 2u + (unsigned)s, lane);
    __syncthreads();
  }
  if (tid < 64) {
    hfin[(ab << 10) + au] = h_keep;
    cfin[(ab << 10) + au] = c_reg;
  }
}

// ---------- small utility kernels ----------
__global__ __launch_bounds__(256) void embed_gather(
    const int* __restrict__ tokens, const float* __restrict__ emb, float* __restrict__ x) {
  int sb = blockIdx.x;
  int tok = tokens[sb];
  const f32x4* src = (const f32x4*)(emb + (size_t)tok * 1024);
  f32x4* dst = (f32x4*)(x + (size_t)sb * 1024);
  dst[threadIdx.x] = src[threadIdx.x];
}

__global__ void transpose_wh(const float* __restrict__ wh, float* __restrict__ whT) {
  __shared__ float tile[32][33];
  int l = blockIdx.z;
  int c0 = blockIdx.x << 5;
  int k0 = blockIdx.y << 5;
  int tx = threadIdx.x, ty = threadIdx.y;  // 32 x 8
  const float* src = wh + ((size_t)l << 22);
  float* dst = whT + ((size_t)l << 22);
#pragma unroll
  for (int i = 0; i < 32; i += 8)
    tile[ty + i][tx] = src[(size_t)(k0 + ty + i) * 4096 + c0 + tx];
  __syncthreads();
#pragma unroll
  for (int i = 0; i < 32; i += 8)
    dst[(size_t)(c0 + ty + i) * 1024 + k0 + tx] = tile[tx][ty + i];
}

// ---------- host ----------
extern "C" void kernel_launch(void* const* d_in, const int* in_sizes, int n_in,
                              void* d_out, int out_size, void* d_ws, size_t ws_size,
                              hipStream_t stream) {
  (void)in_sizes; (void)n_in; (void)out_size; (void)ws_size;
  const int*   tokens    = (const int*)  d_in[0];
  const float* hidden    = (const float*)d_in[1];
  const float* embedding = (const float*)d_in[2];
  const float* wi        = (const float*)d_in[3];
  const float* bi        = (const float*)d_in[4];
  const float* wh        = (const float*)d_in[5];
  const float* bh        = (const float*)d_in[6];
  const float* wdec      = (const float*)d_in[7];
  const float* bdec      = (const float*)d_in[8];

  float* out     = (float*)d_out;
  float* out_res = out;                                   // 256*16*50257
  float* out_nh  = out + (size_t)205852672;               // 2*2*16*1024
  float* out_x   = out + (size_t)205852672 + 65536;       // 256*16*1024

  // workspace layout (floats)
  float* ws    = (float*)d_ws;
  float* whT   = ws;                        // 2*4096*1024 = 8388608
  float* x_emb = whT   + 8388608;           // 4096*1024   = 4194304
  float* xwb   = x_emb + 4194304;           // 4096*4096   = 16777216
  float* ys0   = xwb   + 16777216;          // 4096*1024   = 4194304
  unsigned* hP    = (unsigned*)(ys0 + 4194304);  // 2*16*1024 u32 packed h
  unsigned* flags = hP + 32768;                  // 256 u32 (pad 4096)

  hipMemsetAsync(flags, 0, 4096 * sizeof(unsigned), stream);
  transpose_wh<<<dim3(128, 32, 2), dim3(32, 8), 0, stream>>>(wh, whT);
  embed_gather<<<4096, 256, 0, stream>>>(tokens, embedding, x_emb);

  for (int l = 0; l < 2; ++l) {
    const float* a = (l == 0) ? x_emb : ys0;
    gemm_split3<<<dim3(32, 32), 256, 0, stream>>>(
        a, wi + (size_t)l * 4194304, bi + l * 4096, xwb, 4096, 4096, 1024);

    const float* wT   = whT + (size_t)l * 4194304;
    const float* xwp  = xwb;
    const float* bhl  = bh + l * 4096;
    const float* h0p  = hidden + (size_t)l * 32768;
    const float* c0p  = h0p + 16384;
    unsigned* hPp = hP;
    float* ysp  = (l == 0) ? ys0 : out_x;
    float* hfin = out_nh + (size_t)l * 32768;
    float* cfin = hfin + 16384;
    unsigned basev = (unsigned)(l * 260);
    unsigned* flp = flags;
    void* args[] = { &wT, &xwp, &bhl, &h0p, &c0p, &hPp, &ysp, &hfin, &cfin, &flp, &basev };
    hipLaunchCooperativeKernel((const void*)lstm_persistent,
                               dim3(256), dim3(256), args, 0, stream);
  }
  gemm_split3<<<dim3(32, 393), 256, 0, stream>>>(
      out_x, wdec, bdec, out_res, 4096, 50257, 1024);
}

// Round 6
// 7466.965 us; speedup vs baseline: 2.1911x; 1.2536x over previous
//
#include <hip/hip_runtime.h>

// ---------- types ----------
typedef float  f32x4  __attribute__((ext_vector_type(4)));
typedef unsigned short u16x4 __attribute__((ext_vector_type(4)));
typedef unsigned short u16x8 __attribute__((ext_vector_type(8)));
typedef __bf16 bf16x8 __attribute__((ext_vector_type(8)));

// round-to-nearest-even f32 -> bf16 (bit trick)
static __device__ __forceinline__ unsigned short bf16_rn(float x) {
  unsigned u = __builtin_bit_cast(unsigned, x);
  unsigned r = (u + 0x7FFFu + ((u >> 16) & 1u)) >> 16;
  return (unsigned short)r;
}
// split x ~= hi + lo (each bf16); residual ~2^-17 relative
static __device__ __forceinline__ void split1(float x, unsigned short& h, unsigned short& l) {
  unsigned short hh = bf16_rn(x);
  float hf = __builtin_bit_cast(float, ((unsigned)hh) << 16);
  h = hh;
  l = bf16_rn(x - hf);
}

// ---------- GEMM: C = A(f32,MxK) * B(f32,KxN) + bias, split-bf16 3-term MFMA ----------
#define BM 128
#define BN 128
#define BK 32
#define LDK 40

// XOR-swizzled LDS index: 16B chunks permuted by row (kills the 16-way
// transposed-write bank conflict, keeps 16B alignment for ds_read_b128).
static __device__ __forceinline__ int lds_idx(int row, int k) {
  return row * LDK + ((((k >> 3) ^ (row >> 2)) & 3) << 3) + (k & 7);
}

__global__ __launch_bounds__(256) void gemm_split3(
    const float* __restrict__ A, const float* __restrict__ B,
    const float* __restrict__ bias, float* __restrict__ C,
    int M, int N, int K) {
  __shared__ unsigned short Ah[BM * LDK];
  __shared__ unsigned short Al[BM * LDK];
  __shared__ unsigned short Bh[BN * LDK];
  __shared__ unsigned short Bl[BN * LDK];

  const int tid  = threadIdx.x;
  const int lane = tid & 63;
  const int wave = tid >> 6;
  const int bm = blockIdx.x * BM;
  const int bn = blockIdx.y * BN;
  const int wm = (wave >> 1) * 64;
  const int wn = (wave & 1) * 64;
  const bool nvec = ((N & 3) == 0);

  f32x4 acc[4][4] = {};

  const int ar  = tid >> 3;
  const int ak  = (tid & 7) << 2;
  const int bk  = tid >> 5;
  const int bn4 = (tid & 31) << 2;

  for (int k0 = 0; k0 < K; k0 += BK) {
#pragma unroll
    for (int p = 0; p < 4; ++p) {
      int r = ar + (p << 5);
      f32x4 v = *(const f32x4*)(A + (size_t)(bm + r) * K + (k0 + ak));
      u16x4 h, l;
#pragma unroll
      for (int j = 0; j < 4; ++j) { unsigned short hh, ll; split1(v[j], hh, ll); h[j] = hh; l[j] = ll; }
      int ix = lds_idx(r, ak);
      *(u16x4*)(&Ah[ix]) = h;
      *(u16x4*)(&Al[ix]) = l;
    }
#pragma unroll
    for (int p = 0; p < 4; ++p) {
      int kr = bk + (p << 3);
      const float* src = B + (size_t)(k0 + kr) * N + (bn + bn4);
      float v[4];
      if (nvec) {
        f32x4 t4 = *(const f32x4*)src;
        v[0] = t4.x; v[1] = t4.y; v[2] = t4.z; v[3] = t4.w;
      } else {
#pragma unroll
        for (int j = 0; j < 4; ++j) {
          int col = bn + bn4 + j;
          v[j] = (col < N) ? src[j] : 0.f;
        }
      }
#pragma unroll
      for (int j = 0; j < 4; ++j) {
        unsigned short hh, ll; split1(v[j], hh, ll);
        int ix = lds_idx(bn4 + j, kr);
        Bh[ix] = hh;
        Bl[ix] = ll;
      }
    }
    __syncthreads();

    const int fr = lane & 15;
    const int kg = (lane >> 4) << 3;
    u16x8 a_h[4], a_l[4], b_h[4], b_l[4];
#pragma unroll
    for (int i = 0; i < 4; ++i) {
      int ia = lds_idx(wm + i * 16 + fr, kg);
      int ib = lds_idx(wn + i * 16 + fr, kg);
      a_h[i] = *(const u16x8*)(&Ah[ia]);
      a_l[i] = *(const u16x8*)(&Al[ia]);
      b_h[i] = *(const u16x8*)(&Bh[ib]);
      b_l[i] = *(const u16x8*)(&Bl[ib]);
    }
#pragma unroll
    for (int i = 0; i < 4; ++i)
#pragma unroll
      for (int j = 0; j < 4; ++j) {
        acc[i][j] = __builtin_amdgcn_mfma_f32_16x16x32_bf16(
            __builtin_bit_cast(bf16x8, a_h[i]), __builtin_bit_cast(bf16x8, b_h[j]), acc[i][j], 0, 0, 0);
        acc[i][j] = __builtin_amdgcn_mfma_f32_16x16x32_bf16(
            __builtin_bit_cast(bf16x8, a_h[i]), __builtin_bit_cast(bf16x8, b_l[j]), acc[i][j], 0, 0, 0);
        acc[i][j] = __builtin_amdgcn_mfma_f32_16x16x32_bf16(
            __builtin_bit_cast(bf16x8, a_l[i]), __builtin_bit_cast(bf16x8, b_h[j]), acc[i][j], 0, 0, 0);
      }
    __syncthreads();
  }
  const int cc = lane & 15;
  const int rg = (lane >> 4) << 2;
#pragma unroll
  for (int i = 0; i < 4; ++i)
#pragma unroll
    for (int j = 0; j < 4; ++j)
#pragma unroll
      for (int r = 0; r < 4; ++r) {
        int row = bm + wm + i * 16 + rg + r;
        int col = bn + wn + j * 16 + cc;
        if (col < N) {
          float v = acc[i][j][r];
          if (bias) v += bias[col];
          C[(size_t)row * N + col] = v;
        }
      }
}

// ---------- fence-free grid barrier ----------
// Flags move via relaxed AGENT-scope atomics (uncached, coherence-point).
// h itself moves via ys[s]: step-unique addresses -> consumers may use plain
// CACHED loads (first-touch guarantees no stale L1/L2 copy), producers use
// agent-scope write-through atomic stores. No cache-maintenance instructions.
static __device__ __forceinline__ void poll_flags(const unsigned* flags, unsigned tgt, int lane) {
  for (;;) {
    unsigned v0 = __hip_atomic_load(flags + lane,       __ATOMIC_RELAXED, __HIP_MEMORY_SCOPE_AGENT);
    unsigned v1 = __hip_atomic_load(flags + 64 + lane,  __ATOMIC_RELAXED, __HIP_MEMORY_SCOPE_AGENT);
    unsigned v2 = __hip_atomic_load(flags + 128 + lane, __ATOMIC_RELAXED, __HIP_MEMORY_SCOPE_AGENT);
    unsigned v3 = __hip_atomic_load(flags + 192 + lane, __ATOMIC_RELAXED, __HIP_MEMORY_SCOPE_AGENT);
    unsigned m01 = v0 < v1 ? v0 : v1;
    unsigned m23 = v2 < v3 ? v2 : v3;
    unsigned mn  = m01 < m23 ? m01 : m23;
    if (__all((int)(mn >= tgt))) break;
    __builtin_amdgcn_s_sleep(1);
  }
  asm volatile("" ::: "memory");  // keep subsequent data loads below the poll
}

// ---------- persistent LSTM recurrence (cooperative, weights in VGPRs) ----------
// h for step s is read from ys[s-1] (plain cached loads; L2-broadcast within
// each XCD) and written to ys[s] via agent-scope atomic stores.
__global__ __launch_bounds__(256) void lstm_persistent(
    const float* __restrict__ whT,   // [4096 cols][1024 k] this layer
    const float* __restrict__ xw,    // [256][16][4096]
    const float* __restrict__ bh,    // [4096]
    const float* __restrict__ h0,    // [16][1024]
    const float* __restrict__ c0,    // [16][1024]
    float* __restrict__ ys,          // [256][16][1024] = h sequence (output)
    float* __restrict__ hfin, float* __restrict__ cfin,
    unsigned* __restrict__ flags, unsigned base) {
  __shared__ float red[4][16][16];
  const int tid  = threadIdx.x;
  const int lane = tid & 63;
  const int wave = tid >> 6;
  const int bid  = blockIdx.x;
  const int lc   = lane & 15;
  const int kg8  = (lane >> 4) << 3;
  const int wk   = wave << 8;

  // B-frags: weights, split bf16, loaded once into VGPRs
  const int gcol = (lc & 3) * 1024 + (bid << 2) + (lc >> 2);
  bf16x8 w_h[8], w_l[8];
#pragma unroll
  for (int kk = 0; kk < 8; ++kk) {
    const float* src = whT + ((size_t)gcol << 10) + (wk + (kk << 5) + kg8);
    f32x4 v0 = *(const f32x4*)src;
    f32x4 v1 = *(const f32x4*)(src + 4);
    u16x8 h8, l8;
#pragma unroll
    for (int j = 0; j < 4; ++j) {
      unsigned short hh, ll;
      split1(v0[j], hh, ll); h8[j] = hh;     l8[j] = ll;
      split1(v1[j], hh, ll); h8[4 + j] = hh; l8[4 + j] = ll;
    }
    w_h[kk] = __builtin_bit_cast(bf16x8, h8);
    w_l[kk] = __builtin_bit_cast(bf16x8, l8);
  }

  // activation-thread state (tid<64 == wave 0): (batch ab, unit-local ai)
  const int ab = tid & 15;
  const int ai = tid >> 4;
  const int au = (bid << 2) + (ai & 3);
  float c_reg = 0.f, h_keep = 0.f;
  float bhv[4], xwv[4], xwn[4];
  if (tid < 64) {
    c_reg = c0[(ab << 10) + au];
#pragma unroll
    for (int g = 0; g < 4; ++g) bhv[g] = bh[(g << 10) + au];
#pragma unroll
    for (int g = 0; g < 4; ++g) xwv[g] = xw[(ab << 12) + (g << 10) + au];
  }

  for (int s = 0; s < 256; ++s) {
    // prefetch next step's xw early: in flight under the whole step
    if (tid < 64 && s < 255) {
      const float* xn = xw + ((size_t)(s + 1) << 16);
#pragma unroll
      for (int g = 0; g < 4; ++g) xwn[g] = xn[(ab << 12) + (g << 10) + au];
    }
    // h source: step-unique address (first-touch) -> plain cached loads
    const float* hsrc = (s == 0) ? h0 : (ys + ((size_t)(s - 1) << 14));
    f32x4 acc0 = {}, acc1 = {}, acc2 = {};
#pragma unroll
    for (int kk = 0; kk < 8; ++kk) {
      const float* hp = hsrc + (lc << 10) + wk + (kk << 5) + kg8;
      f32x4 v0 = *(const f32x4*)hp;
      f32x4 v1 = *(const f32x4*)(hp + 4);
      u16x8 h8, l8;
#pragma unroll
      for (int j = 0; j < 4; ++j) {
        unsigned short hh, ll;
        split1(v0[j], hh, ll); h8[j] = hh;     l8[j] = ll;
        split1(v1[j], hh, ll); h8[4 + j] = hh; l8[4 + j] = ll;
      }
      bf16x8 ah = __builtin_bit_cast(bf16x8, h8);
      bf16x8 al = __builtin_bit_cast(bf16x8, l8);
      acc0 = __builtin_amdgcn_mfma_f32_16x16x32_bf16(ah, w_h[kk], acc0, 0, 0, 0);
      acc1 = __builtin_amdgcn_mfma_f32_16x16x32_bf16(ah, w_l[kk], acc1, 0, 0, 0);
      acc2 = __builtin_amdgcn_mfma_f32_16x16x32_bf16(al, w_h[kk], acc2, 0, 0, 0);
    }
    f32x4 a = acc0 + acc1 + acc2;
#pragma unroll
    for (int r = 0; r < 4; ++r) red[wave][(lane >> 4) * 4 + r][lc] = a[r];
    __syncthreads();
    if (tid < 64) {
      float pre[4];
#pragma unroll
      for (int g = 0; g < 4; ++g) {
        int c = (ai << 2) + g;
        pre[g] = red[0][ab][c] + red[1][ab][c] + red[2][ab][c] + red[3][ab][c]
               + xwv[g] + bhv[g];
      }
      float f  = 1.f / (1.f + expf(-pre[0]));
      float i_ = 1.f / (1.f + expf(-pre[1]));
      float o  = 1.f / (1.f + expf(-pre[2]));
      float g_ = tanhf(pre[3]);
      c_reg = f * c_reg + i_ * g_;
      float h = o * tanhf(c_reg);
      h_keep = h;
      // publish h: write-through agent-scope atomic store to ys[s]
      __hip_atomic_store((unsigned*)ys + (((size_t)s << 14) + (ab << 10) + au),
                         __builtin_bit_cast(unsigned, h),
                         __ATOMIC_RELAXED, __HIP_MEMORY_SCOPE_AGENT);
#pragma unroll
      for (int g = 0; g < 4; ++g) xwv[g] = xwn[g];
    }
    if (wave == 0) {
      asm volatile("s_waitcnt vmcnt(0)" ::: "memory");  // h stores ack'd at coherence point
      if (lane == 0)
        __hip_atomic_store(&flags[bid], base + 1u + (unsigned)s, __ATOMIC_RELAXED, __HIP_MEMORY_SCOPE_AGENT);
      if (s < 255)
        poll_flags(flags, base + 1u + (unsigned)s, lane);
    }
    __syncthreads();
  }
  if (tid < 64) {
    hfin[(ab << 10) + au] = h_keep;
    cfin[(ab << 10) + au] = c_reg;
  }
}

// ---------- small utility kernels ----------
__global__ __launch_bounds__(256) void embed_gather(
    const int* __restrict__ tokens, const float* __restrict__ emb, float* __restrict__ x) {
  int sb = blockIdx.x;
  int tok = tokens[sb];
  const f32x4* src = (const f32x4*)(emb + (size_t)tok * 1024);
  f32x4* dst = (f32x4*)(x + (size_t)sb * 1024);
  dst[threadIdx.x] = src[threadIdx.x];
}

__global__ void transpose_wh(const float* __restrict__ wh, float* __restrict__ whT) {
  __shared__ float tile[32][33];
  int l = blockIdx.z;
  int c0 = blockIdx.x << 5;
  int k0 = blockIdx.y << 5;
  int tx = threadIdx.x, ty = threadIdx.y;  // 32 x 8
  const float* src = wh + ((size_t)l << 22);
  float* dst = whT + ((size_t)l << 22);
#pragma unroll
  for (int i = 0; i < 32; i += 8)
    tile[ty + i][tx] = src[(size_t)(k0 + ty + i) * 4096 + c0 + tx];
  __syncthreads();
#pragma unroll
  for (int i = 0; i < 32; i += 8)
    dst[(size_t)(c0 + ty + i) * 1024 + k0 + tx] = tile[tx][ty + i];
}

// ---------- host ----------
extern "C" void kernel_launch(void* const* d_in, const int* in_sizes, int n_in,
                              void* d_out, int out_size, void* d_ws, size_t ws_size,
                              hipStream_t stream) {
  (void)in_sizes; (void)n_in; (void)out_size; (void)ws_size;
  const int*   tokens    = (const int*)  d_in[0];
  const float* hidden    = (const float*)d_in[1];
  const float* embedding = (const float*)d_in[2];
  const float* wi        = (const float*)d_in[3];
  const float* bi        = (const float*)d_in[4];
  const float* wh        = (const float*)d_in[5];
  const float* bh        = (const float*)d_in[6];
  const float* wdec      = (const float*)d_in[7];
  const float* bdec      = (const float*)d_in[8];

  float* out     = (float*)d_out;
  float* out_res = out;                                   // 256*16*50257
  float* out_nh  = out + (size_t)205852672;               // 2*2*16*1024
  float* out_x   = out + (size_t)205852672 + 65536;       // 256*16*1024

  // workspace layout (floats)
  float* ws    = (float*)d_ws;
  float* whT   = ws;                        // 2*4096*1024 = 8388608
  float* x_emb = whT   + 8388608;           // 4096*1024   = 4194304
  float* xwb   = x_emb + 4194304;           // 4096*4096   = 16777216
  float* ys0   = xwb   + 16777216;          // 4096*1024   = 4194304
  unsigned* flags = (unsigned*)(ys0 + 4194304);  // 256 u32 (pad 4096)

  hipMemsetAsync(flags, 0, 4096 * sizeof(unsigned), stream);
  transpose_wh<<<dim3(128, 32, 2), dim3(32, 8), 0, stream>>>(wh, whT);
  embed_gather<<<4096, 256, 0, stream>>>(tokens, embedding, x_emb);

  for (int l = 0; l < 2; ++l) {
    const float* a = (l == 0) ? x_emb : ys0;
    gemm_split3<<<dim3(32, 32), 256, 0, stream>>>(
        a, wi + (size_t)l * 4194304, bi + l * 4096, xwb, 4096, 4096, 1024);

    const float* wT   = whT + (size_t)l * 4194304;
    const float* xwp  = xwb;
    const float* bhl  = bh + l * 4096;
    const float* h0p  = hidden + (size_t)l * 32768;
    const float* c0p  = h0p + 16384;
    float* ysp  = (l == 0) ? ys0 : out_x;
    float* hfin = out_nh + (size_t)l * 32768;
    float* cfin = hfin + 16384;
    unsigned basev = (unsigned)(l * 256);
    unsigned* flp = flags;
    void* args[] = { &wT, &xwp, &bhl, &h0p, &c0p, &ysp, &hfin, &cfin, &flp, &basev };
    hipLaunchCooperativeKernel((const void*)lstm_persistent,
                               dim3(256), dim3(256), args, 0, stream);
  }
  gemm_split3<<<dim3(32, 393), 256, 0, stream>>>(
      out_x, wdec, bdec, out_res, 4096, 50257, 1024);
}

// Round 7
// 7109.869 us; speedup vs baseline: 2.3011x; 1.0502x over previous
//
#include <hip/hip_runtime.h>

// ---------- types ----------
typedef float  f32x4  __attribute__((ext_vector_type(4)));
typedef unsigned short u16x4 __attribute__((ext_vector_type(4)));
typedef unsigned short u16x8 __attribute__((ext_vector_type(8)));
typedef __bf16 bf16x8 __attribute__((ext_vector_type(8)));

// round-to-nearest-even f32 -> bf16 (bit trick)
static __device__ __forceinline__ unsigned short bf16_rn(float x) {
  unsigned u = __builtin_bit_cast(unsigned, x);
  unsigned r = (u + 0x7FFFu + ((u >> 16) & 1u)) >> 16;
  return (unsigned short)r;
}
// split x ~= hi + lo (each bf16); residual ~2^-17 relative
static __device__ __forceinline__ void split1(float x, unsigned short& h, unsigned short& l) {
  unsigned short hh = bf16_rn(x);
  float hf = __builtin_bit_cast(float, ((unsigned)hh) << 16);
  h = hh;
  l = bf16_rn(x - hf);
}

// ---------- GEMM: C = A(f32,MxK) * B(f32,KxN) + bias, split-bf16 3-term MFMA ----------
#define BM 128
#define BN 128
#define BK 32
#define LDK 40

// XOR-swizzled LDS index: 16B chunks permuted by row (breaks power-of-2 row
// alignment for reads, keeps 16B alignment for ds_read_b128 / ds_write_b128).
static __device__ __forceinline__ int lds_idx(int row, int k) {
  return row * LDK + ((((k >> 3) ^ (row >> 2)) & 3) << 3) + (k & 7);
}

__global__ __launch_bounds__(256) void gemm_split3(
    const float* __restrict__ A, const float* __restrict__ B,
    const float* __restrict__ bias, float* __restrict__ C,
    int M, int N, int K) {
  __shared__ unsigned short Ah[BM * LDK];
  __shared__ unsigned short Al[BM * LDK];
  __shared__ unsigned short Bh[BN * LDK];
  __shared__ unsigned short Bl[BN * LDK];

  const int tid  = threadIdx.x;
  const int lane = tid & 63;
  const int wave = tid >> 6;
  const int bm = blockIdx.x * BM;
  const int bn = blockIdx.y * BN;
  const int wm = (wave >> 1) * 64;
  const int wn = (wave & 1) * 64;

  f32x4 acc[4][4] = {};

  const int ar  = tid >> 3;          // A-stage: row 0..31 (+p*32)
  const int ak  = (tid & 7) << 2;    // A-stage: k 0..28
  const int bcol = tid & 127;        // B-stage: column within tile
  const int bkh  = (tid >> 7) << 4;  // B-stage: k-half base (0 or 16)
  const bool bok = (bn + bcol) < N;
  const float* bsrc0 = B + (size_t)bkh * N + (bn + bcol);

  for (int k0 = 0; k0 < K; k0 += BK) {
    // ---- stage A (128x32 f32), split, vector LDS stores (u16x4) ----
#pragma unroll
    for (int p = 0; p < 4; ++p) {
      int r = ar + (p << 5);
      f32x4 v = *(const f32x4*)(A + (size_t)(bm + r) * K + (k0 + ak));
      u16x4 h, l;
#pragma unroll
      for (int j = 0; j < 4; ++j) { unsigned short hh, ll; split1(v[j], hh, ll); h[j] = hh; l[j] = ll; }
      int ix = lds_idx(r, ak);
      *(u16x4*)(&Ah[ix]) = h;
      *(u16x4*)(&Al[ix]) = l;
    }
    // ---- stage B: thread owns 1 col x 16 consecutive k ----
    // loads: 16 stride-N scalars, wave-coalesced (64 consecutive cols);
    // stores: 2x u16x8 per matrix at 16B-aligned chunks -> conflict-free.
    {
      const float* src = bsrc0 + (size_t)k0 * N;
      float bv[16];
#pragma unroll
      for (int q = 0; q < 16; ++q)
        bv[q] = bok ? src[(size_t)q * N] : 0.f;
      u16x8 h0, h1, l0, l1;
#pragma unroll
      for (int q = 0; q < 8; ++q) {
        unsigned short hh, ll;
        split1(bv[q], hh, ll);     h0[q] = hh; l0[q] = ll;
        split1(bv[8 + q], hh, ll); h1[q] = hh; l1[q] = ll;
      }
      int ix0 = lds_idx(bcol, bkh);
      int ix1 = lds_idx(bcol, bkh + 8);
      *(u16x8*)(&Bh[ix0]) = h0;
      *(u16x8*)(&Bh[ix1]) = h1;
      *(u16x8*)(&Bl[ix0]) = l0;
      *(u16x8*)(&Bl[ix1]) = l1;
    }
    __syncthreads();

    const int fr = lane & 15;
    const int kg = (lane >> 4) << 3;
    u16x8 a_h[4], a_l[4], b_h[4], b_l[4];
#pragma unroll
    for (int i = 0; i < 4; ++i) {
      int ia = lds_idx(wm + i * 16 + fr, kg);
      int ib = lds_idx(wn + i * 16 + fr, kg);
      a_h[i] = *(const u16x8*)(&Ah[ia]);
      a_l[i] = *(const u16x8*)(&Al[ia]);
      b_h[i] = *(const u16x8*)(&Bh[ib]);
      b_l[i] = *(const u16x8*)(&Bl[ib]);
    }
#pragma unroll
    for (int i = 0; i < 4; ++i)
#pragma unroll
      for (int j = 0; j < 4; ++j) {
        acc[i][j] = __builtin_amdgcn_mfma_f32_16x16x32_bf16(
            __builtin_bit_cast(bf16x8, a_h[i]), __builtin_bit_cast(bf16x8, b_h[j]), acc[i][j], 0, 0, 0);
        acc[i][j] = __builtin_amdgcn_mfma_f32_16x16x32_bf16(
            __builtin_bit_cast(bf16x8, a_h[i]), __builtin_bit_cast(bf16x8, b_l[j]), acc[i][j], 0, 0, 0);
        acc[i][j] = __builtin_amdgcn_mfma_f32_16x16x32_bf16(
            __builtin_bit_cast(bf16x8, a_l[i]), __builtin_bit_cast(bf16x8, b_h[j]), acc[i][j], 0, 0, 0);
      }
    __syncthreads();
  }
  const int cc = lane & 15;
  const int rg = (lane >> 4) << 2;
#pragma unroll
  for (int i = 0; i < 4; ++i)
#pragma unroll
    for (int j = 0; j < 4; ++j)
#pragma unroll
      for (int r = 0; r < 4; ++r) {
        int row = bm + wm + i * 16 + rg + r;
        int col = bn + wn + j * 16 + cc;
        if (col < N) {
          float v = acc[i][j][r];
          if (bias) v += bias[col];
          C[(size_t)row * N + col] = v;
        }
      }
}

// ---------- fence-free grid barrier ----------
// Flags move via relaxed AGENT-scope atomics (uncached, coherence-point).
// h itself moves via ys[s]: step-unique addresses -> consumers may use plain
// CACHED loads (first-touch guarantees no stale L1/L2 copy), producers use
// agent-scope write-through atomic stores. No cache-maintenance instructions.
static __device__ __forceinline__ void poll_flags(const unsigned* flags, unsigned tgt, int lane) {
  for (;;) {
    unsigned v0 = __hip_atomic_load(flags + lane,       __ATOMIC_RELAXED, __HIP_MEMORY_SCOPE_AGENT);
    unsigned v1 = __hip_atomic_load(flags + 64 + lane,  __ATOMIC_RELAXED, __HIP_MEMORY_SCOPE_AGENT);
    unsigned v2 = __hip_atomic_load(flags + 128 + lane, __ATOMIC_RELAXED, __HIP_MEMORY_SCOPE_AGENT);
    unsigned v3 = __hip_atomic_load(flags + 192 + lane, __ATOMIC_RELAXED, __HIP_MEMORY_SCOPE_AGENT);
    unsigned m01 = v0 < v1 ? v0 : v1;
    unsigned m23 = v2 < v3 ? v2 : v3;
    unsigned mn  = m01 < m23 ? m01 : m23;
    if (__all((int)(mn >= tgt))) break;
    __builtin_amdgcn_s_sleep(1);
  }
  asm volatile("" ::: "memory");  // keep subsequent data loads below the poll
}

// ---------- persistent LSTM recurrence (cooperative, weights in VGPRs) ----------
// h for step s is read from ys[s-1] (plain cached loads; L2-broadcast within
// each XCD) and written to ys[s] via agent-scope atomic stores.
__global__ __launch_bounds__(256) void lstm_persistent(
    const float* __restrict__ whT,   // [4096 cols][1024 k] this layer
    const float* __restrict__ xw,    // [256][16][4096]
    const float* __restrict__ bh,    // [4096]
    const float* __restrict__ h0,    // [16][1024]
    const float* __restrict__ c0,    // [16][1024]
    float* __restrict__ ys,          // [256][16][1024] = h sequence (output)
    float* __restrict__ hfin, float* __restrict__ cfin,
    unsigned* __restrict__ flags, unsigned base) {
  __shared__ float red[4][16][16];
  const int tid  = threadIdx.x;
  const int lane = tid & 63;
  const int wave = tid >> 6;
  const int bid  = blockIdx.x;
  const int lc   = lane & 15;
  const int kg8  = (lane >> 4) << 3;
  const int wk   = wave << 8;

  // B-frags: weights, split bf16, loaded once into VGPRs
  const int gcol = (lc & 3) * 1024 + (bid << 2) + (lc >> 2);
  bf16x8 w_h[8], w_l[8];
#pragma unroll
  for (int kk = 0; kk < 8; ++kk) {
    const float* src = whT + ((size_t)gcol << 10) + (wk + (kk << 5) + kg8);
    f32x4 v0 = *(const f32x4*)src;
    f32x4 v1 = *(const f32x4*)(src + 4);
    u16x8 h8, l8;
#pragma unroll
    for (int j = 0; j < 4; ++j) {
      unsigned short hh, ll;
      split1(v0[j], hh, ll); h8[j] = hh;     l8[j] = ll;
      split1(v1[j], hh, ll); h8[4 + j] = hh; l8[4 + j] = ll;
    }
    w_h[kk] = __builtin_bit_cast(bf16x8, h8);
    w_l[kk] = __builtin_bit_cast(bf16x8, l8);
  }

  // activation-thread state (tid<64 == wave 0): (batch ab, unit-local ai)
  const int ab = tid & 15;
  const int ai = tid >> 4;
  const int au = (bid << 2) + (ai & 3);
  float c_reg = 0.f, h_keep = 0.f;
  float bhv[4], xwv[4], xwn[4];
  if (tid < 64) {
    c_reg = c0[(ab << 10) + au];
#pragma unroll
    for (int g = 0; g < 4; ++g) bhv[g] = bh[(g << 10) + au];
#pragma unroll
    for (int g = 0; g < 4; ++g) xwv[g] = xw[(ab << 12) + (g << 10) + au];
  }

  for (int s = 0; s < 256; ++s) {
    // prefetch next step's xw early: in flight under the whole step
    if (tid < 64 && s < 255) {
      const float* xn = xw + ((size_t)(s + 1) << 16);
#pragma unroll
      for (int g = 0; g < 4; ++g) xwn[g] = xn[(ab << 12) + (g << 10) + au];
    }
    // h source: step-unique address (first-touch) -> plain cached loads
    const float* hsrc = (s == 0) ? h0 : (ys + ((size_t)(s - 1) << 14));
    f32x4 acc0 = {}, acc1 = {}, acc2 = {};
#pragma unroll
    for (int kk = 0; kk < 8; ++kk) {
      const float* hp = hsrc + (lc << 10) + wk + (kk << 5) + kg8;
      f32x4 v0 = *(const f32x4*)hp;
      f32x4 v1 = *(const f32x4*)(hp + 4);
      u16x8 h8, l8;
#pragma unroll
      for (int j = 0; j < 4; ++j) {
        unsigned short hh, ll;
        split1(v0[j], hh, ll); h8[j] = hh;     l8[j] = ll;
        split1(v1[j], hh, ll); h8[4 + j] = hh; l8[4 + j] = ll;
      }
      bf16x8 ah = __builtin_bit_cast(bf16x8, h8);
      bf16x8 al = __builtin_bit_cast(bf16x8, l8);
      acc0 = __builtin_amdgcn_mfma_f32_16x16x32_bf16(ah, w_h[kk], acc0, 0, 0, 0);
      acc1 = __builtin_amdgcn_mfma_f32_16x16x32_bf16(ah, w_l[kk], acc1, 0, 0, 0);
      acc2 = __builtin_amdgcn_mfma_f32_16x16x32_bf16(al, w_h[kk], acc2, 0, 0, 0);
    }
    f32x4 a = acc0 + acc1 + acc2;
#pragma unroll
    for (int r = 0; r < 4; ++r) red[wave][(lane >> 4) * 4 + r][lc] = a[r];
    __syncthreads();
    if (tid < 64) {
      float pre[4];
#pragma unroll
      for (int g = 0; g < 4; ++g) {
        int c = (ai << 2) + g;
        pre[g] = red[0][ab][c] + red[1][ab][c] + red[2][ab][c] + red[3][ab][c]
               + xwv[g] + bhv[g];
      }
      float f  = 1.f / (1.f + expf(-pre[0]));
      float i_ = 1.f / (1.f + expf(-pre[1]));
      float o  = 1.f / (1.f + expf(-pre[2]));
      float g_ = tanhf(pre[3]);
      c_reg = f * c_reg + i_ * g_;
      float h = o * tanhf(c_reg);
      h_keep = h;
      // publish h: write-through agent-scope atomic store to ys[s]
      __hip_atomic_store((unsigned*)ys + (((size_t)s << 14) + (ab << 10) + au),
                         __builtin_bit_cast(unsigned, h),
                         __ATOMIC_RELAXED, __HIP_MEMORY_SCOPE_AGENT);
#pragma unroll
      for (int g = 0; g < 4; ++g) xwv[g] = xwn[g];
    }
    if (wave == 0) {
      asm volatile("s_waitcnt vmcnt(0)" ::: "memory");  // h stores ack'd at coherence point
      if (lane == 0)
        __hip_atomic_store(&flags[bid], base + 1u + (unsigned)s, __ATOMIC_RELAXED, __HIP_MEMORY_SCOPE_AGENT);
      if (s < 255)
        poll_flags(flags, base + 1u + (unsigned)s, lane);
    }
    __syncthreads();
  }
  if (tid < 64) {
    hfin[(ab << 10) + au] = h_keep;
    cfin[(ab << 10) + au] = c_reg;
  }
}

// ---------- small utility kernels ----------
__global__ __launch_bounds__(256) void embed_gather(
    const int* __restrict__ tokens, const float* __restrict__ emb, float* __restrict__ x) {
  int sb = blockIdx.x;
  int tok = tokens[sb];
  const f32x4* src = (const f32x4*)(emb + (size_t)tok * 1024);
  f32x4* dst = (f32x4*)(x + (size_t)sb * 1024);
  dst[threadIdx.x] = src[threadIdx.x];
}

__global__ void transpose_wh(const float* __restrict__ wh, float* __restrict__ whT) {
  __shared__ float tile[32][33];
  int l = blockIdx.z;
  int c0 = blockIdx.x << 5;
  int k0 = blockIdx.y << 5;
  int tx = threadIdx.x, ty = threadIdx.y;  // 32 x 8
  const float* src = wh + ((size_t)l << 22);
  float* dst = whT + ((size_t)l << 22);
#pragma unroll
  for (int i = 0; i < 32; i += 8)
    tile[ty + i][tx] = src[(size_t)(k0 + ty + i) * 4096 + c0 + tx];
  __syncthreads();
#pragma unroll
  for (int i = 0; i < 32; i += 8)
    dst[(size_t)(c0 + ty + i) * 1024 + k0 + tx] = tile[tx][ty + i];
}

// ---------- host ----------
extern "C" void kernel_launch(void* const* d_in, const int* in_sizes, int n_in,
                              void* d_out, int out_size, void* d_ws, size_t ws_size,
                              hipStream_t stream) {
  (void)in_sizes; (void)n_in; (void)out_size; (void)ws_size;
  const int*   tokens    = (const int*)  d_in[0];
  const float* hidden    = (const float*)d_in[1];
  const float* embedding = (const float*)d_in[2];
  const float* wi        = (const float*)d_in[3];
  const float* bi        = (const float*)d_in[4];
  const float* wh        = (const float*)d_in[5];
  const float* bh        = (const float*)d_in[6];
  const float* wdec      = (const float*)d_in[7];
  const float* bdec      = (const float*)d_in[8];

  float* out     = (float*)d_out;
  float* out_res = out;                                   // 256*16*50257
  float* out_nh  = out + (size_t)205852672;               // 2*2*16*1024
  float* out_x   = out + (size_t)205852672 + 65536;       // 256*16*1024

  // workspace layout (floats)
  float* ws    = (float*)d_ws;
  float* whT   = ws;                        // 2*4096*1024 = 8388608
  float* x_emb = whT   + 8388608;           // 4096*1024   = 4194304
  float* xwb   = x_emb + 4194304;           // 4096*4096   = 16777216
  float* ys0   = xwb   + 16777216;          // 4096*1024   = 4194304
  unsigned* flags = (unsigned*)(ys0 + 4194304);  // 256 u32 (pad 4096)

  hipMemsetAsync(flags, 0, 4096 * sizeof(unsigned), stream);
  transpose_wh<<<dim3(128, 32, 2), dim3(32, 8), 0, stream>>>(wh, whT);
  embed_gather<<<4096, 256, 0, stream>>>(tokens, embedding, x_emb);

  for (int l = 0; l < 2; ++l) {
    const float* a = (l == 0) ? x_emb : ys0;
    gemm_split3<<<dim3(32, 32), 256, 0, stream>>>(
        a, wi + (size_t)l * 4194304, bi + l * 4096, xwb, 4096, 4096, 1024);

    const float* wT   = whT + (size_t)l * 4194304;
    const float* xwp  = xwb;
    const float* bhl  = bh + l * 4096;
    const float* h0p  = hidden + (size_t)l * 32768;
    const float* c0p  = h0p + 16384;
    float* ysp  = (l == 0) ? ys0 : out_x;
    float* hfin = out_nh + (size_t)l * 32768;
    float* cfin = hfin + 16384;
    unsigned basev = (unsigned)(l * 256);
    unsigned* flp = flags;
    void* args[] = { &wT, &xwp, &bhl, &h0p, &c0p, &ysp, &hfin, &cfin, &flp, &basev };
    hipLaunchCooperativeKernel((const void*)lstm_persistent,
                               dim3(256), dim3(256), args, 0, stream);
  }
  gemm_split3<<<dim3(32, 393), 256, 0, stream>>>(
      out_x, wdec, bdec, out_res, 4096, 50257, 1024);
}

// Round 8
// 6775.315 us; speedup vs baseline: 2.4148x; 1.0494x over previous
//
#include <hip/hip_runtime.h>

// ---------- types ----------
typedef float  f32x4  __attribute__((ext_vector_type(4)));
typedef unsigned short u16x4 __attribute__((ext_vector_type(4)));
typedef unsigned short u16x8 __attribute__((ext_vector_type(8)));
typedef __bf16 bf16x8 __attribute__((ext_vector_type(8)));

// round-to-nearest-even f32 -> bf16 (bit trick)
static __device__ __forceinline__ unsigned short bf16_rn(float x) {
  unsigned u = __builtin_bit_cast(unsigned, x);
  unsigned r = (u + 0x7FFFu + ((u >> 16) & 1u)) >> 16;
  return (unsigned short)r;
}
// split x ~= hi + lo (each bf16); residual ~2^-17 relative
static __device__ __forceinline__ void split1(float x, unsigned short& h, unsigned short& l) {
  unsigned short hh = bf16_rn(x);
  float hf = __builtin_bit_cast(float, ((unsigned)hh) << 16);
  h = hh;
  l = bf16_rn(x - hf);
}

#define BM 128
#define BN 128
#define BK 32
#define LDK 40

// XOR-swizzled LDS index: 16B chunks permuted by row (breaks power-of-2 row
// alignment, keeps 16B alignment for ds_read_b128 / ds_write_b128).
static __device__ __forceinline__ int lds_idx(int row, int k) {
  return row * LDK + ((((k >> 3) ^ (row >> 2)) & 3) << 3) + (k & 7);
}

// ---------- GEMM (pre-split inputs): C = A * B^T + bias ----------
// A_h/A_l: [M][K] bf16 row-major. B_h/B_l: [Npad][K] bf16 (k-contiguous,
// pre-transposed, pad rows zero-filled). 3-term split MFMA, fp32-grade.
__global__ __launch_bounds__(256) void gemm_ps(
    const unsigned short* __restrict__ Ahg, const unsigned short* __restrict__ Alg,
    const unsigned short* __restrict__ Bhg, const unsigned short* __restrict__ Blg,
    const float* __restrict__ bias, float* __restrict__ C,
    int M, int N, int K) {
  __shared__ unsigned short Ah[BM * LDK];
  __shared__ unsigned short Al[BM * LDK];
  __shared__ unsigned short Bh[BN * LDK];
  __shared__ unsigned short Bl[BN * LDK];

  const int tid  = threadIdx.x;
  const int lane = tid & 63;
  const int wave = tid >> 6;
  const int bm = blockIdx.x * BM;
  const int bn = blockIdx.y * BN;
  const int wm = (wave >> 1) * 64;
  const int wn = (wave & 1) * 64;

  f32x4 acc[4][4] = {};

  // staging: thread t -> row (t>>2)+64p, k-chunk (t&3)*8 (4 lanes/row = 64B line)
  const int srow = tid >> 2;
  const int sk   = (tid & 3) << 3;

  for (int k0 = 0; k0 < K; k0 += BK) {
#pragma unroll
    for (int p = 0; p < 2; ++p) {
      int r = srow + (p << 6);
      size_t ga = (size_t)(bm + r) * K + k0 + sk;
      size_t gb = (size_t)(bn + r) * K + k0 + sk;
      int ix = lds_idx(r, sk);
      *(u16x8*)(&Ah[ix]) = *(const u16x8*)(Ahg + ga);
      *(u16x8*)(&Al[ix]) = *(const u16x8*)(Alg + ga);
      *(u16x8*)(&Bh[ix]) = *(const u16x8*)(Bhg + gb);
      *(u16x8*)(&Bl[ix]) = *(const u16x8*)(Blg + gb);
    }
    __syncthreads();

    const int fr = lane & 15;
    const int kg = (lane >> 4) << 3;
    u16x8 a_h[4], a_l[4], b_h[4], b_l[4];
#pragma unroll
    for (int i = 0; i < 4; ++i) {
      int ia = lds_idx(wm + i * 16 + fr, kg);
      int ib = lds_idx(wn + i * 16 + fr, kg);
      a_h[i] = *(const u16x8*)(&Ah[ia]);
      a_l[i] = *(const u16x8*)(&Al[ia]);
      b_h[i] = *(const u16x8*)(&Bh[ib]);
      b_l[i] = *(const u16x8*)(&Bl[ib]);
    }
#pragma unroll
    for (int i = 0; i < 4; ++i)
#pragma unroll
      for (int j = 0; j < 4; ++j) {
        acc[i][j] = __builtin_amdgcn_mfma_f32_16x16x32_bf16(
            __builtin_bit_cast(bf16x8, a_h[i]), __builtin_bit_cast(bf16x8, b_h[j]), acc[i][j], 0, 0, 0);
        acc[i][j] = __builtin_amdgcn_mfma_f32_16x16x32_bf16(
            __builtin_bit_cast(bf16x8, a_h[i]), __builtin_bit_cast(bf16x8, b_l[j]), acc[i][j], 0, 0, 0);
        acc[i][j] = __builtin_amdgcn_mfma_f32_16x16x32_bf16(
            __builtin_bit_cast(bf16x8, a_l[i]), __builtin_bit_cast(bf16x8, b_h[j]), acc[i][j], 0, 0, 0);
      }
    __syncthreads();
  }
  const int cc = lane & 15;
  const int rg = (lane >> 4) << 2;
#pragma unroll
  for (int i = 0; i < 4; ++i)
#pragma unroll
    for (int j = 0; j < 4; ++j)
#pragma unroll
      for (int r = 0; r < 4; ++r) {
        int row = bm + wm + i * 16 + rg + r;
        int col = bn + wn + j * 16 + cc;
        if (col < N) {
          float v = acc[i][j][r];
          if (bias) v += bias[col];
          C[(size_t)row * N + col] = v;
        }
      }
}

// ---------- legacy GEMM (inline split) -- fallback when ws is small ----------
__global__ __launch_bounds__(256) void gemm_split3(
    const float* __restrict__ A, const float* __restrict__ B,
    const float* __restrict__ bias, float* __restrict__ C,
    int M, int N, int K) {
  __shared__ unsigned short Ah[BM * LDK];
  __shared__ unsigned short Al[BM * LDK];
  __shared__ unsigned short Bh[BN * LDK];
  __shared__ unsigned short Bl[BN * LDK];

  const int tid  = threadIdx.x;
  const int lane = tid & 63;
  const int wave = tid >> 6;
  const int bm = blockIdx.x * BM;
  const int bn = blockIdx.y * BN;
  const int wm = (wave >> 1) * 64;
  const int wn = (wave & 1) * 64;

  f32x4 acc[4][4] = {};

  const int ar  = tid >> 3;
  const int ak  = (tid & 7) << 2;
  const int bcol = tid & 127;
  const int bkh  = (tid >> 7) << 4;
  const bool bok = (bn + bcol) < N;
  const float* bsrc0 = B + (size_t)bkh * N + (bn + bcol);

  for (int k0 = 0; k0 < K; k0 += BK) {
#pragma unroll
    for (int p = 0; p < 4; ++p) {
      int r = ar + (p << 5);
      f32x4 v = *(const f32x4*)(A + (size_t)(bm + r) * K + (k0 + ak));
      u16x4 h, l;
#pragma unroll
      for (int j = 0; j < 4; ++j) { unsigned short hh, ll; split1(v[j], hh, ll); h[j] = hh; l[j] = ll; }
      int ix = lds_idx(r, ak);
      *(u16x4*)(&Ah[ix]) = h;
      *(u16x4*)(&Al[ix]) = l;
    }
    {
      const float* src = bsrc0 + (size_t)k0 * N;
      float bv[16];
#pragma unroll
      for (int q = 0; q < 16; ++q)
        bv[q] = bok ? src[(size_t)q * N] : 0.f;
      u16x8 h0, h1, l0, l1;
#pragma unroll
      for (int q = 0; q < 8; ++q) {
        unsigned short hh, ll;
        split1(bv[q], hh, ll);     h0[q] = hh; l0[q] = ll;
        split1(bv[8 + q], hh, ll); h1[q] = hh; l1[q] = ll;
      }
      int ix0 = lds_idx(bcol, bkh);
      int ix1 = lds_idx(bcol, bkh + 8);
      *(u16x8*)(&Bh[ix0]) = h0;
      *(u16x8*)(&Bh[ix1]) = h1;
      *(u16x8*)(&Bl[ix0]) = l0;
      *(u16x8*)(&Bl[ix1]) = l1;
    }
    __syncthreads();

    const int fr = lane & 15;
    const int kg = (lane >> 4) << 3;
    u16x8 a_h[4], a_l[4], b_h[4], b_l[4];
#pragma unroll
    for (int i = 0; i < 4; ++i) {
      int ia = lds_idx(wm + i * 16 + fr, kg);
      int ib = lds_idx(wn + i * 16 + fr, kg);
      a_h[i] = *(const u16x8*)(&Ah[ia]);
      a_l[i] = *(const u16x8*)(&Al[ia]);
      b_h[i] = *(const u16x8*)(&Bh[ib]);
      b_l[i] = *(const u16x8*)(&Bl[ib]);
    }
#pragma unroll
    for (int i = 0; i < 4; ++i)
#pragma unroll
      for (int j = 0; j < 4; ++j) {
        acc[i][j] = __builtin_amdgcn_mfma_f32_16x16x32_bf16(
            __builtin_bit_cast(bf16x8, a_h[i]), __builtin_bit_cast(bf16x8, b_h[j]), acc[i][j], 0, 0, 0);
        acc[i][j] = __builtin_amdgcn_mfma_f32_16x16x32_bf16(
            __builtin_bit_cast(bf16x8, a_h[i]), __builtin_bit_cast(bf16x8, b_l[j]), acc[i][j], 0, 0, 0);
        acc[i][j] = __builtin_amdgcn_mfma_f32_16x16x32_bf16(
            __builtin_bit_cast(bf16x8, a_l[i]), __builtin_bit_cast(bf16x8, b_h[j]), acc[i][j], 0, 0, 0);
      }
    __syncthreads();
  }
  const int cc = lane & 15;
  const int rg = (lane >> 4) << 2;
#pragma unroll
  for (int i = 0; i < 4; ++i)
#pragma unroll
    for (int j = 0; j < 4; ++j)
#pragma unroll
      for (int r = 0; r < 4; ++r) {
        int row = bm + wm + i * 16 + rg + r;
        int col = bn + wn + j * 16 + cc;
        if (col < N) {
          float v = acc[i][j][r];
          if (bias) v += bias[col];
          C[(size_t)row * N + col] = v;
        }
      }
}

// ---------- fence-free grid barrier ----------
static __device__ __forceinline__ void poll_flags(const unsigned* flags, unsigned tgt, int lane) {
  for (;;) {
    unsigned v0 = __hip_atomic_load(flags + lane,       __ATOMIC_RELAXED, __HIP_MEMORY_SCOPE_AGENT);
    unsigned v1 = __hip_atomic_load(flags + 64 + lane,  __ATOMIC_RELAXED, __HIP_MEMORY_SCOPE_AGENT);
    unsigned v2 = __hip_atomic_load(flags + 128 + lane, __ATOMIC_RELAXED, __HIP_MEMORY_SCOPE_AGENT);
    unsigned v3 = __hip_atomic_load(flags + 192 + lane, __ATOMIC_RELAXED, __HIP_MEMORY_SCOPE_AGENT);
    unsigned m01 = v0 < v1 ? v0 : v1;
    unsigned m23 = v2 < v3 ? v2 : v3;
    unsigned mn  = m01 < m23 ? m01 : m23;
    if (__all((int)(mn >= tgt))) break;
    __builtin_amdgcn_s_sleep(1);
  }
  asm volatile("" ::: "memory");  // keep subsequent data loads below the poll
}

// ---------- persistent LSTM recurrence (cooperative, weights in VGPRs) ----------
// h for step s is read from ys[s-1] (plain cached loads; first-touch addresses
// so no stale copies) and written to ys[s] via agent-scope atomic stores.
__global__ __launch_bounds__(256) void lstm_persistent(
    const float* __restrict__ whT,   // [4096 cols][1024 k] this layer
    const float* __restrict__ xw,    // [256][16][4096]
    const float* __restrict__ bh,    // [4096]
    const float* __restrict__ h0,    // [16][1024]
    const float* __restrict__ c0,    // [16][1024]
    float* __restrict__ ys,          // [256][16][1024] = h sequence (output)
    float* __restrict__ hfin, float* __restrict__ cfin,
    unsigned* __restrict__ flags, unsigned base) {
  __shared__ float red[4][16][16];
  const int tid  = threadIdx.x;
  const int lane = tid & 63;
  const int wave = tid >> 6;
  const int bid  = blockIdx.x;
  const int lc   = lane & 15;
  const int kg8  = (lane >> 4) << 3;
  const int wk   = wave << 8;

  // B-frags: weights, split bf16, loaded once into VGPRs
  const int gcol = (lc & 3) * 1024 + (bid << 2) + (lc >> 2);
  bf16x8 w_h[8], w_l[8];
#pragma unroll
  for (int kk = 0; kk < 8; ++kk) {
    const float* src = whT + ((size_t)gcol << 10) + (wk + (kk << 5) + kg8);
    f32x4 v0 = *(const f32x4*)src;
    f32x4 v1 = *(const f32x4*)(src + 4);
    u16x8 h8, l8;
#pragma unroll
    for (int j = 0; j < 4; ++j) {
      unsigned short hh, ll;
      split1(v0[j], hh, ll); h8[j] = hh;     l8[j] = ll;
      split1(v1[j], hh, ll); h8[4 + j] = hh; l8[4 + j] = ll;
    }
    w_h[kk] = __builtin_bit_cast(bf16x8, h8);
    w_l[kk] = __builtin_bit_cast(bf16x8, l8);
  }

  const int ab = tid & 15;
  const int ai = tid >> 4;
  const int au = (bid << 2) + (ai & 3);
  float c_reg = 0.f, h_keep = 0.f;
  float bhv[4], xwv[4], xwn[4];
  if (tid < 64) {
    c_reg = c0[(ab << 10) + au];
#pragma unroll
    for (int g = 0; g < 4; ++g) bhv[g] = bh[(g << 10) + au];
#pragma unroll
    for (int g = 0; g < 4; ++g) xwv[g] = xw[(ab << 12) + (g << 10) + au];
  }

  for (int s = 0; s < 256; ++s) {
    if (tid < 64 && s < 255) {
      const float* xn = xw + ((size_t)(s + 1) << 16);
#pragma unroll
      for (int g = 0; g < 4; ++g) xwn[g] = xn[(ab << 12) + (g << 10) + au];
    }
    const float* hsrc = (s == 0) ? h0 : (ys + ((size_t)(s - 1) << 14));
    f32x4 acc0 = {}, acc1 = {}, acc2 = {};
#pragma unroll
    for (int kk = 0; kk < 8; ++kk) {
      const float* hp = hsrc + (lc << 10) + wk + (kk << 5) + kg8;
      f32x4 v0 = *(const f32x4*)hp;
      f32x4 v1 = *(const f32x4*)(hp + 4);
      u16x8 h8, l8;
#pragma unroll
      for (int j = 0; j < 4; ++j) {
        unsigned short hh, ll;
        split1(v0[j], hh, ll); h8[j] = hh;     l8[j] = ll;
        split1(v1[j], hh, ll); h8[4 + j] = hh; l8[4 + j] = ll;
      }
      bf16x8 ah = __builtin_bit_cast(bf16x8, h8);
      bf16x8 al = __builtin_bit_cast(bf16x8, l8);
      acc0 = __builtin_amdgcn_mfma_f32_16x16x32_bf16(ah, w_h[kk], acc0, 0, 0, 0);
      acc1 = __builtin_amdgcn_mfma_f32_16x16x32_bf16(ah, w_l[kk], acc1, 0, 0, 0);
      acc2 = __builtin_amdgcn_mfma_f32_16x16x32_bf16(al, w_h[kk], acc2, 0, 0, 0);
    }
    f32x4 a = acc0 + acc1 + acc2;
#pragma unroll
    for (int r = 0; r < 4; ++r) red[wave][(lane >> 4) * 4 + r][lc] = a[r];
    __syncthreads();
    if (tid < 64) {
      float pre[4];
#pragma unroll
      for (int g = 0; g < 4; ++g) {
        int c = (ai << 2) + g;
        pre[g] = red[0][ab][c] + red[1][ab][c] + red[2][ab][c] + red[3][ab][c]
               + xwv[g] + bhv[g];
      }
      float f  = 1.f / (1.f + expf(-pre[0]));
      float i_ = 1.f / (1.f + expf(-pre[1]));
      float o  = 1.f / (1.f + expf(-pre[2]));
      float g_ = tanhf(pre[3]);
      c_reg = f * c_reg + i_ * g_;
      float h = o * tanhf(c_reg);
      h_keep = h;
      __hip_atomic_store((unsigned*)ys + (((size_t)s << 14) + (ab << 10) + au),
                         __builtin_bit_cast(unsigned, h),
                         __ATOMIC_RELAXED, __HIP_MEMORY_SCOPE_AGENT);
#pragma unroll
      for (int g = 0; g < 4; ++g) xwv[g] = xwn[g];
    }
    if (wave == 0) {
      asm volatile("s_waitcnt vmcnt(0)" ::: "memory");
      if (lane == 0)
        __hip_atomic_store(&flags[bid], base + 1u + (unsigned)s, __ATOMIC_RELAXED, __HIP_MEMORY_SCOPE_AGENT);
      if (s < 255)
        poll_flags(flags, base + 1u + (unsigned)s, lane);
    }
    __syncthreads();
  }
  if (tid < 64) {
    hfin[(ab << 10) + au] = h_keep;
    cfin[(ab << 10) + au] = c_reg;
  }
}

// ---------- prep kernels ----------
__global__ __launch_bounds__(256) void embed_gather(
    const int* __restrict__ tokens, const float* __restrict__ emb, float* __restrict__ x) {
  int sb = blockIdx.x;
  int tok = tokens[sb];
  const f32x4* src = (const f32x4*)(emb + (size_t)tok * 1024);
  f32x4* dst = (f32x4*)(x + (size_t)sb * 1024);
  dst[threadIdx.x] = src[threadIdx.x];
}

// gather + split: xh/xl [4096][1024] bf16
__global__ __launch_bounds__(256) void embed_gather_split(
    const int* __restrict__ tokens, const float* __restrict__ emb,
    unsigned short* __restrict__ xh, unsigned short* __restrict__ xl) {
  int sb = blockIdx.x;
  int tok = tokens[sb];
  f32x4 v = ((const f32x4*)(emb + (size_t)tok * 1024))[threadIdx.x];
  u16x4 h, l;
#pragma unroll
  for (int j = 0; j < 4; ++j) { unsigned short hh, ll; split1(v[j], hh, ll); h[j] = hh; l[j] = ll; }
  size_t o = (size_t)sb * 1024 + threadIdx.x * 4;
  *(u16x4*)(xh + o) = h;
  *(u16x4*)(xl + o) = l;
}

// split f32 array -> bf16 hi/lo (element count multiple of 1024)
__global__ __launch_bounds__(256) void split_mat(
    const float* __restrict__ x, unsigned short* __restrict__ xh,
    unsigned short* __restrict__ xl) {
  size_t i = (size_t)blockIdx.x * 256 + threadIdx.x;
  f32x4 v = ((const f32x4*)x)[i];
  u16x4 h, l;
#pragma unroll
  for (int j = 0; j < 4; ++j) { unsigned short hh, ll; split1(v[j], hh, ll); h[j] = hh; l[j] = ll; }
  *(u16x4*)(xh + i * 4) = h;
  *(u16x4*)(xl + i * 4) = l;
}

// W [K][N] f32 -> WT_h/WT_l [Npad][K] bf16 (k-contiguous); pad rows zeroed
__global__ void split_transpose_w(
    const float* __restrict__ W, unsigned short* __restrict__ WTh,
    unsigned short* __restrict__ WTl, int K, int N) {
  __shared__ float tile[32][33];
  int n0 = blockIdx.x << 5;
  int k0 = blockIdx.y << 5;
  int tx = threadIdx.x, ty = threadIdx.y;  // 32 x 8
#pragma unroll
  for (int i = 0; i < 32; i += 8) {
    int n = n0 + tx;
    tile[ty + i][tx] = (n < N) ? W[(size_t)(k0 + ty + i) * N + n] : 0.f;
  }
  __syncthreads();
#pragma unroll
  for (int i = 0; i < 32; i += 8) {
    int n = n0 + ty + i;
    float v = tile[tx][ty + i];
    unsigned short h, l; split1(v, h, l);
    WTh[(size_t)n * K + k0 + tx] = h;
    WTl[(size_t)n * K + k0 + tx] = l;
  }
}

__global__ void transpose_wh(const float* __restrict__ wh, float* __restrict__ whT) {
  __shared__ float tile[32][33];
  int l = blockIdx.z;
  int c0 = blockIdx.x << 5;
  int k0 = blockIdx.y << 5;
  int tx = threadIdx.x, ty = threadIdx.y;  // 32 x 8
  const float* src = wh + ((size_t)l << 22);
  float* dst = whT + ((size_t)l << 22);
#pragma unroll
  for (int i = 0; i < 32; i += 8)
    tile[ty + i][tx] = src[(size_t)(k0 + ty + i) * 4096 + c0 + tx];
  __syncthreads();
#pragma unroll
  for (int i = 0; i < 32; i += 8)
    dst[(size_t)(c0 + ty + i) * 1024 + k0 + tx] = tile[tx][ty + i];
}

// ---------- host ----------
extern "C" void kernel_launch(void* const* d_in, const int* in_sizes, int n_in,
                              void* d_out, int out_size, void* d_ws, size_t ws_size,
                              hipStream_t stream) {
  (void)in_sizes; (void)n_in; (void)out_size;
  const int*   tokens    = (const int*)  d_in[0];
  const float* hidden    = (const float*)d_in[1];
  const float* embedding = (const float*)d_in[2];
  const float* wi        = (const float*)d_in[3];
  const float* bi        = (const float*)d_in[4];
  const float* wh        = (const float*)d_in[5];
  const float* bh        = (const float*)d_in[6];
  const float* wdec      = (const float*)d_in[7];
  const float* bdec      = (const float*)d_in[8];

  float* out     = (float*)d_out;
  float* out_res = out;                                   // 256*16*50257
  float* out_nh  = out + (size_t)205852672;               // 2*2*16*1024
  float* out_x   = out + (size_t)205852672 + 65536;       // 256*16*1024

  // ---- common workspace (floats) ----
  float* ws    = (float*)d_ws;
  float* whT   = ws;                        // 2*4096*1024 = 8388608 f
  float* xwb   = whT + 8388608;             // 4096*4096   = 16777216 f
  float* ys0   = xwb + 16777216;            // 4096*1024   = 4194304 f
  unsigned* flags = (unsigned*)(ys0 + 4194304);  // 4096 u32
  // presplit region (u16) after flags:
  unsigned short* u16base = (unsigned short*)(flags + 4096);
  unsigned short* Ah_s  = u16base;                 // 4194304
  unsigned short* Al_s  = Ah_s + 4194304;          // 4194304
  unsigned short* wiTh  = Al_s + 4194304;          // 2*4096*1024 = 8388608
  unsigned short* wiTl  = wiTh + 8388608;          // 8388608
  unsigned short* wdTh  = wiTl + 8388608;          // 50304*1024 = 51511296
  unsigned short* wdTl  = wdTh + 51511296;         // 51511296
  size_t need = (size_t)((char*)(wdTl + 51511296) - (char*)d_ws);
  const bool presplit = ws_size >= need;

  hipMemsetAsync(flags, 0, 4096 * sizeof(unsigned), stream);
  transpose_wh<<<dim3(128, 32, 2), dim3(32, 8), 0, stream>>>(wh, whT);

  if (presplit) {
    // pre-split + transpose all GEMM operands once
    split_transpose_w<<<dim3(128, 32), dim3(32, 8), 0, stream>>>(wi, wiTh, wiTl, 1024, 4096);
    split_transpose_w<<<dim3(128, 32), dim3(32, 8), 0, stream>>>(wi + 4194304, wiTh + 4194304, wiTl + 4194304, 1024, 4096);
    split_transpose_w<<<dim3(1572, 32), dim3(32, 8), 0, stream>>>(wdec, wdTh, wdTl, 1024, 50257);
    embed_gather_split<<<4096, 256, 0, stream>>>(tokens, embedding, Ah_s, Al_s);

    for (int l = 0; l < 2; ++l) {
      gemm_ps<<<dim3(32, 32), 256, 0, stream>>>(
          Ah_s, Al_s, wiTh + (size_t)l * 4194304, wiTl + (size_t)l * 4194304,
          bi + l * 4096, xwb, 4096, 4096, 1024);

      const float* wT   = whT + (size_t)l * 4194304;
      const float* xwp  = xwb;
      const float* bhl  = bh + l * 4096;
      const float* h0p  = hidden + (size_t)l * 32768;
      const float* c0p  = h0p + 16384;
      float* ysp  = (l == 0) ? ys0 : out_x;
      float* hfin = out_nh + (size_t)l * 32768;
      float* cfin = hfin + 16384;
      unsigned basev = (unsigned)(l * 256);
      unsigned* flp = flags;
      void* args[] = { &wT, &xwp, &bhl, &h0p, &c0p, &ysp, &hfin, &cfin, &flp, &basev };
      hipLaunchCooperativeKernel((const void*)lstm_persistent,
                                 dim3(256), dim3(256), args, 0, stream);
      split_mat<<<4096, 256, 0, stream>>>(ysp, Ah_s, Al_s);
    }
    gemm_ps<<<dim3(32, 393), 256, 0, stream>>>(
        Ah_s, Al_s, wdTh, wdTl, bdec, out_res, 4096, 50257, 1024);
  } else {
    // fallback: inline-split path (round-7 structure); reuse Ah_s region as x_emb
    float* x_emb = (float*)u16base;   // 4194304 f
    embed_gather<<<4096, 256, 0, stream>>>(tokens, embedding, x_emb);
    for (int l = 0; l < 2; ++l) {
      const float* a = (l == 0) ? x_emb : ys0;
      gemm_split3<<<dim3(32, 32), 256, 0, stream>>>(
          a, wi + (size_t)l * 4194304, bi + l * 4096, xwb, 4096, 4096, 1024);
      const float* wT   = whT + (size_t)l * 4194304;
      const float* xwp  = xwb;
      const float* bhl  = bh + l * 4096;
      const float* h0p  = hidden + (size_t)l * 32768;
      const float* c0p  = h0p + 16384;
      float* ysp  = (l == 0) ? ys0 : out_x;
      float* hfin = out_nh + (size_t)l * 32768;
      float* cfin = hfin + 16384;
      unsigned basev = (unsigned)(l * 256);
      unsigned* flp = flags;
      void* args[] = { &wT, &xwp, &bhl, &h0p, &c0p, &ysp, &hfin, &cfin, &flp, &basev };
      hipLaunchCooperativeKernel((const void*)lstm_persistent,
                                 dim3(256), dim3(256), args, 0, stream);
    }
    gemm_split3<<<dim3(32, 393), 256, 0, stream>>>(
        out_x, wdec, bdec, out_res, 4096, 50257, 1024);
  }
}

// Round 11
// 6770.210 us; speedup vs baseline: 2.4166x; 1.0008x over previous
//
#include <hip/hip_runtime.h>

// ---------- types ----------
typedef float  f32x4  __attribute__((ext_vector_type(4)));
typedef unsigned short u16x4 __attribute__((ext_vector_type(4)));
typedef unsigned short u16x8 __attribute__((ext_vector_type(8)));
typedef __bf16 bf16x8 __attribute__((ext_vector_type(8)));

// round-to-nearest-even f32 -> bf16 (bit trick)
static __device__ __forceinline__ unsigned short bf16_rn(float x) {
  unsigned u = __builtin_bit_cast(unsigned, x);
  unsigned r = (u + 0x7FFFu + ((u >> 16) & 1u)) >> 16;
  return (unsigned short)r;
}
// split x ~= hi + lo (each bf16); residual ~2^-17 relative
static __device__ __forceinline__ void split1(float x, unsigned short& h, unsigned short& l) {
  unsigned short hh = bf16_rn(x);
  float hf = __builtin_bit_cast(float, ((unsigned)hh) << 16);
  h = hh;
  l = bf16_rn(x - hf);
}

#define BM 128
#define BN 128
#define BK 32
#define LDK 40

// XOR-swizzled LDS index: 16B chunks permuted by row.
static __device__ __forceinline__ int lds_idx(int row, int k) {
  return row * LDK + ((((k >> 3) ^ (row >> 2)) & 3) << 3) + (k & 7);
}

// ---------- GEMM (pre-split inputs): C = A * B^T + bias ----------
__global__ __launch_bounds__(256) void gemm_ps(
    const unsigned short* __restrict__ Ahg, const unsigned short* __restrict__ Alg,
    const unsigned short* __restrict__ Bhg, const unsigned short* __restrict__ Blg,
    const float* __restrict__ bias, float* __restrict__ C,
    int M, int N, int K) {
  __shared__ unsigned short Ah[BM * LDK];
  __shared__ unsigned short Al[BM * LDK];
  __shared__ unsigned short Bh[BN * LDK];
  __shared__ unsigned short Bl[BN * LDK];

  const int tid  = threadIdx.x;
  const int lane = tid & 63;
  const int wave = tid >> 6;
  const int bm = blockIdx.x * BM;
  const int bn = blockIdx.y * BN;
  const int wm = (wave >> 1) * 64;
  const int wn = (wave & 1) * 64;

  f32x4 acc[4][4] = {};

  const int srow = tid >> 2;
  const int sk   = (tid & 3) << 3;

  for (int k0 = 0; k0 < K; k0 += BK) {
#pragma unroll
    for (int p = 0; p < 2; ++p) {
      int r = srow + (p << 6);
      size_t ga = (size_t)(bm + r) * K + k0 + sk;
      size_t gb = (size_t)(bn + r) * K + k0 + sk;
      int ix = lds_idx(r, sk);
      *(u16x8*)(&Ah[ix]) = *(const u16x8*)(Ahg + ga);
      *(u16x8*)(&Al[ix]) = *(const u16x8*)(Alg + ga);
      *(u16x8*)(&Bh[ix]) = *(const u16x8*)(Bhg + gb);
      *(u16x8*)(&Bl[ix]) = *(const u16x8*)(Blg + gb);
    }
    __syncthreads();

    const int fr = lane & 15;
    const int kg = (lane >> 4) << 3;
    u16x8 a_h[4], a_l[4], b_h[4], b_l[4];
#pragma unroll
    for (int i = 0; i < 4; ++i) {
      int ia = lds_idx(wm + i * 16 + fr, kg);
      int ib = lds_idx(wn + i * 16 + fr, kg);
      a_h[i] = *(const u16x8*)(&Ah[ia]);
      a_l[i] = *(const u16x8*)(&Al[ia]);
      b_h[i] = *(const u16x8*)(&Bh[ib]);
      b_l[i] = *(const u16x8*)(&Bl[ib]);
    }
#pragma unroll
    for (int i = 0; i < 4; ++i)
#pragma unroll
      for (int j = 0; j < 4; ++j) {
        acc[i][j] = __builtin_amdgcn_mfma_f32_16x16x32_bf16(
            __builtin_bit_cast(bf16x8, a_h[i]), __builtin_bit_cast(bf16x8, b_h[j]), acc[i][j], 0, 0, 0);
        acc[i][j] = __builtin_amdgcn_mfma_f32_16x16x32_bf16(
            __builtin_bit_cast(bf16x8, a_h[i]), __builtin_bit_cast(bf16x8, b_l[j]), acc[i][j], 0, 0, 0);
        acc[i][j] = __builtin_amdgcn_mfma_f32_16x16x32_bf16(
            __builtin_bit_cast(bf16x8, a_l[i]), __builtin_bit_cast(bf16x8, b_h[j]), acc[i][j], 0, 0, 0);
      }
    __syncthreads();
  }
  const int cc = lane & 15;
  const int rg = (lane >> 4) << 2;
#pragma unroll
  for (int i = 0; i < 4; ++i)
#pragma unroll
    for (int j = 0; j < 4; ++j)
#pragma unroll
      for (int r = 0; r < 4; ++r) {
        int row = bm + wm + i * 16 + rg + r;
        int col = bn + wn + j * 16 + cc;
        if (col < N) {
          float v = acc[i][j][r];
          if (bias) v += bias[col];
          C[(size_t)row * N + col] = v;
        }
      }
}

// ---------- fence-free grid barrier (flags via agent-scope atomics) ----------
static __device__ __forceinline__ void poll_flags(const unsigned* flags, unsigned tgt, int lane) {
  for (;;) {
    unsigned v0 = __hip_atomic_load(flags + lane,       __ATOMIC_RELAXED, __HIP_MEMORY_SCOPE_AGENT);
    unsigned v1 = __hip_atomic_load(flags + 64 + lane,  __ATOMIC_RELAXED, __HIP_MEMORY_SCOPE_AGENT);
    unsigned v2 = __hip_atomic_load(flags + 128 + lane, __ATOMIC_RELAXED, __HIP_MEMORY_SCOPE_AGENT);
    unsigned v3 = __hip_atomic_load(flags + 192 + lane, __ATOMIC_RELAXED, __HIP_MEMORY_SCOPE_AGENT);
    unsigned m01 = v0 < v1 ? v0 : v1;
    unsigned m23 = v2 < v3 ? v2 : v3;
    unsigned mn  = m01 < m23 ? m01 : m23;
    if (__all((int)(mn >= tgt))) break;
    __builtin_amdgcn_s_sleep(1);
  }
  asm volatile("" ::: "memory");
}

// ---------- shared helpers for recurrence kernels ----------
static __device__ __forceinline__ void load_wset(
    const float* __restrict__ WT, int gcol, int wkoff,
    bf16x8* wh, bf16x8* wl) {
#pragma unroll
  for (int kk = 0; kk < 8; ++kk) {
    const float* src = WT + ((size_t)gcol << 10) + (wkoff + (kk << 5));
    f32x4 v0 = *(const f32x4*)src;
    f32x4 v1 = *(const f32x4*)(src + 4);
    u16x8 h8, l8;
#pragma unroll
    for (int j = 0; j < 4; ++j) {
      unsigned short hh, ll;
      split1(v0[j], hh, ll); h8[j] = hh;     l8[j] = ll;
      split1(v1[j], hh, ll); h8[4 + j] = hh; l8[4 + j] = ll;
    }
    wh[kk] = __builtin_bit_cast(bf16x8, h8);
    wl[kk] = __builtin_bit_cast(bf16x8, l8);
  }
}

static __device__ __forceinline__ void split_a(
    const float* __restrict__ hp, bf16x8& ah, bf16x8& al) {
  f32x4 v0 = *(const f32x4*)hp;
  f32x4 v1 = *(const f32x4*)(hp + 4);
  u16x8 h8, l8;
#pragma unroll
  for (int j = 0; j < 4; ++j) {
    unsigned short hh, ll;
    split1(v0[j], hh, ll); h8[j] = hh;     l8[j] = ll;
    split1(v1[j], hh, ll); h8[4 + j] = hh; l8[4 + j] = ll;
  }
  ah = __builtin_bit_cast(bf16x8, h8);
  al = __builtin_bit_cast(bf16x8, l8);
}

static __device__ __forceinline__ void dot3(
    const float* __restrict__ hsrc, int off,
    const bf16x8* wh, const bf16x8* wl,
    f32x4& a0, f32x4& a1, f32x4& a2) {
#pragma unroll
  for (int kk = 0; kk < 8; ++kk) {
    bf16x8 ah, al;
    split_a(hsrc + off + (kk << 5), ah, al);
    a0 = __builtin_amdgcn_mfma_f32_16x16x32_bf16(ah, wh[kk], a0, 0, 0, 0);
    a1 = __builtin_amdgcn_mfma_f32_16x16x32_bf16(ah, wl[kk], a1, 0, 0, 0);
    a2 = __builtin_amdgcn_mfma_f32_16x16x32_bf16(al, wh[kk], a2, 0, 0, 0);
  }
}

static __device__ __forceinline__ void dot3_stream(
    const float* __restrict__ hsrc, int off,
    const unsigned short* __restrict__ Wh, const unsigned short* __restrict__ Wl,
    size_t woff, f32x4& a0, f32x4& a1, f32x4& a2) {
#pragma unroll
  for (int kk = 0; kk < 8; ++kk) {
    u16x8 wh8 = *(const u16x8*)(Wh + woff + (kk << 5));
    u16x8 wl8 = *(const u16x8*)(Wl + woff + (kk << 5));
    bf16x8 ah, al;
    split_a(hsrc + off + (kk << 5), ah, al);
    a0 = __builtin_amdgcn_mfma_f32_16x16x32_bf16(ah, __builtin_bit_cast(bf16x8, wh8), a0, 0, 0, 0);
    a1 = __builtin_amdgcn_mfma_f32_16x16x32_bf16(ah, __builtin_bit_cast(bf16x8, wl8), a1, 0, 0, 0);
    a2 = __builtin_amdgcn_mfma_f32_16x16x32_bf16(al, __builtin_bit_cast(bf16x8, wh8), a2, 0, 0, 0);
  }
}

// ---------- r8 single-layer persistent LSTM (known-good fallback) ----------
__global__ __launch_bounds__(256) void lstm_persistent(
    const float* __restrict__ whT, const float* __restrict__ xw,
    const float* __restrict__ bh, const float* __restrict__ h0,
    const float* __restrict__ c0, float* __restrict__ ys,
    float* __restrict__ hfin, float* __restrict__ cfin,
    unsigned* __restrict__ flags, unsigned base) {
  __shared__ float red[4][16][16];
  const int tid  = threadIdx.x;
  const int lane = tid & 63;
  const int wave = tid >> 6;
  const int bid  = blockIdx.x;
  const int lc   = lane & 15;
  const int kg8  = (lane >> 4) << 3;
  const int wk   = wave << 8;

  const int gcol = (lc & 3) * 1024 + (bid << 2) + (lc >> 2);
  bf16x8 w_h[8], w_l[8];
  load_wset(whT, gcol, wk + kg8, w_h, w_l);

  const int ab = tid & 15;
  const int ai = tid >> 4;
  const int au = (bid << 2) + (ai & 3);
  float c_reg = 0.f, h_keep = 0.f;
  float bhv[4], xwv[4], xwn[4];
  if (tid < 64) {
    c_reg = c0[(ab << 10) + au];
#pragma unroll
    for (int g = 0; g < 4; ++g) bhv[g] = bh[(g << 10) + au];
#pragma unroll
    for (int g = 0; g < 4; ++g) xwv[g] = xw[(ab << 12) + (g << 10) + au];
  }
  const int hoff = (lc << 10) + wk + kg8;

  for (int s = 0; s < 256; ++s) {
    if (tid < 64 && s < 255) {
      const float* xn = xw + ((size_t)(s + 1) << 16);
#pragma unroll
      for (int g = 0; g < 4; ++g) xwn[g] = xn[(ab << 12) + (g << 10) + au];
    }
    const float* hsrc = (s == 0) ? h0 : (ys + ((size_t)(s - 1) << 14));
    f32x4 acc0 = {}, acc1 = {}, acc2 = {};
    dot3(hsrc, hoff, w_h, w_l, acc0, acc1, acc2);
    f32x4 a = acc0 + acc1 + acc2;
#pragma unroll
    for (int r = 0; r < 4; ++r) red[wave][(lane >> 4) * 4 + r][lc] = a[r];
    __syncthreads();
    if (tid < 64) {
      float pre[4];
#pragma unroll
      for (int g = 0; g < 4; ++g) {
        int c = (ai << 2) + g;
        pre[g] = red[0][ab][c] + red[1][ab][c] + red[2][ab][c] + red[3][ab][c]
               + xwv[g] + bhv[g];
      }
      float f  = 1.f / (1.f + expf(-pre[0]));
      float i_ = 1.f / (1.f + expf(-pre[1]));
      float o  = 1.f / (1.f + expf(-pre[2]));
      float g_ = tanhf(pre[3]);
      c_reg = f * c_reg + i_ * g_;
      float h = o * tanhf(c_reg);
      h_keep = h;
      __hip_atomic_store((unsigned*)ys + (((size_t)s << 14) + (ab << 10) + au),
                         __builtin_bit_cast(unsigned, h),
                         __ATOMIC_RELAXED, __HIP_MEMORY_SCOPE_AGENT);
#pragma unroll
      for (int g = 0; g < 4; ++g) xwv[g] = xwn[g];
    }
    if (wave == 0) {
      asm volatile("s_waitcnt vmcnt(0)" ::: "memory");
      if (lane == 0)
        __hip_atomic_store(&flags[bid], base + 1u + (unsigned)s, __ATOMIC_RELAXED, __HIP_MEMORY_SCOPE_AGENT);
      if (s < 255)
        poll_flags(flags, base + 1u + (unsigned)s, lane);
    }
    __syncthreads();
  }
  if (tid < 64) {
    hfin[(ab << 10) + au] = h_keep;
    cfin[(ab << 10) + au] = c_reg;
  }
}

// ---------- fused 2-layer pipelined LSTM (r10 logic, gated at launch) ----------
__global__ __launch_bounds__(256) void lstm2_persistent(
    const float* __restrict__ wh1T, const float* __restrict__ wh2T,
    const unsigned short* __restrict__ wi2Th, const unsigned short* __restrict__ wi2Tl,
    const float* __restrict__ xw1, const float* __restrict__ bh,
    const float* __restrict__ bi, const float* __restrict__ hidden,
    float* __restrict__ h1buf, float* __restrict__ ys2,
    float* __restrict__ nh, unsigned* __restrict__ flags) {
  __shared__ float red1[4][16][16];
  __shared__ float red2[4][16][16];
  const int tid  = threadIdx.x;
  const int lane = tid & 63;
  const int wave = tid >> 6;
  const int bid  = blockIdx.x;
  const int lc   = lane & 15;
  const int kg8  = (lane >> 4) << 3;
  const int wk   = wave << 8;
  const int wkoff = wk + kg8;

  const int gcol = (lc & 3) * 1024 + (bid << 2) + (lc >> 2);
  const size_t woff = ((size_t)gcol << 10) + wkoff;
  bf16x8 w1h[8], w1l[8], w2hh[8], w2hl[8];
  load_wset(wh1T, gcol, wkoff, w1h, w1l);
  load_wset(wh2T, gcol, wkoff, w2hh, w2hl);

  const float* h01 = hidden;
  const float* c01 = hidden + 16384;
  const float* h02 = hidden + 32768;
  const float* c02 = hidden + 49152;

  const int at = tid & 63;
  const int ab = at & 15;
  const int ai = at >> 4;
  const int au = (bid << 2) + ai;
  float c1 = 0.f, c2 = 0.f;
  float b1v[4], b2v[4], xwv[4], xwn[4];
  if (tid < 64) {
    c1 = c01[(ab << 10) + au];
#pragma unroll
    for (int g = 0; g < 4; ++g) b1v[g] = bh[(g << 10) + au];
#pragma unroll
    for (int g = 0; g < 4; ++g) xwv[g] = xw1[(ab << 12) + (g << 10) + au];
  } else if (tid < 128) {
    c2 = c02[(ab << 10) + au];
#pragma unroll
    for (int g = 0; g < 4; ++g)
      b2v[g] = bh[4096 + (g << 10) + au] + bi[4096 + (g << 10) + au];
  }

  const int hoff = (lc << 10) + wkoff;

  for (int k = 0; k <= 256; ++k) {
    if (k < 256) {
      const float* hs = (k == 0) ? h01 : (h1buf + ((size_t)(k - 1) << 14));
      f32x4 a0 = {}, a1 = {}, a2 = {};
      dot3(hs, hoff, w1h, w1l, a0, a1, a2);
      f32x4 s = a0 + a1 + a2;
#pragma unroll
      for (int r = 0; r < 4; ++r) red1[wave][(lane >> 4) * 4 + r][lc] = s[r];
    }
    if (k >= 1) {
      const float* hx  = h1buf + ((size_t)(k - 1) << 14);
      const float* h2s = (k == 1) ? h02 : (ys2 + ((size_t)(k - 2) << 14));
      f32x4 b0 = {}, b1 = {}, b2 = {};
      dot3_stream(hx, hoff, wi2Th, wi2Tl, woff, b0, b1, b2);
      dot3(h2s, hoff, w2hh, w2hl, b0, b1, b2);
      f32x4 s = b0 + b1 + b2;
#pragma unroll
      for (int r = 0; r < 4; ++r) red2[wave][(lane >> 4) * 4 + r][lc] = s[r];
    }
    __syncthreads();

    if (k < 256 && tid < 64) {
      float pre[4];
#pragma unroll
      for (int g = 0; g < 4; ++g) {
        int c = (ai << 2) + g;
        pre[g] = red1[0][ab][c] + red1[1][ab][c] + red1[2][ab][c] + red1[3][ab][c]
               + xwv[g] + b1v[g];
      }
      float f  = 1.f / (1.f + expf(-pre[0]));
      float i_ = 1.f / (1.f + expf(-pre[1]));
      float o  = 1.f / (1.f + expf(-pre[2]));
      float g_ = tanhf(pre[3]);
      c1 = f * c1 + i_ * g_;
      float h = o * tanhf(c1);
      __hip_atomic_store((unsigned*)h1buf + (((size_t)k << 14) + (ab << 10) + au),
                         __builtin_bit_cast(unsigned, h),
                         __ATOMIC_RELAXED, __HIP_MEMORY_SCOPE_AGENT);
      if (k == 255) {
        nh[(ab << 10) + au] = h;
        nh[16384 + (ab << 10) + au] = c1;
      }
    }
    if (k >= 1 && wave == 1) {
      int s2 = k - 1;
      float pre[4];
#pragma unroll
      for (int g = 0; g < 4; ++g) {
        int c = (ai << 2) + g;
        pre[g] = red2[0][ab][c] + red2[1][ab][c] + red2[2][ab][c] + red2[3][ab][c]
               + b2v[g];
      }
      float f  = 1.f / (1.f + expf(-pre[0]));
      float i_ = 1.f / (1.f + expf(-pre[1]));
      float o  = 1.f / (1.f + expf(-pre[2]));
      float g_ = tanhf(pre[3]);
      c2 = f * c2 + i_ * g_;
      float h = o * tanhf(c2);
      __hip_atomic_store((unsigned*)ys2 + (((size_t)s2 << 14) + (ab << 10) + au),
                         __builtin_bit_cast(unsigned, h),
                         __ATOMIC_RELAXED, __HIP_MEMORY_SCOPE_AGENT);
      if (s2 == 255) {
        nh[32768 + (ab << 10) + au] = h;
        nh[49152 + (ab << 10) + au] = c2;
      }
    }
    if (wave < 2) asm volatile("s_waitcnt vmcnt(0)" ::: "memory");
    __syncthreads();

    if (k < 256) {
      if (wave == 0) {
        if (lane == 0)
          __hip_atomic_store(&flags[bid], (unsigned)(k + 1), __ATOMIC_RELAXED, __HIP_MEMORY_SCOPE_AGENT);
        if (k < 255) {
          const float* xn = xw1 + ((size_t)(k + 1) << 16);
#pragma unroll
          for (int g = 0; g < 4; ++g) xwn[g] = xn[(ab << 12) + (g << 10) + au];
        }
        poll_flags(flags, (unsigned)(k + 1), lane);
        if (k < 255) {
#pragma unroll
          for (int g = 0; g < 4; ++g) xwv[g] = xwn[g];
        }
      }
      __syncthreads();
    }
  }
}

// ---------- prep kernels ----------
__global__ __launch_bounds__(256) void embed_gather_split(
    const int* __restrict__ tokens, const float* __restrict__ emb,
    unsigned short* __restrict__ xh, unsigned short* __restrict__ xl) {
  int sb = blockIdx.x;
  int tok = tokens[sb];
  f32x4 v = ((const f32x4*)(emb + (size_t)tok * 1024))[threadIdx.x];
  u16x4 h, l;
#pragma unroll
  for (int j = 0; j < 4; ++j) { unsigned short hh, ll; split1(v[j], hh, ll); h[j] = hh; l[j] = ll; }
  size_t o = (size_t)sb * 1024 + threadIdx.x * 4;
  *(u16x4*)(xh + o) = h;
  *(u16x4*)(xl + o) = l;
}

__global__ __launch_bounds__(256) void split_mat(
    const float* __restrict__ x, unsigned short* __restrict__ xh,
    unsigned short* __restrict__ xl) {
  size_t i = (size_t)blockIdx.x * 256 + threadIdx.x;
  f32x4 v = ((const f32x4*)x)[i];
  u16x4 h, l;
#pragma unroll
  for (int j = 0; j < 4; ++j) { unsigned short hh, ll; split1(v[j], hh, ll); h[j] = hh; l[j] = ll; }
  *(u16x4*)(xh + i * 4) = h;
  *(u16x4*)(xl + i * 4) = l;
}

__global__ void split_transpose_w(
    const float* __restrict__ W, unsigned short* __restrict__ WTh,
    unsigned short* __restrict__ WTl, int K, int N) {
  __shared__ float tile[32][33];
  int n0 = blockIdx.x << 5;
  int k0 = blockIdx.y << 5;
  int tx = threadIdx.x, ty = threadIdx.y;  // 32 x 8
#pragma unroll
  for (int i = 0; i < 32; i += 8) {
    int n = n0 + tx;
    tile[ty + i][tx] = (n < N) ? W[(size_t)(k0 + ty + i) * N + n] : 0.f;
  }
  __syncthreads();
#pragma unroll
  for (int i = 0; i < 32; i += 8) {
    int n = n0 + ty + i;
    float v = tile[tx][ty + i];
    unsigned short h, l; split1(v, h, l);
    WTh[(size_t)n * K + k0 + tx] = h;
    WTl[(size_t)n * K + k0 + tx] = l;
  }
}

// [1024][4096] f32 -> [4096][1024] f32
__global__ void transpose1(const float* __restrict__ src, float* __restrict__ dst) {
  __shared__ float tile[32][33];
  int c0 = blockIdx.x << 5;
  int k0 = blockIdx.y << 5;
  int tx = threadIdx.x, ty = threadIdx.y;  // 32 x 8
#pragma unroll
  for (int i = 0; i < 32; i += 8)
    tile[ty + i][tx] = src[(size_t)(k0 + ty + i) * 4096 + c0 + tx];
  __syncthreads();
#pragma unroll
  for (int i = 0; i < 32; i += 8)
    dst[(size_t)(c0 + ty + i) * 1024 + k0 + tx] = tile[tx][ty + i];
}

// ---------- host ----------
extern "C" void kernel_launch(void* const* d_in, const int* in_sizes, int n_in,
                              void* d_out, int out_size, void* d_ws, size_t ws_size,
                              hipStream_t stream) {
  (void)in_sizes; (void)n_in; (void)out_size; (void)ws_size;
  const int*   tokens    = (const int*)  d_in[0];
  const float* hidden    = (const float*)d_in[1];
  const float* embedding = (const float*)d_in[2];
  const float* wi        = (const float*)d_in[3];
  const float* bi        = (const float*)d_in[4];
  const float* wh        = (const float*)d_in[5];
  const float* bh        = (const float*)d_in[6];
  const float* wdec      = (const float*)d_in[7];
  const float* bdec      = (const float*)d_in[8];

  float* out     = (float*)d_out;
  float* out_res = out;                                   // 256*16*50257
  float* out_nh  = out + (size_t)205852672;               // 2*2*16*1024
  float* out_x   = out + (size_t)205852672 + 65536;       // 256*16*1024
  float* h1buf   = out_res;                               // fused-path scratch

  // ---- workspace layout (373.8 MB total; proven to fit in r8) ----
  float* ws    = (float*)d_ws;
  float* whT   = ws;                        // 2*4194304 f (layers contiguous)
  float* xwb   = whT + 8388608;             // 16777216 f
  float* ys0   = xwb + 16777216;            // 4194304 f (fallback h1 seq)
  unsigned* flags = (unsigned*)(ys0 + 4194304);  // 4096 u32
  unsigned short* u16base = (unsigned short*)(flags + 4096);
  unsigned short* Ah_s  = u16base;                 // 4194304
  unsigned short* Al_s  = Ah_s + 4194304;          // 4194304
  unsigned short* wiTh  = Al_s + 4194304;          // 4194304 (layer 0)
  unsigned short* wiTl  = wiTh + 4194304;          // 4194304
  unsigned short* wi2Th = wiTl + 4194304;          // 4194304 (layer 1)
  unsigned short* wi2Tl = wi2Th + 4194304;         // 4194304
  unsigned short* wdTh  = wi2Tl + 4194304;         // 51511296
  unsigned short* wdTl  = wdTh + 51511296;         // 51511296

  hipMemsetAsync(flags, 0, 4096 * sizeof(unsigned), stream);
  transpose1<<<dim3(128, 32), dim3(32, 8), 0, stream>>>(wh, whT);
  transpose1<<<dim3(128, 32), dim3(32, 8), 0, stream>>>(wh + 4194304, whT + 4194304);
  embed_gather_split<<<4096, 256, 0, stream>>>(tokens, embedding, Ah_s, Al_s);
  split_transpose_w<<<dim3(128, 32), dim3(32, 8), 0, stream>>>(wi, wiTh, wiTl, 1024, 4096);
  split_transpose_w<<<dim3(128, 32), dim3(32, 8), 0, stream>>>(wi + 4194304, wi2Th, wi2Tl, 1024, 4096);
  split_transpose_w<<<dim3(1572, 32), dim3(32, 8), 0, stream>>>(wdec, wdTh, wdTl, 1024, 50257);

  // xw1 = emb @ wi0^T + bi0 (both paths need this)
  gemm_ps<<<dim3(32, 32), 256, 0, stream>>>(
      Ah_s, Al_s, wiTh, wiTl, bi, xwb, 4096, 4096, 1024);

  // ---- fused path, gated on occupancy + launch acceptance ----
  bool fused_ok = false;
  int nb = 0;
  hipError_t qerr = hipOccupancyMaxActiveBlocksPerMultiprocessor(
      &nb, (const void*)lstm2_persistent, 256, 0);
  if (qerr == hipSuccess && nb >= 1) {
    const float* p_wh1T = whT; const float* p_wh2T = whT + 4194304;
    const unsigned short* p_wi2Th = wi2Th; const unsigned short* p_wi2Tl = wi2Tl;
    const float* p_xw1 = xwb;  const float* p_bh = bh;   const float* p_bi = bi;
    const float* p_hid = hidden;
    float* p_h1 = h1buf; float* p_ys2 = out_x; float* p_nh = out_nh;
    unsigned* p_fl = flags;
    void* args[] = { &p_wh1T, &p_wh2T, &p_wi2Th, &p_wi2Tl, &p_xw1, &p_bh, &p_bi,
                     &p_hid, &p_h1, &p_ys2, &p_nh, &p_fl };
    hipError_t cerr = hipLaunchCooperativeKernel((const void*)lstm2_persistent,
                                                 dim3(256), dim3(256), args, 0, stream);
    fused_ok = (cerr == hipSuccess);
  }

  if (!fused_ok) {
    // ---- exact r8 fallback: per-layer coop kernels ----
    for (int l = 0; l < 2; ++l) {
      if (l == 1) {
        gemm_ps<<<dim3(32, 32), 256, 0, stream>>>(
            Ah_s, Al_s, wi2Th, wi2Tl, bi + 4096, xwb, 4096, 4096, 1024);
      }
      const float* wT  = whT + (size_t)l * 4194304;
      const float* xwp = xwb;
      const float* bhl = bh + l * 4096;
      const float* h0p = hidden + (size_t)l * 32768;
      const float* c0p = h0p + 16384;
      float* ysp  = (l == 0) ? ys0 : out_x;
      float* hfin = out_nh + (size_t)l * 32768;
      float* cfin = hfin + 16384;
      unsigned basev = (unsigned)(l * 256);
      unsigned* flp = flags;
      void* args[] = { &wT, &xwp, &bhl, &h0p, &c0p, &ysp, &hfin, &cfin, &flp, &basev };
      hipLaunchCooperativeKernel((const void*)lstm_persistent,
                                 dim3(256), dim3(256), args, 0, stream);
      split_mat<<<4096, 256, 0, stream>>>(ysp, Ah_s, Al_s);
    }
  } else {
    split_mat<<<4096, 256, 0, stream>>>(out_x, Ah_s, Al_s);
  }

  // decode
  gemm_ps<<<dim3(32, 393), 256, 0, stream>>>(
      Ah_s, Al_s, wdTh, wdTl, bdec, out_res, 4096, 50257, 1024);
}

// Round 12
// 6751.511 us; speedup vs baseline: 2.4233x; 1.0028x over previous
//
#include <hip/hip_runtime.h>

// ---------- types ----------
typedef float  f32x4  __attribute__((ext_vector_type(4)));
typedef unsigned short u16x4 __attribute__((ext_vector_type(4)));
typedef unsigned short u16x8 __attribute__((ext_vector_type(8)));
typedef __bf16 bf16x8 __attribute__((ext_vector_type(8)));

// round-to-nearest-even f32 -> bf16 (bit trick)
static __device__ __forceinline__ unsigned short bf16_rn(float x) {
  unsigned u = __builtin_bit_cast(unsigned, x);
  unsigned r = (u + 0x7FFFu + ((u >> 16) & 1u)) >> 16;
  return (unsigned short)r;
}
// split x ~= hi + lo (each bf16); residual ~2^-17 relative
static __device__ __forceinline__ void split1(float x, unsigned short& h, unsigned short& l) {
  unsigned short hh = bf16_rn(x);
  float hf = __builtin_bit_cast(float, ((unsigned)hh) << 16);
  h = hh;
  l = bf16_rn(x - hf);
}

#define BM 128
#define BN 128
#define BK 32
#define LDK 40

// XOR-swizzled LDS index: 16B chunks permuted by row.
static __device__ __forceinline__ int lds_idx(int row, int k) {
  return row * LDK + ((((k >> 3) ^ (row >> 2)) & 3) << 3) + (k & 7);
}

// ---------- GEMM (pre-split inputs): C = A * B^T + bias ----------
__global__ __launch_bounds__(256) void gemm_ps(
    const unsigned short* __restrict__ Ahg, const unsigned short* __restrict__ Alg,
    const unsigned short* __restrict__ Bhg, const unsigned short* __restrict__ Blg,
    const float* __restrict__ bias, float* __restrict__ C,
    int M, int N, int K) {
  __shared__ unsigned short Ah[BM * LDK];
  __shared__ unsigned short Al[BM * LDK];
  __shared__ unsigned short Bh[BN * LDK];
  __shared__ unsigned short Bl[BN * LDK];

  const int tid  = threadIdx.x;
  const int lane = tid & 63;
  const int wave = tid >> 6;
  const int bm = blockIdx.x * BM;
  const int bn = blockIdx.y * BN;
  const int wm = (wave >> 1) * 64;
  const int wn = (wave & 1) * 64;

  f32x4 acc[4][4] = {};

  const int srow = tid >> 2;
  const int sk   = (tid & 3) << 3;

  for (int k0 = 0; k0 < K; k0 += BK) {
#pragma unroll
    for (int p = 0; p < 2; ++p) {
      int r = srow + (p << 6);
      size_t ga = (size_t)(bm + r) * K + k0 + sk;
      size_t gb = (size_t)(bn + r) * K + k0 + sk;
      int ix = lds_idx(r, sk);
      *(u16x8*)(&Ah[ix]) = *(const u16x8*)(Ahg + ga);
      *(u16x8*)(&Al[ix]) = *(const u16x8*)(Alg + ga);
      *(u16x8*)(&Bh[ix]) = *(const u16x8*)(Bhg + gb);
      *(u16x8*)(&Bl[ix]) = *(const u16x8*)(Blg + gb);
    }
    __syncthreads();

    const int fr = lane & 15;
    const int kg = (lane >> 4) << 3;
    u16x8 a_h[4], a_l[4], b_h[4], b_l[4];
#pragma unroll
    for (int i = 0; i < 4; ++i) {
      int ia = lds_idx(wm + i * 16 + fr, kg);
      int ib = lds_idx(wn + i * 16 + fr, kg);
      a_h[i] = *(const u16x8*)(&Ah[ia]);
      a_l[i] = *(const u16x8*)(&Al[ia]);
      b_h[i] = *(const u16x8*)(&Bh[ib]);
      b_l[i] = *(const u16x8*)(&Bl[ib]);
    }
#pragma unroll
    for (int i = 0; i < 4; ++i)
#pragma unroll
      for (int j = 0; j < 4; ++j) {
        acc[i][j] = __builtin_amdgcn_mfma_f32_16x16x32_bf16(
            __builtin_bit_cast(bf16x8, a_h[i]), __builtin_bit_cast(bf16x8, b_h[j]), acc[i][j], 0, 0, 0);
        acc[i][j] = __builtin_amdgcn_mfma_f32_16x16x32_bf16(
            __builtin_bit_cast(bf16x8, a_h[i]), __builtin_bit_cast(bf16x8, b_l[j]), acc[i][j], 0, 0, 0);
        acc[i][j] = __builtin_amdgcn_mfma_f32_16x16x32_bf16(
            __builtin_bit_cast(bf16x8, a_l[i]), __builtin_bit_cast(bf16x8, b_h[j]), acc[i][j], 0, 0, 0);
      }
    __syncthreads();
  }
  const int cc = lane & 15;
  const int rg = (lane >> 4) << 2;
#pragma unroll
  for (int i = 0; i < 4; ++i)
#pragma unroll
    for (int j = 0; j < 4; ++j)
#pragma unroll
      for (int r = 0; r < 4; ++r) {
        int row = bm + wm + i * 16 + rg + r;
        int col = bn + wn + j * 16 + cc;
        if (col < N) {
          float v = acc[i][j][r];
          if (bias) v += bias[col];
          C[(size_t)row * N + col] = v;
        }
      }
}

// ---------- legacy dense-flag poll (fallback path only) ----------
static __device__ __forceinline__ void poll_flags(const unsigned* flags, unsigned tgt, int lane) {
  for (;;) {
    unsigned v0 = __hip_atomic_load(flags + lane,       __ATOMIC_RELAXED, __HIP_MEMORY_SCOPE_AGENT);
    unsigned v1 = __hip_atomic_load(flags + 64 + lane,  __ATOMIC_RELAXED, __HIP_MEMORY_SCOPE_AGENT);
    unsigned v2 = __hip_atomic_load(flags + 128 + lane, __ATOMIC_RELAXED, __HIP_MEMORY_SCOPE_AGENT);
    unsigned v3 = __hip_atomic_load(flags + 192 + lane, __ATOMIC_RELAXED, __HIP_MEMORY_SCOPE_AGENT);
    unsigned m01 = v0 < v1 ? v0 : v1;
    unsigned m23 = v2 < v3 ? v2 : v3;
    unsigned mn  = m01 < m23 ? m01 : m23;
    if (__all((int)(mn >= tgt))) break;
    __builtin_amdgcn_s_sleep(1);
  }
  asm volatile("" ::: "memory");
}

// ---------- shared helpers for recurrence kernels ----------
static __device__ __forceinline__ void load_wset(
    const float* __restrict__ WT, int gcol, int wkoff,
    bf16x8* wh, bf16x8* wl) {
#pragma unroll
  for (int kk = 0; kk < 8; ++kk) {
    const float* src = WT + ((size_t)gcol << 10) + (wkoff + (kk << 5));
    f32x4 v0 = *(const f32x4*)src;
    f32x4 v1 = *(const f32x4*)(src + 4);
    u16x8 h8, l8;
#pragma unroll
    for (int j = 0; j < 4; ++j) {
      unsigned short hh, ll;
      split1(v0[j], hh, ll); h8[j] = hh;     l8[j] = ll;
      split1(v1[j], hh, ll); h8[4 + j] = hh; l8[4 + j] = ll;
    }
    wh[kk] = __builtin_bit_cast(bf16x8, h8);
    wl[kk] = __builtin_bit_cast(bf16x8, l8);
  }
}

static __device__ __forceinline__ void split_a(
    const float* __restrict__ hp, bf16x8& ah, bf16x8& al) {
  f32x4 v0 = *(const f32x4*)hp;
  f32x4 v1 = *(const f32x4*)(hp + 4);
  u16x8 h8, l8;
#pragma unroll
  for (int j = 0; j < 4; ++j) {
    unsigned short hh, ll;
    split1(v0[j], hh, ll); h8[j] = hh;     l8[j] = ll;
    split1(v1[j], hh, ll); h8[4 + j] = hh; l8[4 + j] = ll;
  }
  ah = __builtin_bit_cast(bf16x8, h8);
  al = __builtin_bit_cast(bf16x8, l8);
}

static __device__ __forceinline__ void dot3(
    const float* __restrict__ hsrc, int off,
    const bf16x8* wh, const bf16x8* wl,
    f32x4& a0, f32x4& a1, f32x4& a2) {
#pragma unroll
  for (int kk = 0; kk < 8; ++kk) {
    bf16x8 ah, al;
    split_a(hsrc + off + (kk << 5), ah, al);
    a0 = __builtin_amdgcn_mfma_f32_16x16x32_bf16(ah, wh[kk], a0, 0, 0, 0);
    a1 = __builtin_amdgcn_mfma_f32_16x16x32_bf16(ah, wl[kk], a1, 0, 0, 0);
    a2 = __builtin_amdgcn_mfma_f32_16x16x32_bf16(al, wh[kk], a2, 0, 0, 0);
  }
}

static __device__ __forceinline__ void dot3_stream(
    const float* __restrict__ hsrc, int off,
    const unsigned short* __restrict__ Wh, const unsigned short* __restrict__ Wl,
    size_t woff, f32x4& a0, f32x4& a1, f32x4& a2) {
#pragma unroll
  for (int kk = 0; kk < 8; ++kk) {
    u16x8 wh8 = *(const u16x8*)(Wh + woff + (kk << 5));
    u16x8 wl8 = *(const u16x8*)(Wl + woff + (kk << 5));
    bf16x8 ah, al;
    split_a(hsrc + off + (kk << 5), ah, al);
    a0 = __builtin_amdgcn_mfma_f32_16x16x32_bf16(ah, __builtin_bit_cast(bf16x8, wh8), a0, 0, 0, 0);
    a1 = __builtin_amdgcn_mfma_f32_16x16x32_bf16(ah, __builtin_bit_cast(bf16x8, wl8), a1, 0, 0, 0);
    a2 = __builtin_amdgcn_mfma_f32_16x16x32_bf16(al, __builtin_bit_cast(bf16x8, wh8), a2, 0, 0, 0);
  }
}

// ---------- r8 single-layer persistent LSTM (known-good fallback) ----------
__global__ __launch_bounds__(256) void lstm_persistent(
    const float* __restrict__ whT, const float* __restrict__ xw,
    const float* __restrict__ bh, const float* __restrict__ h0,
    const float* __restrict__ c0, float* __restrict__ ys,
    float* __restrict__ hfin, float* __restrict__ cfin,
    unsigned* __restrict__ flags, unsigned base) {
  __shared__ float red[4][16][16];
  const int tid  = threadIdx.x;
  const int lane = tid & 63;
  const int wave = tid >> 6;
  const int bid  = blockIdx.x;
  const int lc   = lane & 15;
  const int kg8  = (lane >> 4) << 3;
  const int wk   = wave << 8;

  const int gcol = (lc & 3) * 1024 + (bid << 2) + (lc >> 2);
  bf16x8 w_h[8], w_l[8];
  load_wset(whT, gcol, wk + kg8, w_h, w_l);

  const int ab = tid & 15;
  const int ai = tid >> 4;
  const int au = (bid << 2) + (ai & 3);
  float c_reg = 0.f, h_keep = 0.f;
  float bhv[4], xwv[4], xwn[4];
  if (tid < 64) {
    c_reg = c0[(ab << 10) + au];
#pragma unroll
    for (int g = 0; g < 4; ++g) bhv[g] = bh[(g << 10) + au];
#pragma unroll
    for (int g = 0; g < 4; ++g) xwv[g] = xw[(ab << 12) + (g << 10) + au];
  }
  const int hoff = (lc << 10) + wk + kg8;

  for (int s = 0; s < 256; ++s) {
    if (tid < 64 && s < 255) {
      const float* xn = xw + ((size_t)(s + 1) << 16);
#pragma unroll
      for (int g = 0; g < 4; ++g) xwn[g] = xn[(ab << 12) + (g << 10) + au];
    }
    const float* hsrc = (s == 0) ? h0 : (ys + ((size_t)(s - 1) << 14));
    f32x4 acc0 = {}, acc1 = {}, acc2 = {};
    dot3(hsrc, hoff, w_h, w_l, acc0, acc1, acc2);
    f32x4 a = acc0 + acc1 + acc2;
#pragma unroll
    for (int r = 0; r < 4; ++r) red[wave][(lane >> 4) * 4 + r][lc] = a[r];
    __syncthreads();
    if (tid < 64) {
      float pre[4];
#pragma unroll
      for (int g = 0; g < 4; ++g) {
        int c = (ai << 2) + g;
        pre[g] = red[0][ab][c] + red[1][ab][c] + red[2][ab][c] + red[3][ab][c]
               + xwv[g] + bhv[g];
      }
      float f  = 1.f / (1.f + expf(-pre[0]));
      float i_ = 1.f / (1.f + expf(-pre[1]));
      float o  = 1.f / (1.f + expf(-pre[2]));
      float g_ = tanhf(pre[3]);
      c_reg = f * c_reg + i_ * g_;
      float h = o * tanhf(c_reg);
      h_keep = h;
      __hip_atomic_store((unsigned*)ys + (((size_t)s << 14) + (ab << 10) + au),
                         __builtin_bit_cast(unsigned, h),
                         __ATOMIC_RELAXED, __HIP_MEMORY_SCOPE_AGENT);
#pragma unroll
      for (int g = 0; g < 4; ++g) xwv[g] = xwn[g];
    }
    if (wave == 0) {
      asm volatile("s_waitcnt vmcnt(0)" ::: "memory");
      if (lane == 0)
        __hip_atomic_store(&flags[bid], base + 1u + (unsigned)s, __ATOMIC_RELAXED, __HIP_MEMORY_SCOPE_AGENT);
      if (s < 255)
        poll_flags(flags, base + 1u + (unsigned)s, lane);
    }
    __syncthreads();
  }
  if (tid < 64) {
    hfin[(ab << 10) + au] = h_keep;
    cfin[(ab << 10) + au] = c_reg;
  }
}

// ---------- fused 2-layer pipelined LSTM with hub-and-spoke barrier ----------
// flags layout (u32): arr[b] at flags[b*16] (one 64B line per WG, 1 writer /
// 1 reader=WG0); go[b] at flags[4096 + b*16] (1 writer=WG0 / 1 reader=WG b).
// Arrival: WG publishes its line. Detect: WG0 wave0 polls all 256 arrival
// lines (sole reader -> no contention). Broadcast: WG0's 256 threads store
// 256 go lines; each WG spins on ITS OWN go line (broadcast read, 1 line).
__global__ __launch_bounds__(256) void lstm2_persistent(
    const float* __restrict__ wh1T, const float* __restrict__ wh2T,
    const unsigned short* __restrict__ wi2Th, const unsigned short* __restrict__ wi2Tl,
    const float* __restrict__ xw1, const float* __restrict__ bh,
    const float* __restrict__ bi, const float* __restrict__ hidden,
    float* __restrict__ h1buf, float* __restrict__ ys2,
    float* __restrict__ nh, unsigned* __restrict__ flags) {
  __shared__ float red1[4][16][16];
  __shared__ float red2[4][16][16];
  const int tid  = threadIdx.x;
  const int lane = tid & 63;
  const int wave = tid >> 6;
  const int bid  = blockIdx.x;
  const int lc   = lane & 15;
  const int kg8  = (lane >> 4) << 3;
  const int wk   = wave << 8;
  const int wkoff = wk + kg8;

  const int gcol = (lc & 3) * 1024 + (bid << 2) + (lc >> 2);
  const size_t woff = ((size_t)gcol << 10) + wkoff;
  bf16x8 w1h[8], w1l[8], w2hh[8], w2hl[8];
  load_wset(wh1T, gcol, wkoff, w1h, w1l);
  load_wset(wh2T, gcol, wkoff, w2hh, w2hl);

  const float* h01 = hidden;
  const float* c01 = hidden + 16384;
  const float* h02 = hidden + 32768;
  const float* c02 = hidden + 49152;

  const int at = tid & 63;
  const int ab = at & 15;
  const int ai = at >> 4;
  const int au = (bid << 2) + ai;
  float c1 = 0.f, c2 = 0.f;
  float b1v[4], b2v[4], xwv[4], xwn[4];
  if (tid < 64) {
    c1 = c01[(ab << 10) + au];
#pragma unroll
    for (int g = 0; g < 4; ++g) b1v[g] = bh[(g << 10) + au];
#pragma unroll
    for (int g = 0; g < 4; ++g) xwv[g] = xw1[(ab << 12) + (g << 10) + au];
  } else if (tid < 128) {
    c2 = c02[(ab << 10) + au];
#pragma unroll
    for (int g = 0; g < 4; ++g)
      b2v[g] = bh[4096 + (g << 10) + au] + bi[4096 + (g << 10) + au];
  }

  const int hoff = (lc << 10) + wkoff;

  for (int k = 0; k <= 256; ++k) {
    if (k < 256) {
      const float* hs = (k == 0) ? h01 : (h1buf + ((size_t)(k - 1) << 14));
      f32x4 a0 = {}, a1 = {}, a2 = {};
      dot3(hs, hoff, w1h, w1l, a0, a1, a2);
      f32x4 s = a0 + a1 + a2;
#pragma unroll
      for (int r = 0; r < 4; ++r) red1[wave][(lane >> 4) * 4 + r][lc] = s[r];
    }
    if (k >= 1) {
      const float* hx  = h1buf + ((size_t)(k - 1) << 14);
      const float* h2s = (k == 1) ? h02 : (ys2 + ((size_t)(k - 2) << 14));
      f32x4 b0 = {}, b1 = {}, b2 = {};
      dot3_stream(hx, hoff, wi2Th, wi2Tl, woff, b0, b1, b2);
      dot3(h2s, hoff, w2hh, w2hl, b0, b1, b2);
      f32x4 s = b0 + b1 + b2;
#pragma unroll
      for (int r = 0; r < 4; ++r) red2[wave][(lane >> 4) * 4 + r][lc] = s[r];
    }
    __syncthreads();

    if (k < 256 && tid < 64) {
      float pre[4];
#pragma unroll
      for (int g = 0; g < 4; ++g) {
        int c = (ai << 2) + g;
        pre[g] = red1[0][ab][c] + red1[1][ab][c] + red1[2][ab][c] + red1[3][ab][c]
               + xwv[g] + b1v[g];
      }
      float f  = 1.f / (1.f + expf(-pre[0]));
      float i_ = 1.f / (1.f + expf(-pre[1]));
      float o  = 1.f / (1.f + expf(-pre[2]));
      float g_ = tanhf(pre[3]);
      c1 = f * c1 + i_ * g_;
      float h = o * tanhf(c1);
      __hip_atomic_store((unsigned*)h1buf + (((size_t)k << 14) + (ab << 10) + au),
                         __builtin_bit_cast(unsigned, h),
                         __ATOMIC_RELAXED, __HIP_MEMORY_SCOPE_AGENT);
      if (k == 255) {
        nh[(ab << 10) + au] = h;
        nh[16384 + (ab << 10) + au] = c1;
      }
    }
    if (k >= 1 && wave == 1) {
      int s2 = k - 1;
      float pre[4];
#pragma unroll
      for (int g = 0; g < 4; ++g) {
        int c = (ai << 2) + g;
        pre[g] = red2[0][ab][c] + red2[1][ab][c] + red2[2][ab][c] + red2[3][ab][c]
               + b2v[g];
      }
      float f  = 1.f / (1.f + expf(-pre[0]));
      float i_ = 1.f / (1.f + expf(-pre[1]));
      float o  = 1.f / (1.f + expf(-pre[2]));
      float g_ = tanhf(pre[3]);
      c2 = f * c2 + i_ * g_;
      float h = o * tanhf(c2);
      __hip_atomic_store((unsigned*)ys2 + (((size_t)s2 << 14) + (ab << 10) + au),
                         __builtin_bit_cast(unsigned, h),
                         __ATOMIC_RELAXED, __HIP_MEMORY_SCOPE_AGENT);
      if (s2 == 255) {
        nh[32768 + (ab << 10) + au] = h;
        nh[49152 + (ab << 10) + au] = c2;
      }
    }
    if (wave < 2) asm volatile("s_waitcnt vmcnt(0)" ::: "memory");  // drain h stores
    __syncthreads();

    if (k < 256) {
      const unsigned e = (unsigned)(k + 1);
      if (wave == 0 && lane == 0)
        __hip_atomic_store(&flags[bid << 4], e, __ATOMIC_RELAXED, __HIP_MEMORY_SCOPE_AGENT);
      if (bid == 0) {
        if (wave == 0) {
          if (k < 255) {   // prefetch next xw: overlaps detection
            const float* xn = xw1 + ((size_t)(k + 1) << 16);
#pragma unroll
            for (int g = 0; g < 4; ++g) xwn[g] = xn[(ab << 12) + (g << 10) + au];
          }
          for (;;) {       // sole reader of all 256 arrival lines
            unsigned v0 = __hip_atomic_load(&flags[lane << 4],         __ATOMIC_RELAXED, __HIP_MEMORY_SCOPE_AGENT);
            unsigned v1 = __hip_atomic_load(&flags[(64 + lane) << 4],  __ATOMIC_RELAXED, __HIP_MEMORY_SCOPE_AGENT);
            unsigned v2 = __hip_atomic_load(&flags[(128 + lane) << 4], __ATOMIC_RELAXED, __HIP_MEMORY_SCOPE_AGENT);
            unsigned v3 = __hip_atomic_load(&flags[(192 + lane) << 4], __ATOMIC_RELAXED, __HIP_MEMORY_SCOPE_AGENT);
            unsigned m01 = v0 < v1 ? v0 : v1;
            unsigned m23 = v2 < v3 ? v2 : v3;
            unsigned mn  = m01 < m23 ? m01 : m23;
            if (__all((int)(mn >= e))) break;
            __builtin_amdgcn_s_sleep(1);
          }
          asm volatile("" ::: "memory");
          if (k < 255) {
#pragma unroll
            for (int g = 0; g < 4; ++g) xwv[g] = xwn[g];
          }
        }
        __syncthreads();
        // broadcast: 256 threads -> 256 private go lines
        __hip_atomic_store(&flags[4096 + (tid << 4)], e, __ATOMIC_RELAXED, __HIP_MEMORY_SCOPE_AGENT);
      } else {
        if (wave == 0) {
          if (k < 255) {
            const float* xn = xw1 + ((size_t)(k + 1) << 16);
#pragma unroll
            for (int g = 0; g < 4; ++g) xwn[g] = xn[(ab << 12) + (g << 10) + au];
          }
          const unsigned* gop = &flags[4096 + (bid << 4)];
          for (;;) {       // spin on OWN go line (broadcast read, 1 line)
            unsigned v = __hip_atomic_load(gop, __ATOMIC_RELAXED, __HIP_MEMORY_SCOPE_AGENT);
            if (v >= e) break;
            __builtin_amdgcn_s_sleep(1);
          }
          asm volatile("" ::: "memory");
          if (k < 255) {
#pragma unroll
            for (int g = 0; g < 4; ++g) xwv[g] = xwn[g];
          }
        }
        __syncthreads();
      }
    }
  }
}

// ---------- prep kernels ----------
__global__ __launch_bounds__(256) void embed_gather_split(
    const int* __restrict__ tokens, const float* __restrict__ emb,
    unsigned short* __restrict__ xh, unsigned short* __restrict__ xl) {
  int sb = blockIdx.x;
  int tok = tokens[sb];
  f32x4 v = ((const f32x4*)(emb + (size_t)tok * 1024))[threadIdx.x];
  u16x4 h, l;
#pragma unroll
  for (int j = 0; j < 4; ++j) { unsigned short hh, ll; split1(v[j], hh, ll); h[j] = hh; l[j] = ll; }
  size_t o = (size_t)sb * 1024 + threadIdx.x * 4;
  *(u16x4*)(xh + o) = h;
  *(u16x4*)(xl + o) = l;
}

__global__ __launch_bounds__(256) void split_mat(
    const float* __restrict__ x, unsigned short* __restrict__ xh,
    unsigned short* __restrict__ xl) {
  size_t i = (size_t)blockIdx.x * 256 + threadIdx.x;
  f32x4 v = ((const f32x4*)x)[i];
  u16x4 h, l;
#pragma unroll
  for (int j = 0; j < 4; ++j) { unsigned short hh, ll; split1(v[j], hh, ll); h[j] = hh; l[j] = ll; }
  *(u16x4*)(xh + i * 4) = h;
  *(u16x4*)(xl + i * 4) = l;
}

__global__ void split_transpose_w(
    const float* __restrict__ W, unsigned short* __restrict__ WTh,
    unsigned short* __restrict__ WTl, int K, int N) {
  __shared__ float tile[32][33];
  int n0 = blockIdx.x << 5;
  int k0 = blockIdx.y << 5;
  int tx = threadIdx.x, ty = threadIdx.y;  // 32 x 8
#pragma unroll
  for (int i = 0; i < 32; i += 8) {
    int n = n0 + tx;
    tile[ty + i][tx] = (n < N) ? W[(size_t)(k0 + ty + i) * N + n] : 0.f;
  }
  __syncthreads();
#pragma unroll
  for (int i = 0; i < 32; i += 8) {
    int n = n0 + ty + i;
    float v = tile[tx][ty + i];
    unsigned short h, l; split1(v, h, l);
    WTh[(size_t)n * K + k0 + tx] = h;
    WTl[(size_t)n * K + k0 + tx] = l;
  }
}

// [1024][4096] f32 -> [4096][1024] f32
__global__ void transpose1(const float* __restrict__ src, float* __restrict__ dst) {
  __shared__ float tile[32][33];
  int c0 = blockIdx.x << 5;
  int k0 = blockIdx.y << 5;
  int tx = threadIdx.x, ty = threadIdx.y;  // 32 x 8
#pragma unroll
  for (int i = 0; i < 32; i += 8)
    tile[ty + i][tx] = src[(size_t)(k0 + ty + i) * 4096 + c0 + tx];
  __syncthreads();
#pragma unroll
  for (int i = 0; i < 32; i += 8)
    dst[(size_t)(c0 + ty + i) * 1024 + k0 + tx] = tile[tx][ty + i];
}

// ---------- host ----------
extern "C" void kernel_launch(void* const* d_in, const int* in_sizes, int n_in,
                              void* d_out, int out_size, void* d_ws, size_t ws_size,
                              hipStream_t stream) {
  (void)in_sizes; (void)n_in; (void)out_size; (void)ws_size;
  const int*   tokens    = (const int*)  d_in[0];
  const float* hidden    = (const float*)d_in[1];
  const float* embedding = (const float*)d_in[2];
  const float* wi        = (const float*)d_in[3];
  const float* bi        = (const float*)d_in[4];
  const float* wh        = (const float*)d_in[5];
  const float* bh        = (const float*)d_in[6];
  const float* wdec      = (const float*)d_in[7];
  const float* bdec      = (const float*)d_in[8];

  float* out     = (float*)d_out;
  float* out_res = out;                                   // 256*16*50257
  float* out_nh  = out + (size_t)205852672;               // 2*2*16*1024
  float* out_x   = out + (size_t)205852672 + 65536;       // 256*16*1024
  float* h1buf   = out_res;                               // fused-path scratch

  // ---- workspace layout ----
  float* ws    = (float*)d_ws;
  float* whT   = ws;                        // 2*4194304 f (layers contiguous)
  float* xwb   = whT + 8388608;             // 16777216 f
  float* ys0   = xwb + 16777216;            // 4194304 f (fallback h1 seq)
  unsigned* flags = (unsigned*)(ys0 + 4194304);  // 16384 u32 (arr/go lines + fallback dense)
  unsigned short* u16base = (unsigned short*)(flags + 16384);
  unsigned short* Ah_s  = u16base;                 // 4194304
  unsigned short* Al_s  = Ah_s + 4194304;          // 4194304
  unsigned short* wiTh  = Al_s + 4194304;          // 4194304 (layer 0)
  unsigned short* wiTl  = wiTh + 4194304;          // 4194304
  unsigned short* wi2Th = wiTl + 4194304;          // 4194304 (layer 1)
  unsigned short* wi2Tl = wi2Th + 4194304;         // 4194304
  unsigned short* wdTh  = wi2Tl + 4194304;         // 51511296
  unsigned short* wdTl  = wdTh + 51511296;         // 51511296

  hipMemsetAsync(flags, 0, 16384 * sizeof(unsigned), stream);
  transpose1<<<dim3(128, 32), dim3(32, 8), 0, stream>>>(wh, whT);
  transpose1<<<dim3(128, 32), dim3(32, 8), 0, stream>>>(wh + 4194304, whT + 4194304);
  embed_gather_split<<<4096, 256, 0, stream>>>(tokens, embedding, Ah_s, Al_s);
  split_transpose_w<<<dim3(128, 32), dim3(32, 8), 0, stream>>>(wi, wiTh, wiTl, 1024, 4096);
  split_transpose_w<<<dim3(128, 32), dim3(32, 8), 0, stream>>>(wi + 4194304, wi2Th, wi2Tl, 1024, 4096);
  split_transpose_w<<<dim3(1572, 32), dim3(32, 8), 0, stream>>>(wdec, wdTh, wdTl, 1024, 50257);

  // xw1 = emb @ wi0^T + bi0 (both paths need this)
  gemm_ps<<<dim3(32, 32), 256, 0, stream>>>(
      Ah_s, Al_s, wiTh, wiTl, bi, xwb, 4096, 4096, 1024);

  // ---- fused path, gated on occupancy + launch acceptance (r11 lesson) ----
  bool fused_ok = false;
  int nb = 0;
  hipError_t qerr = hipOccupancyMaxActiveBlocksPerMultiprocessor(
      &nb, (const void*)lstm2_persistent, 256, 0);
  if (qerr == hipSuccess && nb >= 1) {
    const float* p_wh1T = whT; const float* p_wh2T = whT + 4194304;
    const unsigned short* p_wi2Th = wi2Th; const unsigned short* p_wi2Tl = wi2Tl;
    const float* p_xw1 = xwb;  const float* p_bh = bh;   const float* p_bi = bi;
    const float* p_hid = hidden;
    float* p_h1 = h1buf; float* p_ys2 = out_x; float* p_nh = out_nh;
    unsigned* p_fl = flags;
    void* args[] = { &p_wh1T, &p_wh2T, &p_wi2Th, &p_wi2Tl, &p_xw1, &p_bh, &p_bi,
                     &p_hid, &p_h1, &p_ys2, &p_nh, &p_fl };
    hipError_t cerr = hipLaunchCooperativeKernel((const void*)lstm2_persistent,
                                                 dim3(256), dim3(256), args, 0, stream);
    fused_ok = (cerr == hipSuccess);
  }

  if (!fused_ok) {
    // ---- exact r8 fallback: per-layer coop kernels (dense flags at +8192) ----
    unsigned* fl2 = flags + 8192;
    for (int l = 0; l < 2; ++l) {
      if (l == 1) {
        gemm_ps<<<dim3(32, 32), 256, 0, stream>>>(
            Ah_s, Al_s, wi2Th, wi2Tl, bi + 4096, xwb, 4096, 4096, 1024);
      }
      const float* wT  = whT + (size_t)l * 4194304;
      const float* xwp = xwb;
      const float* bhl = bh + l * 4096;
      const float* h0p = hidden + (size_t)l * 32768;
      const float* c0p = h0p + 16384;
      float* ysp  = (l == 0) ? ys0 : out_x;
      float* hfin = out_nh + (size_t)l * 32768;
      float* cfin = hfin + 16384;
      unsigned basev = (unsigned)(l * 256);
      void* args[] = { &wT, &xwp, &bhl, &h0p, &c0p, &ysp, &hfin, &cfin, &fl2, &basev };
      hipLaunchCooperativeKernel((const void*)lstm_persistent,
                                 dim3(256), dim3(256), args, 0, stream);
      split_mat<<<4096, 256, 0, stream>>>(ysp, Ah_s, Al_s);
    }
  } else {
    split_mat<<<4096, 256, 0, stream>>>(out_x, Ah_s, Al_s);
  }

  // decode
  gemm_ps<<<dim3(32, 393), 256, 0, stream>>>(
      Ah_s, Al_s, wdTh, wdTl, bdec, out_res, 4096, 50257, 1024);
}

// Round 13
// 6409.365 us; speedup vs baseline: 2.5526x; 1.0534x over previous
//
#include <hip/hip_runtime.h>

// ---------- types ----------
typedef float  f32x4  __attribute__((ext_vector_type(4)));
typedef unsigned short u16x4 __attribute__((ext_vector_type(4)));
typedef unsigned short u16x8 __attribute__((ext_vector_type(8)));
typedef __bf16 bf16x8 __attribute__((ext_vector_type(8)));

// round-to-nearest-even f32 -> bf16 (bit trick)
static __device__ __forceinline__ unsigned short bf16_rn(float x) {
  unsigned u = __builtin_bit_cast(unsigned, x);
  unsigned r = (u + 0x7FFFu + ((u >> 16) & 1u)) >> 16;
  return (unsigned short)r;
}
// split x ~= hi + lo (each bf16); residual ~2^-17 relative
static __device__ __forceinline__ void split1(float x, unsigned short& h, unsigned short& l) {
  unsigned short hh = bf16_rn(x);
  float hf = __builtin_bit_cast(float, ((unsigned)hh) << 16);
  h = hh;
  l = bf16_rn(x - hf);
}

#define BM 128
#define BN 128
#define BK 32

// LDS tile [128 rows][32 u16], 64B rows, XOR chunk swizzle: chunk position
// p holds global chunk p ^ ((row>>2)&3). 16-lane fragment reads touch 8
// distinct 16B slots -> 2-way banks (free, m136).
static __device__ __forceinline__ int lds_i32(int row, int k) {
  return (row << 5) + ((((k >> 3) ^ (row >> 2)) & 3) << 3) + (k & 7);
}

// async global->LDS, 16B per lane; LDS dest wave-uniform base + lane*16
static __device__ __forceinline__ void gld16(const unsigned short* g, unsigned short* l) {
  __builtin_amdgcn_global_load_lds(
      (const __attribute__((address_space(1))) void*)g,
      (__attribute__((address_space(3))) void*)l, 16, 0, 0);
}

// ---------- GEMM (pre-split inputs): C = A * B^T + bias ----------
// Staging via global_load_lds with pre-swizzled per-lane global source
// (linear LDS dest): lane l of wave w, inst i covers row r0+(l>>2),
// LDS chunk pos l&3, loading global chunk (l&3)^((row>>2)&3).
__global__ __launch_bounds__(256) void gemm_ps(
    const unsigned short* __restrict__ Ahg, const unsigned short* __restrict__ Alg,
    const unsigned short* __restrict__ Bhg, const unsigned short* __restrict__ Blg,
    const float* __restrict__ bias, float* __restrict__ C,
    int M, int N, int K) {
  __shared__ unsigned short Ah[BM * 32];
  __shared__ unsigned short Al[BM * 32];
  __shared__ unsigned short Bh[BN * 32];
  __shared__ unsigned short Bl[BN * 32];

  const int tid  = threadIdx.x;
  const int lane = tid & 63;
  const int wave = tid >> 6;
  const int bm = blockIdx.x * BM;
  const int bn = blockIdx.y * BN;
  const int wm = (wave >> 1) * 64;
  const int wn = (wave & 1) * 64;

  f32x4 acc[4][4] = {};

  const int rl = lane >> 2;   // row within 16-row group
  const int ch = lane & 3;    // LDS chunk position

  for (int k0 = 0; k0 < K; k0 += BK) {
#pragma unroll
    for (int i = 0; i < 2; ++i) {
      int r0  = ((wave << 1) + i) << 4;          // group base row (wave-uniform)
      int row = r0 + rl;
      int gc  = ch ^ ((row >> 2) & 3);           // pre-swizzled global chunk
      size_t ga = (size_t)(bm + row) * K + k0 + (gc << 3);
      size_t gb = (size_t)(bn + row) * K + k0 + (gc << 3);
      int lb = r0 << 5;                          // u16 index of group start
      gld16(Ahg + ga, &Ah[lb]);
      gld16(Alg + ga, &Al[lb]);
      gld16(Bhg + gb, &Bh[lb]);
      gld16(Blg + gb, &Bl[lb]);
    }
    __syncthreads();

    const int fr = lane & 15;
    const int kg = (lane >> 4) << 3;
    u16x8 a_h[4], a_l[4], b_h[4], b_l[4];
#pragma unroll
    for (int i = 0; i < 4; ++i) {
      int ia = lds_i32(wm + i * 16 + fr, kg);
      int ib = lds_i32(wn + i * 16 + fr, kg);
      a_h[i] = *(const u16x8*)(&Ah[ia]);
      a_l[i] = *(const u16x8*)(&Al[ia]);
      b_h[i] = *(const u16x8*)(&Bh[ib]);
      b_l[i] = *(const u16x8*)(&Bl[ib]);
    }
#pragma unroll
    for (int i = 0; i < 4; ++i)
#pragma unroll
      for (int j = 0; j < 4; ++j) {
        acc[i][j] = __builtin_amdgcn_mfma_f32_16x16x32_bf16(
            __builtin_bit_cast(bf16x8, a_h[i]), __builtin_bit_cast(bf16x8, b_h[j]), acc[i][j], 0, 0, 0);
        acc[i][j] = __builtin_amdgcn_mfma_f32_16x16x32_bf16(
            __builtin_bit_cast(bf16x8, a_h[i]), __builtin_bit_cast(bf16x8, b_l[j]), acc[i][j], 0, 0, 0);
        acc[i][j] = __builtin_amdgcn_mfma_f32_16x16x32_bf16(
            __builtin_bit_cast(bf16x8, a_l[i]), __builtin_bit_cast(bf16x8, b_h[j]), acc[i][j], 0, 0, 0);
      }
    __syncthreads();
  }
  const int cc = lane & 15;
  const int rg = (lane >> 4) << 2;
#pragma unroll
  for (int i = 0; i < 4; ++i)
#pragma unroll
    for (int j = 0; j < 4; ++j)
#pragma unroll
      for (int r = 0; r < 4; ++r) {
        int row = bm + wm + i * 16 + rg + r;
        int col = bn + wn + j * 16 + cc;
        if (col < N) {
          float v = acc[i][j][r];
          if (bias) v += bias[col];
          C[(size_t)row * N + col] = v;
        }
      }
}

// ---------- legacy dense-flag poll (fallback path only) ----------
static __device__ __forceinline__ void poll_flags(const unsigned* flags, unsigned tgt, int lane) {
  for (;;) {
    unsigned v0 = __hip_atomic_load(flags + lane,       __ATOMIC_RELAXED, __HIP_MEMORY_SCOPE_AGENT);
    unsigned v1 = __hip_atomic_load(flags + 64 + lane,  __ATOMIC_RELAXED, __HIP_MEMORY_SCOPE_AGENT);
    unsigned v2 = __hip_atomic_load(flags + 128 + lane, __ATOMIC_RELAXED, __HIP_MEMORY_SCOPE_AGENT);
    unsigned v3 = __hip_atomic_load(flags + 192 + lane, __ATOMIC_RELAXED, __HIP_MEMORY_SCOPE_AGENT);
    unsigned m01 = v0 < v1 ? v0 : v1;
    unsigned m23 = v2 < v3 ? v2 : v3;
    unsigned mn  = m01 < m23 ? m01 : m23;
    if (__all((int)(mn >= tgt))) break;
    __builtin_amdgcn_s_sleep(1);
  }
  asm volatile("" ::: "memory");
}

// ---------- shared helpers for recurrence kernels ----------
static __device__ __forceinline__ void load_wset(
    const float* __restrict__ WT, int gcol, int wkoff,
    bf16x8* wh, bf16x8* wl) {
#pragma unroll
  for (int kk = 0; kk < 8; ++kk) {
    const float* src = WT + ((size_t)gcol << 10) + (wkoff + (kk << 5));
    f32x4 v0 = *(const f32x4*)src;
    f32x4 v1 = *(const f32x4*)(src + 4);
    u16x8 h8, l8;
#pragma unroll
    for (int j = 0; j < 4; ++j) {
      unsigned short hh, ll;
      split1(v0[j], hh, ll); h8[j] = hh;     l8[j] = ll;
      split1(v1[j], hh, ll); h8[4 + j] = hh; l8[4 + j] = ll;
    }
    wh[kk] = __builtin_bit_cast(bf16x8, h8);
    wl[kk] = __builtin_bit_cast(bf16x8, l8);
  }
}

static __device__ __forceinline__ void split_a(
    const float* __restrict__ hp, bf16x8& ah, bf16x8& al) {
  f32x4 v0 = *(const f32x4*)hp;
  f32x4 v1 = *(const f32x4*)(hp + 4);
  u16x8 h8, l8;
#pragma unroll
  for (int j = 0; j < 4; ++j) {
    unsigned short hh, ll;
    split1(v0[j], hh, ll); h8[j] = hh;     l8[j] = ll;
    split1(v1[j], hh, ll); h8[4 + j] = hh; l8[4 + j] = ll;
  }
  ah = __builtin_bit_cast(bf16x8, h8);
  al = __builtin_bit_cast(bf16x8, l8);
}

static __device__ __forceinline__ void dot3(
    const float* __restrict__ hsrc, int off,
    const bf16x8* wh, const bf16x8* wl,
    f32x4& a0, f32x4& a1, f32x4& a2) {
#pragma unroll
  for (int kk = 0; kk < 8; ++kk) {
    bf16x8 ah, al;
    split_a(hsrc + off + (kk << 5), ah, al);
    a0 = __builtin_amdgcn_mfma_f32_16x16x32_bf16(ah, wh[kk], a0, 0, 0, 0);
    a1 = __builtin_amdgcn_mfma_f32_16x16x32_bf16(ah, wl[kk], a1, 0, 0, 0);
    a2 = __builtin_amdgcn_mfma_f32_16x16x32_bf16(al, wh[kk], a2, 0, 0, 0);
  }
}

// packed-h consumers: h stored as (hi<<16)|lo by producer -> unpack is 2 ops/elem
static __device__ __forceinline__ void unpack_a(
    const unsigned* __restrict__ p, bf16x8& ah, bf16x8& al) {
  u16x8 h8, l8;
#pragma unroll
  for (int j = 0; j < 8; ++j) {
    unsigned r = p[j];
    h8[j] = (unsigned short)(r >> 16);
    l8[j] = (unsigned short)(r & 0xffffu);
  }
  ah = __builtin_bit_cast(bf16x8, h8);
  al = __builtin_bit_cast(bf16x8, l8);
}

static __device__ __forceinline__ void dot3_packed(
    const unsigned* __restrict__ hsrc, int off,
    const bf16x8* wh, const bf16x8* wl,
    f32x4& a0, f32x4& a1, f32x4& a2) {
#pragma unroll
  for (int kk = 0; kk < 8; ++kk) {
    bf16x8 ah, al;
    unpack_a(hsrc + off + (kk << 5), ah, al);
    a0 = __builtin_amdgcn_mfma_f32_16x16x32_bf16(ah, wh[kk], a0, 0, 0, 0);
    a1 = __builtin_amdgcn_mfma_f32_16x16x32_bf16(ah, wl[kk], a1, 0, 0, 0);
    a2 = __builtin_amdgcn_mfma_f32_16x16x32_bf16(al, wh[kk], a2, 0, 0, 0);
  }
}

static __device__ __forceinline__ void dot3_sp(
    const unsigned* __restrict__ hsrc, int off,
    const unsigned short* __restrict__ Wh, const unsigned short* __restrict__ Wl,
    size_t woff, f32x4& a0, f32x4& a1, f32x4& a2) {
#pragma unroll
  for (int kk = 0; kk < 8; ++kk) {
    u16x8 wh8 = *(const u16x8*)(Wh + woff + (kk << 5));
    u16x8 wl8 = *(const u16x8*)(Wl + woff + (kk << 5));
    bf16x8 ah, al;
    unpack_a(hsrc + off + (kk << 5), ah, al);
    a0 = __builtin_amdgcn_mfma_f32_16x16x32_bf16(ah, __builtin_bit_cast(bf16x8, wh8), a0, 0, 0, 0);
    a1 = __builtin_amdgcn_mfma_f32_16x16x32_bf16(ah, __builtin_bit_cast(bf16x8, wl8), a1, 0, 0, 0);
    a2 = __builtin_amdgcn_mfma_f32_16x16x32_bf16(al, __builtin_bit_cast(bf16x8, wh8), a2, 0, 0, 0);
  }
}

// ---------- r8 single-layer persistent LSTM (known-good fallback) ----------
__global__ __launch_bounds__(256) void lstm_persistent(
    const float* __restrict__ whT, const float* __restrict__ xw,
    const float* __restrict__ bh, const float* __restrict__ h0,
    const float* __restrict__ c0, float* __restrict__ ys,
    float* __restrict__ hfin, float* __restrict__ cfin,
    unsigned* __restrict__ flags, unsigned base) {
  __shared__ float red[4][16][16];
  const int tid  = threadIdx.x;
  const int lane = tid & 63;
  const int wave = tid >> 6;
  const int bid  = blockIdx.x;
  const int lc   = lane & 15;
  const int kg8  = (lane >> 4) << 3;
  const int wk   = wave << 8;

  const int gcol = (lc & 3) * 1024 + (bid << 2) + (lc >> 2);
  bf16x8 w_h[8], w_l[8];
  load_wset(whT, gcol, wk + kg8, w_h, w_l);

  const int ab = tid & 15;
  const int ai = tid >> 4;
  const int au = (bid << 2) + (ai & 3);
  float c_reg = 0.f, h_keep = 0.f;
  float bhv[4], xwv[4], xwn[4];
  if (tid < 64) {
    c_reg = c0[(ab << 10) + au];
#pragma unroll
    for (int g = 0; g < 4; ++g) bhv[g] = bh[(g << 10) + au];
#pragma unroll
    for (int g = 0; g < 4; ++g) xwv[g] = xw[(ab << 12) + (g << 10) + au];
  }
  const int hoff = (lc << 10) + wk + kg8;

  for (int s = 0; s < 256; ++s) {
    if (tid < 64 && s < 255) {
      const float* xn = xw + ((size_t)(s + 1) << 16);
#pragma unroll
      for (int g = 0; g < 4; ++g) xwn[g] = xn[(ab << 12) + (g << 10) + au];
    }
    const float* hsrc = (s == 0) ? h0 : (ys + ((size_t)(s - 1) << 14));
    f32x4 acc0 = {}, acc1 = {}, acc2 = {};
    dot3(hsrc, hoff, w_h, w_l, acc0, acc1, acc2);
    f32x4 a = acc0 + acc1 + acc2;
#pragma unroll
    for (int r = 0; r < 4; ++r) red[wave][(lane >> 4) * 4 + r][lc] = a[r];
    __syncthreads();
    if (tid < 64) {
      float pre[4];
#pragma unroll
      for (int g = 0; g < 4; ++g) {
        int c = (ai << 2) + g;
        pre[g] = red[0][ab][c] + red[1][ab][c] + red[2][ab][c] + red[3][ab][c]
               + xwv[g] + bhv[g];
      }
      float f  = 1.f / (1.f + expf(-pre[0]));
      float i_ = 1.f / (1.f + expf(-pre[1]));
      float o  = 1.f / (1.f + expf(-pre[2]));
      float g_ = tanhf(pre[3]);
      c_reg = f * c_reg + i_ * g_;
      float h = o * tanhf(c_reg);
      h_keep = h;
      __hip_atomic_store((unsigned*)ys + (((size_t)s << 14) + (ab << 10) + au),
                         __builtin_bit_cast(unsigned, h),
                         __ATOMIC_RELAXED, __HIP_MEMORY_SCOPE_AGENT);
#pragma unroll
      for (int g = 0; g < 4; ++g) xwv[g] = xwn[g];
    }
    if (wave == 0) {
      asm volatile("s_waitcnt vmcnt(0)" ::: "memory");
      if (lane == 0)
        __hip_atomic_store(&flags[bid], base + 1u + (unsigned)s, __ATOMIC_RELAXED, __HIP_MEMORY_SCOPE_AGENT);
      if (s < 255)
        poll_flags(flags, base + 1u + (unsigned)s, lane);
    }
    __syncthreads();
  }
  if (tid < 64) {
    hfin[(ab << 10) + au] = h_keep;
    cfin[(ab << 10) + au] = c_reg;
  }
}

// ---------- fused 2-layer pipelined LSTM, hub-and-spoke barrier, packed h ----------
// h1/h2 published PRE-SPLIT as (hi<<16)|lo u32 -> consumers unpack (2 ops/elem)
// instead of splitting (6 ops/elem); ys2 additionally stores f32 (output).
__global__ __launch_bounds__(256) void lstm2_persistent(
    const float* __restrict__ wh1T, const float* __restrict__ wh2T,
    const unsigned short* __restrict__ wi2Th, const unsigned short* __restrict__ wi2Tl,
    const float* __restrict__ xw1, const float* __restrict__ bh,
    const float* __restrict__ bi, const float* __restrict__ hidden,
    unsigned* __restrict__ h1bufP, unsigned* __restrict__ h2bufP,
    float* __restrict__ ys2, float* __restrict__ nh,
    unsigned* __restrict__ flags) {
  __shared__ float red1[4][16][16];
  __shared__ float red2[4][16][16];
  const int tid  = threadIdx.x;
  const int lane = tid & 63;
  const int wave = tid >> 6;
  const int bid  = blockIdx.x;
  const int lc   = lane & 15;
  const int kg8  = (lane >> 4) << 3;
  const int wk   = wave << 8;
  const int wkoff = wk + kg8;

  const int gcol = (lc & 3) * 1024 + (bid << 2) + (lc >> 2);
  const size_t woff = ((size_t)gcol << 10) + wkoff;
  bf16x8 w1h[8], w1l[8], w2hh[8], w2hl[8];
  load_wset(wh1T, gcol, wkoff, w1h, w1l);
  load_wset(wh2T, gcol, wkoff, w2hh, w2hl);

  const float* h01 = hidden;
  const float* c01 = hidden + 16384;
  const float* h02 = hidden + 32768;
  const float* c02 = hidden + 49152;

  const int at = tid & 63;
  const int ab = at & 15;
  const int ai = at >> 4;
  const int au = (bid << 2) + ai;
  float c1 = 0.f, c2 = 0.f;
  float b1v[4], b2v[4], xwv[4], xwn[4];
  if (tid < 64) {
    c1 = c01[(ab << 10) + au];
#pragma unroll
    for (int g = 0; g < 4; ++g) b1v[g] = bh[(g << 10) + au];
#pragma unroll
    for (int g = 0; g < 4; ++g) xwv[g] = xw1[(ab << 12) + (g << 10) + au];
  } else if (tid < 128) {
    c2 = c02[(ab << 10) + au];
#pragma unroll
    for (int g = 0; g < 4; ++g)
      b2v[g] = bh[4096 + (g << 10) + au] + bi[4096 + (g << 10) + au];
  }

  const int hoff = (lc << 10) + wkoff;

  for (int k = 0; k <= 256; ++k) {
    if (k < 256) {
      f32x4 a0 = {}, a1 = {}, a2 = {};
      if (k == 0) dot3(h01, hoff, w1h, w1l, a0, a1, a2);
      else dot3_packed(h1bufP + ((size_t)(k - 1) << 14), hoff, w1h, w1l, a0, a1, a2);
      f32x4 s = a0 + a1 + a2;
#pragma unroll
      for (int r = 0; r < 4; ++r) red1[wave][(lane >> 4) * 4 + r][lc] = s[r];
    }
    if (k >= 1) {
      const unsigned* hx = h1bufP + ((size_t)(k - 1) << 14);
      f32x4 b0 = {}, b1 = {}, b2 = {};
      dot3_sp(hx, hoff, wi2Th, wi2Tl, woff, b0, b1, b2);
      if (k == 1) dot3(h02, hoff, w2hh, w2hl, b0, b1, b2);
      else dot3_packed(h2bufP + ((size_t)(k - 2) << 14), hoff, w2hh, w2hl, b0, b1, b2);
      f32x4 s = b0 + b1 + b2;
#pragma unroll
      for (int r = 0; r < 4; ++r) red2[wave][(lane >> 4) * 4 + r][lc] = s[r];
    }
    __syncthreads();

    if (k < 256 && tid < 64) {
      float pre[4];
#pragma unroll
      for (int g = 0; g < 4; ++g) {
        int c = (ai << 2) + g;
        pre[g] = red1[0][ab][c] + red1[1][ab][c] + red1[2][ab][c] + red1[3][ab][c]
               + xwv[g] + b1v[g];
      }
      float f  = 1.f / (1.f + expf(-pre[0]));
      float i_ = 1.f / (1.f + expf(-pre[1]));
      float o  = 1.f / (1.f + expf(-pre[2]));
      float g_ = tanhf(pre[3]);
      c1 = f * c1 + i_ * g_;
      float h = o * tanhf(c1);
      unsigned short hh, ll; split1(h, hh, ll);
      __hip_atomic_store(&h1bufP[((size_t)k << 14) + (ab << 10) + au],
                         ((unsigned)hh << 16) | (unsigned)ll,
                         __ATOMIC_RELAXED, __HIP_MEMORY_SCOPE_AGENT);
      if (k == 255) {
        nh[(ab << 10) + au] = h;
        nh[16384 + (ab << 10) + au] = c1;
      }
    }
    if (k >= 1 && wave == 1) {
      int s2 = k - 1;
      float pre[4];
#pragma unroll
      for (int g = 0; g < 4; ++g) {
        int c = (ai << 2) + g;
        pre[g] = red2[0][ab][c] + red2[1][ab][c] + red2[2][ab][c] + red2[3][ab][c]
               + b2v[g];
      }
      float f  = 1.f / (1.f + expf(-pre[0]));
      float i_ = 1.f / (1.f + expf(-pre[1]));
      float o  = 1.f / (1.f + expf(-pre[2]));
      float g_ = tanhf(pre[3]);
      c2 = f * c2 + i_ * g_;
      float h = o * tanhf(c2);
      __hip_atomic_store((unsigned*)ys2 + (((size_t)s2 << 14) + (ab << 10) + au),
                         __builtin_bit_cast(unsigned, h),
                         __ATOMIC_RELAXED, __HIP_MEMORY_SCOPE_AGENT);
      unsigned short hh, ll; split1(h, hh, ll);
      __hip_atomic_store(&h2bufP[((size_t)s2 << 14) + (ab << 10) + au],
                         ((unsigned)hh << 16) | (unsigned)ll,
                         __ATOMIC_RELAXED, __HIP_MEMORY_SCOPE_AGENT);
      if (s2 == 255) {
        nh[32768 + (ab << 10) + au] = h;
        nh[49152 + (ab << 10) + au] = c2;
      }
    }
    if (wave < 2) asm volatile("s_waitcnt vmcnt(0)" ::: "memory");  // drain h stores
    __syncthreads();

    if (k < 256) {
      const unsigned e = (unsigned)(k + 1);
      if (wave == 0 && lane == 0)
        __hip_atomic_store(&flags[bid << 4], e, __ATOMIC_RELAXED, __HIP_MEMORY_SCOPE_AGENT);
      if (bid == 0) {
        if (wave == 0) {
          if (k < 255) {   // prefetch next xw: overlaps detection
            const float* xn = xw1 + ((size_t)(k + 1) << 16);
#pragma unroll
            for (int g = 0; g < 4; ++g) xwn[g] = xn[(ab << 12) + (g << 10) + au];
          }
          for (;;) {       // sole reader of all 256 arrival lines
            unsigned v0 = __hip_atomic_load(&flags[lane << 4],         __ATOMIC_RELAXED, __HIP_MEMORY_SCOPE_AGENT);
            unsigned v1 = __hip_atomic_load(&flags[(64 + lane) << 4],  __ATOMIC_RELAXED, __HIP_MEMORY_SCOPE_AGENT);
            unsigned v2 = __hip_atomic_load(&flags[(128 + lane) << 4], __ATOMIC_RELAXED, __HIP_MEMORY_SCOPE_AGENT);
            unsigned v3 = __hip_atomic_load(&flags[(192 + lane) << 4], __ATOMIC_RELAXED, __HIP_MEMORY_SCOPE_AGENT);
            unsigned m01 = v0 < v1 ? v0 : v1;
            unsigned m23 = v2 < v3 ? v2 : v3;
            unsigned mn  = m01 < m23 ? m01 : m23;
            if (__all((int)(mn >= e))) break;
            __builtin_amdgcn_s_sleep(1);
          }
          asm volatile("" ::: "memory");
          if (k < 255) {
#pragma unroll
            for (int g = 0; g < 4; ++g) xwv[g] = xwn[g];
          }
        }
        __syncthreads();
        __hip_atomic_store(&flags[4096 + (tid << 4)], e, __ATOMIC_RELAXED, __HIP_MEMORY_SCOPE_AGENT);
      } else {
        if (wave == 0) {
          if (k < 255) {
            const float* xn = xw1 + ((size_t)(k + 1) << 16);
#pragma unroll
            for (int g = 0; g < 4; ++g) xwn[g] = xn[(ab << 12) + (g << 10) + au];
          }
          const unsigned* gop = &flags[4096 + (bid << 4)];
          for (;;) {       // spin on OWN go line
            unsigned v = __hip_atomic_load(gop, __ATOMIC_RELAXED, __HIP_MEMORY_SCOPE_AGENT);
            if (v >= e) break;
            __builtin_amdgcn_s_sleep(1);
          }
          asm volatile("" ::: "memory");
          if (k < 255) {
#pragma unroll
            for (int g = 0; g < 4; ++g) xwv[g] = xwn[g];
          }
        }
        __syncthreads();
      }
    }
  }
}

// ---------- prep kernels ----------
__global__ __launch_bounds__(256) void embed_gather_split(
    const int* __restrict__ tokens, const float* __restrict__ emb,
    unsigned short* __restrict__ xh, unsigned short* __restrict__ xl) {
  int sb = blockIdx.x;
  int tok = tokens[sb];
  f32x4 v = ((const f32x4*)(emb + (size_t)tok * 1024))[threadIdx.x];
  u16x4 h, l;
#pragma unroll
  for (int j = 0; j < 4; ++j) { unsigned short hh, ll; split1(v[j], hh, ll); h[j] = hh; l[j] = ll; }
  size_t o = (size_t)sb * 1024 + threadIdx.x * 4;
  *(u16x4*)(xh + o) = h;
  *(u16x4*)(xl + o) = l;
}

__global__ __launch_bounds__(256) void split_mat(
    const float* __restrict__ x, unsigned short* __restrict__ xh,
    unsigned short* __restrict__ xl) {
  size_t i = (size_t)blockIdx.x * 256 + threadIdx.x;
  f32x4 v = ((const f32x4*)x)[i];
  u16x4 h, l;
#pragma unroll
  for (int j = 0; j < 4; ++j) { unsigned short hh, ll; split1(v[j], hh, ll); h[j] = hh; l[j] = ll; }
  *(u16x4*)(xh + i * 4) = h;
  *(u16x4*)(xl + i * 4) = l;
}

__global__ void split_transpose_w(
    const float* __restrict__ W, unsigned short* __restrict__ WTh,
    unsigned short* __restrict__ WTl, int K, int N) {
  __shared__ float tile[32][33];
  int n0 = blockIdx.x << 5;
  int k0 = blockIdx.y << 5;
  int tx = threadIdx.x, ty = threadIdx.y;  // 32 x 8
#pragma unroll
  for (int i = 0; i < 32; i += 8) {
    int n = n0 + tx;
    tile[ty + i][tx] = (n < N) ? W[(size_t)(k0 + ty + i) * N + n] : 0.f;
  }
  __syncthreads();
#pragma unroll
  for (int i = 0; i < 32; i += 8) {
    int n = n0 + ty + i;
    float v = tile[tx][ty + i];
    unsigned short h, l; split1(v, h, l);
    WTh[(size_t)n * K + k0 + tx] = h;
    WTl[(size_t)n * K + k0 + tx] = l;
  }
}

// [1024][4096] f32 -> [4096][1024] f32
__global__ void transpose1(const float* __restrict__ src, float* __restrict__ dst) {
  __shared__ float tile[32][33];
  int c0 = blockIdx.x << 5;
  int k0 = blockIdx.y << 5;
  int tx = threadIdx.x, ty = threadIdx.y;  // 32 x 8
#pragma unroll
  for (int i = 0; i < 32; i += 8)
    tile[ty + i][tx] = src[(size_t)(k0 + ty + i) * 4096 + c0 + tx];
  __syncthreads();
#pragma unroll
  for (int i = 0; i < 32; i += 8)
    dst[(size_t)(c0 + ty + i) * 1024 + k0 + tx] = tile[tx][ty + i];
}

// ---------- host ----------
extern "C" void kernel_launch(void* const* d_in, const int* in_sizes, int n_in,
                              void* d_out, int out_size, void* d_ws, size_t ws_size,
                              hipStream_t stream) {
  (void)in_sizes; (void)n_in; (void)out_size; (void)ws_size;
  const int*   tokens    = (const int*)  d_in[0];
  const float* hidden    = (const float*)d_in[1];
  const float* embedding = (const float*)d_in[2];
  const float* wi        = (const float*)d_in[3];
  const float* bi        = (const float*)d_in[4];
  const float* wh        = (const float*)d_in[5];
  const float* bh        = (const float*)d_in[6];
  const float* wdec      = (const float*)d_in[7];
  const float* bdec      = (const float*)d_in[8];

  float* out     = (float*)d_out;
  float* out_res = out;                                   // 256*16*50257
  float* out_nh  = out + (size_t)205852672;               // 2*2*16*1024
  float* out_x   = out + (size_t)205852672 + 65536;       // 256*16*1024
  unsigned* h1bufP = (unsigned*)out_res;                  // packed h1 scratch
  unsigned* h2bufP = (unsigned*)(out_res + 4194304);      // packed h2 scratch
  float* ys0_fb  = out_res + 8388608;                     // fallback h1 seq (f32, scratch)

  // ---- workspace layout ----
  float* ws    = (float*)d_ws;
  float* whT   = ws;                        // 2*4194304 f (layers contiguous)
  float* xwb   = whT + 8388608;             // 16777216 f
  unsigned* flags = (unsigned*)(xwb + 16777216);  // 16384 u32
  unsigned short* u16base = (unsigned short*)(flags + 16384);
  unsigned short* Ah_s  = u16base;                 // 4194304
  unsigned short* Al_s  = Ah_s + 4194304;          // 4194304
  unsigned short* wiTh  = Al_s + 4194304;          // 4194304 (layer 0)
  unsigned short* wiTl  = wiTh + 4194304;          // 4194304
  unsigned short* wi2Th = wiTl + 4194304;          // 4194304 (layer 1)
  unsigned short* wi2Tl = wi2Th + 4194304;         // 4194304
  unsigned short* wdTh  = wi2Tl + 4194304;         // 51511296
  unsigned short* wdTl  = wdTh + 51511296;         // 51511296

  hipMemsetAsync(flags, 0, 16384 * sizeof(unsigned), stream);
  transpose1<<<dim3(128, 32), dim3(32, 8), 0, stream>>>(wh, whT);
  transpose1<<<dim3(128, 32), dim3(32, 8), 0, stream>>>(wh + 4194304, whT + 4194304);
  embed_gather_split<<<4096, 256, 0, stream>>>(tokens, embedding, Ah_s, Al_s);
  split_transpose_w<<<dim3(128, 32), dim3(32, 8), 0, stream>>>(wi, wiTh, wiTl, 1024, 4096);
  split_transpose_w<<<dim3(128, 32), dim3(32, 8), 0, stream>>>(wi + 4194304, wi2Th, wi2Tl, 1024, 4096);
  split_transpose_w<<<dim3(1572, 32), dim3(32, 8), 0, stream>>>(wdec, wdTh, wdTl, 1024, 50257);

  // xw1 = emb @ wi0^T + bi0 (both paths need this)
  gemm_ps<<<dim3(32, 32), 256, 0, stream>>>(
      Ah_s, Al_s, wiTh, wiTl, bi, xwb, 4096, 4096, 1024);

  // ---- fused path, gated on occupancy + launch acceptance (r11 lesson) ----
  bool fused_ok = false;
  int nb = 0;
  hipError_t qerr = hipOccupancyMaxActiveBlocksPerMultiprocessor(
      &nb, (const void*)lstm2_persistent, 256, 0);
  if (qerr == hipSuccess && nb >= 1) {
    const float* p_wh1T = whT; const float* p_wh2T = whT + 4194304;
    const unsigned short* p_wi2Th = wi2Th; const unsigned short* p_wi2Tl = wi2Tl;
    const float* p_xw1 = xwb;  const float* p_bh = bh;   const float* p_bi = bi;
    const float* p_hid = hidden;
    unsigned* p_h1 = h1bufP; unsigned* p_h2 = h2bufP;
    float* p_ys2 = out_x; float* p_nh = out_nh;
    unsigned* p_fl = flags;
    void* args[] = { &p_wh1T, &p_wh2T, &p_wi2Th, &p_wi2Tl, &p_xw1, &p_bh, &p_bi,
                     &p_hid, &p_h1, &p_h2, &p_ys2, &p_nh, &p_fl };
    hipError_t cerr = hipLaunchCooperativeKernel((const void*)lstm2_persistent,
                                                 dim3(256), dim3(256), args, 0, stream);
    fused_ok = (cerr == hipSuccess);
  }

  if (!fused_ok) {
    // ---- exact r8 fallback: per-layer coop kernels (dense flags at +8192) ----
    unsigned* fl2 = flags + 8192;
    for (int l = 0; l < 2; ++l) {
      if (l == 1) {
        gemm_ps<<<dim3(32, 32), 256, 0, stream>>>(
            Ah_s, Al_s, wi2Th, wi2Tl, bi + 4096, xwb, 4096, 4096, 1024);
      }
      const float* wT  = whT + (size_t)l * 4194304;
      const float* xwp = xwb;
      const float* bhl = bh + l * 4096;
      const float* h0p = hidden + (size_t)l * 32768;
      const float* c0p = h0p + 16384;
      float* ysp  = (l == 0) ? ys0_fb : out_x;
      float* hfin = out_nh + (size_t)l * 32768;
      float* cfin = hfin + 16384;
      unsigned basev = (unsigned)(l * 256);
      void* args[] = { &wT, &xwp, &bhl, &h0p, &c0p, &ysp, &hfin, &cfin, &fl2, &basev };
      hipLaunchCooperativeKernel((const void*)lstm_persistent,
                                 dim3(256), dim3(256), args, 0, stream);
      split_mat<<<4096, 256, 0, stream>>>(ysp, Ah_s, Al_s);
    }
  } else {
    split_mat<<<4096, 256, 0, stream>>>(out_x, Ah_s, Al_s);
  }

  // decode
  gemm_ps<<<dim3(32, 393), 256, 0, stream>>>(
      Ah_s, Al_s, wdTh, wdTl, bdec, out_res, 4096, 50257, 1024);
}